// Round 6
// baseline (207.303 us; speedup 1.0000x reference)
//
#include <hip/hip_runtime.h>
#include <hip/hip_bf16.h>
#include <math.h>

#define NB 2
#define C1 64
#define C2 256
#define DD 256
#define NHH 8
#define HDD 32
#define NN 4096
#define FF 1024
#define MTOT (NB*NN)   // 8192 tokens
#define KVB 128

typedef unsigned short u16;
typedef __attribute__((ext_vector_type(8))) short bf16x8;
typedef __attribute__((ext_vector_type(4))) short s16x4;
typedef __attribute__((ext_vector_type(4))) float f32x4;
typedef __attribute__((ext_vector_type(4))) unsigned short us4;
typedef __attribute__((ext_vector_type(4))) unsigned int u32x4;

__device__ __forceinline__ u16 f2bf(float f) {
    union { float f; unsigned int i; } u; u.f = f;
    unsigned int r = u.i + 0x7FFFu + ((u.i >> 16) & 1u);
    return (u16)(r >> 16);
}

__device__ __forceinline__ unsigned cvt_pk_bf16(float a, float b) {
    unsigned r; asm("v_cvt_pk_bf16_f32 %0, %1, %2" : "=v"(r) : "v"(a), "v"(b)); return r;
}

// ---------------------------------------------------------------------------
// Weight f32 -> bf16 conversion (all 7 weight matrices, concatenated)
// ---------------------------------------------------------------------------
__global__ __launch_bounds__(256) void wconv(
    const float* __restrict__ s0, const float* __restrict__ s1,
    const float* __restrict__ s2, const float* __restrict__ s3,
    const float* __restrict__ s4, const float* __restrict__ s5,
    const float* __restrict__ s6, u16* __restrict__ d)
{
    int i = blockIdx.x * 256 + threadIdx.x;
    if (i >= 753664) return;
    const float* s; int off;
    if      (i <  16384) { s = s0; off = i; }
    else if (i <  81920) { s = s1; off = i -  16384; }
    else if (i < 147456) { s = s2; off = i -  81920; }
    else if (i < 212992) { s = s3; off = i - 147456; }
    else if (i < 229376) { s = s4; off = i - 212992; }
    else if (i < 491520) { s = s5; off = i - 229376; }
    else                 { s = s6; off = i - 491520; }
    d[i] = f2bf(s[off]);
}

// ---------------------------------------------------------------------------
// (B, C, N) f32  ->  (B, N, C) bf16   (channels-first to token-major)
// ---------------------------------------------------------------------------
__global__ __launch_bounds__(256) void tconv(const float* __restrict__ src,
                                             u16* __restrict__ dst, int C)
{
    __shared__ float tile[64][65];
    const int n0 = blockIdx.x * 64;
    const int c0 = blockIdx.y * 64;
    const int b  = blockIdx.z;
    const int t  = threadIdx.x;
#pragma unroll
    for (int i = 0; i < 4; ++i) {
        int cc = t + i * 256;
        int c = cc >> 4, off = (cc & 15) * 4;
        const float4 v = *(const float4*)&src[((size_t)b*C + c0 + c)*NN + n0 + off];
        tile[c][off+0] = v.x; tile[c][off+1] = v.y;
        tile[c][off+2] = v.z; tile[c][off+3] = v.w;
    }
    __syncthreads();
    const int n = t >> 2, cch = (t & 3) * 16;
    bf16x8 t0, t1;
#pragma unroll
    for (int i = 0; i < 8; ++i) ((u16*)&t0)[i] = f2bf(tile[cch + i][n]);
#pragma unroll
    for (int i = 0; i < 8; ++i) ((u16*)&t1)[i] = f2bf(tile[cch + 8 + i][n]);
    u16* dp = &dst[((size_t)b*NN + n0 + n)*C + c0 + cch];
    *(bf16x8*)&dp[0] = t0;
    *(bf16x8*)&dp[8] = t1;
}

// ---------------------------------------------------------------------------
// Generic C = A * B^T  (A: M x K row-major bf16, B: N x K row-major bf16)
// 128x128 tile, 4 waves (2x2 of 64x64), 16x16x32 bf16 MFMA, BK=32.
// Epilogues:
//  0: QKV-layout bf16 store ((b,h,n,hd)), value*scale
//  1: f32 row-major (resid)
//  2: f32 = acc + add[idx]             (Wo out + resid)
//  3: bf16 relu(acc + bias[col])       (FFN1)
//  4: f32 = acc + bias[col] + add[idx] (FFN2 + skip)
//  5: V fragment-permuted layout for flash PV B-frags (see flash_attn)
// ---------------------------------------------------------------------------
template<int MODE>
__global__ __launch_bounds__(256) void gemm_bt(
    const u16* __restrict__ A, const u16* __restrict__ Bw,
    int M, int N, int K,
    const float* __restrict__ bias, const float* __restrict__ add,
    float* __restrict__ outf, u16* __restrict__ outb, float scale)
{
    __shared__ u16 lA[128*40];
    __shared__ u16 lB[128*40];
    const int bm = blockIdx.x * 128;
    const int bn = blockIdx.y * 128;
    const int t = threadIdx.x;
    const int lane = t & 63;
    const int wid = t >> 6;
    const int wr = (wid >> 1) * 64, wc = (wid & 1) * 64;
    const int lrow = lane & 15, lk = (lane >> 4) * 8;
    f32x4 acc[4][4] = {};
    for (int k0 = 0; k0 < K; k0 += 32) {
#pragma unroll
        for (int i = 0; i < 2; ++i) {
            int c = t + i * 256;
            int row = c >> 2, off = (c & 3) * 8;
            *(bf16x8*)&lA[row*40 + off] = *(const bf16x8*)&A[(size_t)(bm+row)*K + k0 + off];
            *(bf16x8*)&lB[row*40 + off] = *(const bf16x8*)&Bw[(size_t)(bn+row)*K + k0 + off];
        }
        __syncthreads();
        bf16x8 af[4], bfr[4];
#pragma unroll
        for (int mf = 0; mf < 4; ++mf)
            af[mf] = *(const bf16x8*)&lA[(wr + mf*16 + lrow)*40 + lk];
#pragma unroll
        for (int nf = 0; nf < 4; ++nf)
            bfr[nf] = *(const bf16x8*)&lB[(wc + nf*16 + lrow)*40 + lk];
#pragma unroll
        for (int mf = 0; mf < 4; ++mf)
#pragma unroll
            for (int nf = 0; nf < 4; ++nf)
                acc[mf][nf] = __builtin_amdgcn_mfma_f32_16x16x32_bf16(af[mf], bfr[nf], acc[mf][nf], 0, 0, 0);
        __syncthreads();
    }
#pragma unroll
    for (int mf = 0; mf < 4; ++mf) {
#pragma unroll
        for (int nf = 0; nf < 4; ++nf) {
#pragma unroll
            for (int j = 0; j < 4; ++j) {
                int row = bm + wr + mf*16 + (lane >> 4)*4 + j;
                int col = bn + wc + nf*16 + lrow;
                float v = acc[mf][nf][j];
                if (MODE == 0) {
                    int b = row >> 12, n = row & 4095;
                    int h = col >> 5, hd = col & 31;
                    outb[(((size_t)b*NHH + h)*NN + n)*HDD + hd] = f2bf(v * scale);
                } else if (MODE == 1) {
                    outf[(size_t)row*N + col] = v;
                } else if (MODE == 2) {
                    size_t idx = (size_t)row*N + col;
                    outf[idx] = v + add[idx];
                } else if (MODE == 3) {
                    float r = v + bias[col];
                    outb[(size_t)row*N + col] = f2bf(r > 0.f ? r : 0.f);
                } else if (MODE == 4) {
                    size_t idx = (size_t)row*N + col;
                    outf[idx] = v + bias[col] + add[idx];
                } else {
                    // MODE 5: V fragment-permuted scatter.
                    // value = V[token=col][d_full=row]
                    // dest element: [bh][kb=n>>5][hf][g][d][ hp*4 + r ]
                    int b = col >> 12, n = col & 4095;
                    int h = row >> 5, hd = row & 31;
                    int hf = hd >> 4, d = hd & 15;
                    int bh = b*NHH + h;
                    int kb = n >> 5, kwb = n & 31;
                    int hp = kwb >> 4, gg = (kwb >> 2) & 3, r = kwb & 3;
                    size_t idx = ((((size_t)bh*128 + kb)*2 + hf)*64 + gg*16 + d)*8
                               + hp*4 + r;
                    outb[idx] = f2bf(v);
                }
            }
        }
    }
}

// ---------------------------------------------------------------------------
// Flash attention v6: ZERO LDS, ZERO barriers, coalesced loads, 32 q/wave.
// Two Q fragments per wave share every K and V fragment -> half the L1
// traffic of v5 at identical VALU/MFMA totals.
// - no-max base-2 softmax (scores bounded; scale+log2e folded into Q)
// - swapped QK^T: s = mfma(kf, qf) -> lane holds S for q = lane&15,
//   keys = nf*16 + g*4 + jj (g = lane>>4)
// - PV: A-frag = lane's own 8 P values (cvt_pk); B-frag = one 16B load from
//   fragment-permuted V (MODE 5).  Block = 4 waves x 32 q = 128 q rows.
// - XCD swizzle: 64 consecutive blocks per XCD cover 2 (b,h) -> L2-resident.
// ---------------------------------------------------------------------------
__global__ __launch_bounds__(256) void flash_attn(
    const u16* __restrict__ Qp, const u16* __restrict__ Kp,
    const u16* __restrict__ Vperm, u16* __restrict__ Op)
{
    const int id = blockIdx.x;                 // 0..511
    const int sw = (id & 7) * 64 + (id >> 3);  // XCD-grouped
    const int qt = sw & 31;
    const int bh = sw >> 5;                    // b*8 + h
    const size_t base = (size_t)bh * NN * HDD; // Q/K (b,h,n,hd)
    const int t = threadIdx.x, lane = t & 63, w = t >> 6;
    const int q0 = qt * 128 + w * 32;          // wave's 32 q rows
    const int lrow = lane & 15, g = lane >> 4;

    const bf16x8 qfa = *(const bf16x8*)&Qp[base + (size_t)(q0 + lrow)*HDD + g*8];
    const bf16x8 qfb = *(const bf16x8*)&Qp[base + (size_t)(q0 + 16 + lrow)*HDD + g*8];
    const u16* krow  = &Kp[base + (size_t)lrow*HDD + g*8];           // + key*HDD
    const u16* vlane = &Vperm[(size_t)bh*131072 + g*128 + lrow*8];   // + kb*1024 + hf*512

    f32x4 oa[2] = {}, ob[2] = {};
    float lra = 0.f, lrb = 0.f;

    for (int kv0 = 0; kv0 < NN; kv0 += KVB) {
        // S^T = K Q^T for both q-halves; K frags shared
        f32x4 sa[8], sb[8];
#pragma unroll
        for (int nf = 0; nf < 8; ++nf) {
            bf16x8 kf = *(const bf16x8*)&krow[(size_t)(kv0 + nf*16)*HDD];
            f32x4 z = {};
            sa[nf] = __builtin_amdgcn_mfma_f32_16x16x32_bf16(kf, qfa, z, 0, 0, 0);
            sb[nf] = __builtin_amdgcn_mfma_f32_16x16x32_bf16(kf, qfb, z, 0, 0, 0);
        }
        // softmax + PV per 32-key block kk; V frags shared across q-halves
#pragma unroll
        for (int kk = 0; kk < 4; ++kk) {
            const int kb = (kv0 >> 5) + kk;
            float pa0[4], pa1[4], pb0[4], pb1[4];
#pragma unroll
            for (int jj = 0; jj < 4; ++jj) {
                pa0[jj] = exp2f(sa[2*kk][jj]);
                pa1[jj] = exp2f(sa[2*kk+1][jj]);
                pb0[jj] = exp2f(sb[2*kk][jj]);
                pb1[jj] = exp2f(sb[2*kk+1][jj]);
            }
#pragma unroll
            for (int jj = 0; jj < 4; ++jj) {
                lra += pa0[jj] + pa1[jj];
                lrb += pb0[jj] + pb1[jj];
            }
            u32x4 wa, wb2;
            wa[0] = cvt_pk_bf16(pa0[0], pa0[1]);
            wa[1] = cvt_pk_bf16(pa0[2], pa0[3]);
            wa[2] = cvt_pk_bf16(pa1[0], pa1[1]);
            wa[3] = cvt_pk_bf16(pa1[2], pa1[3]);
            wb2[0] = cvt_pk_bf16(pb0[0], pb0[1]);
            wb2[1] = cvt_pk_bf16(pb0[2], pb0[3]);
            wb2[2] = cvt_pk_bf16(pb1[0], pb1[1]);
            wb2[3] = cvt_pk_bf16(pb1[2], pb1[3]);
            bf16x8 paf = *(bf16x8*)&wa;
            bf16x8 pbf = *(bf16x8*)&wb2;
#pragma unroll
            for (int hf = 0; hf < 2; ++hf) {
                bf16x8 vf = *(const bf16x8*)&vlane[(size_t)kb*1024 + hf*512];
                oa[hf] = __builtin_amdgcn_mfma_f32_16x16x32_bf16(paf, vf, oa[hf], 0, 0, 0);
                ob[hf] = __builtin_amdgcn_mfma_f32_16x16x32_bf16(pbf, vf, ob[hf], 0, 0, 0);
            }
        }
    }
    // row sums: reduce across the 4 g-groups (lanes l, l^16, l^32)
    lra += __shfl_xor(lra, 16); lra += __shfl_xor(lra, 32);
    lrb += __shfl_xor(lrb, 16); lrb += __shfl_xor(lrb, 32);
    const float inva = 1.f / lra;              // for q-row = lane&15 (half a)
    const float invb = 1.f / lrb;              // for q-row = lane&15 (half b)
    float invra[4], invrb[4];
#pragma unroll
    for (int r = 0; r < 4; ++r) {
        invra[r] = __shfl(inva, g*4 + r);
        invrb[r] = __shfl(invb, g*4 + r);
    }
    // store (b, n, D): lane -> d = hf*16 + lrow, q = q0 (+16) + g*4 + r
    const int b = bh >> 3, h = bh & 7;
#pragma unroll
    for (int hf = 0; hf < 2; ++hf)
#pragma unroll
        for (int r = 0; r < 4; ++r) {
            int d = h*HDD + hf*16 + lrow;
            int qa = q0 + g*4 + r;
            int qb = q0 + 16 + g*4 + r;
            Op[((size_t)b*NN + qa)*DD + d] = f2bf(oa[hf][r] * invra[r]);
            Op[((size_t)b*NN + qb)*DD + d] = f2bf(ob[hf][r] * invrb[r]);
        }
}

// ---------------------------------------------------------------------------
// LayerNorm1: y (8192x256 f32) -> x f32 and x bf16. One wave per row.
// ---------------------------------------------------------------------------
__global__ __launch_bounds__(256) void ln_fuse(const float* __restrict__ y,
    const float* __restrict__ g, const float* __restrict__ be,
    float* __restrict__ x, u16* __restrict__ xb)
{
    const int row = blockIdx.x * 4 + (threadIdx.x >> 6);
    const int lane = threadIdx.x & 63;
    const float4 v = *(const float4*)&y[(size_t)row*DD + lane*4];
    float s1 = v.x + v.y + v.z + v.w;
    float s2 = v.x*v.x + v.y*v.y + v.z*v.z + v.w*v.w;
#pragma unroll
    for (int m = 1; m <= 32; m <<= 1) { s1 += __shfl_xor(s1, m); s2 += __shfl_xor(s2, m); }
    float mean = s1 * (1.f/DD);
    float var  = s2 * (1.f/DD) - mean*mean;
    float rstd = rsqrtf(var + 1e-5f);
    const float vv[4] = {v.x, v.y, v.z, v.w};
    float4 xo; us4 xo16;
#pragma unroll
    for (int i = 0; i < 4; ++i) {
        int d = lane*4 + i;
        float r = (vv[i] - mean) * rstd * g[d] + be[d];
        ((float*)&xo)[i] = r;
        xo16[i] = f2bf(r);
    }
    *(float4*)&x[(size_t)row*DD + lane*4] = xo;
    *(us4*)&xb[(size_t)row*DD + lane*4] = xo16;
}

// ---------------------------------------------------------------------------
// LayerNorm2 + transpose to (B, D, H*W). 32 tokens per block via LDS tile.
// ---------------------------------------------------------------------------
__global__ __launch_bounds__(256) void ln2_transpose(const float* __restrict__ z,
    const float* __restrict__ g, const float* __restrict__ be,
    float* __restrict__ out)
{
    __shared__ float tile[32][257];
    const int n0 = blockIdx.x * 32;
    const int b = blockIdx.y;
    const int t = threadIdx.x, lane = t & 63, w = t >> 6;
    for (int r8 = 0; r8 < 8; ++r8) {
        int r = w*8 + r8;
        const float4 v = *(const float4*)&z[((size_t)b*NN + n0 + r)*DD + lane*4];
        float s1 = v.x + v.y + v.z + v.w;
        float s2 = v.x*v.x + v.y*v.y + v.z*v.z + v.w*v.w;
#pragma unroll
        for (int m = 1; m <= 32; m <<= 1) { s1 += __shfl_xor(s1, m); s2 += __shfl_xor(s2, m); }
        float mean = s1 * (1.f/DD);
        float var  = s2 * (1.f/DD) - mean*mean;
        float rstd = rsqrtf(var + 1e-5f);
        const float vv[4] = {v.x, v.y, v.z, v.w};
#pragma unroll
        for (int i = 0; i < 4; ++i) {
            int d = lane*4 + i;
            tile[r][d] = (vv[i] - mean)*rstd*g[d] + be[d];
        }
    }
    __syncthreads();
    const int n = t & 31, dg = t >> 5;
    for (int dd = 0; dd < 32; ++dd) {
        int d = dd*8 + dg;
        out[((size_t)b*DD + d)*NN + n0 + n] = tile[n][d];
    }
}

// ---------------------------------------------------------------------------
extern "C" void kernel_launch(void* const* d_in, const int* in_sizes, int n_in,
                              void* d_out, int out_size, void* d_ws, size_t ws_size,
                              hipStream_t stream)
{
    const float* F_lidar = (const float*)d_in[0];
    const float* F_cam   = (const float*)d_in[1];
    const float* Wq  = (const float*)d_in[2];
    const float* Wk  = (const float*)d_in[3];
    const float* Wv  = (const float*)d_in[4];
    const float* Wo  = (const float*)d_in[5];
    const float* Wrs = (const float*)d_in[6];
    const float* g1  = (const float*)d_in[7];
    const float* b1  = (const float*)d_in[8];
    const float* g2  = (const float*)d_in[9];
    const float* b2  = (const float*)d_in[10];
    const float* W1  = (const float*)d_in[11];
    const float* bf1 = (const float*)d_in[12];
    const float* W2  = (const float*)d_in[13];
    const float* bf2 = (const float*)d_in[14];
    float* out = (float*)d_out;

    char* ws = (char*)d_ws;
    size_t cur = 0;
    auto carve = [&](size_t bytes) {
        size_t o = cur; cur += (bytes + 255) & ~(size_t)255; return (void*)(ws + o);
    };
    u16* wb    = (u16*)carve(753664u * 2);
    u16* xl    = (u16*)carve((size_t)MTOT * C1 * 2);
    u16* xc    = (u16*)carve((size_t)MTOT * C2 * 2);
    u16* Qb    = (u16*)carve((size_t)MTOT * DD * 2);
    u16* Kb    = (u16*)carve((size_t)MTOT * DD * 2);
    u16* Vperm = (u16*)carve((size_t)MTOT * DD * 2);
    float* resid = (float*)carve((size_t)MTOT * DD * 4);
    u16* attn  = (u16*)carve((size_t)MTOT * DD * 2);
    float* y   = (float*)carve((size_t)MTOT * DD * 4);
    float* x   = (float*)carve((size_t)MTOT * DD * 4);
    u16* xb    = (u16*)carve((size_t)MTOT * DD * 2);
    u16* hdn   = (u16*)carve((size_t)MTOT * FF * 2);
    float* zb  = y;   // reuse: y consumed by ln_fuse before FFN2 writes z

    u16* Wqb  = wb;
    u16* Wkb  = wb + 16384;
    u16* Wvb  = wb + 81920;
    u16* Wob  = wb + 147456;
    u16* Wrsb = wb + 212992;
    u16* W1b  = wb + 229376;
    u16* W2b  = wb + 491520;

    wconv<<<2944, 256, 0, stream>>>(Wq, Wk, Wv, Wo, Wrs, W1, W2, wb);
    tconv<<<dim3(64, 1, NB), 256, 0, stream>>>(F_lidar, xl, C1);
    tconv<<<dim3(64, 4, NB), 256, 0, stream>>>(F_cam, xc, C2);

    // softmax scale and log2(e) folded into Q
    const float qscale = 1.4426950408889634f / sqrtf((float)HDD);
    gemm_bt<0><<<dim3(64, 2), 256, 0, stream>>>(xl, Wqb, MTOT, DD, C1, nullptr, nullptr, nullptr, Qb, qscale);
    gemm_bt<0><<<dim3(64, 2), 256, 0, stream>>>(xc, Wkb, MTOT, DD, C2, nullptr, nullptr, nullptr, Kb, 1.f);
    // V^T = Wv * xc^T  (A = Wv 256x256, B = xc 8192x256) -> fragment-permuted
    gemm_bt<5><<<dim3(2, 64), 256, 0, stream>>>(Wvb, xc, DD, MTOT, C2, nullptr, nullptr, nullptr, Vperm, 1.f);
    gemm_bt<1><<<dim3(64, 2), 256, 0, stream>>>(xl, Wrsb, MTOT, DD, C1, nullptr, nullptr, resid, nullptr, 1.f);

    flash_attn<<<512, 256, 0, stream>>>(Qb, Kb, Vperm, attn);

    gemm_bt<2><<<dim3(64, 2), 256, 0, stream>>>(attn, Wob, MTOT, DD, DD, nullptr, resid, y, nullptr, 1.f);
    ln_fuse<<<2048, 256, 0, stream>>>(y, g1, b1, x, xb);
    gemm_bt<3><<<dim3(64, 8), 256, 0, stream>>>(xb, W1b, MTOT, FF, DD, bf1, nullptr, nullptr, hdn, 1.f);
    gemm_bt<4><<<dim3(64, 2), 256, 0, stream>>>(hdn, W2b, MTOT, DD, FF, bf2, x, zb, nullptr, 1.f);
    ln2_transpose<<<dim3(128, NB), 256, 0, stream>>>(zb, g2, b2, out);
}

// Round 7
// 188.990 us; speedup vs baseline: 1.0969x; 1.0969x over previous
//
#include <hip/hip_runtime.h>
#include <hip/hip_bf16.h>
#include <math.h>

#define NB 2
#define C1 64
#define C2 256
#define DD 256
#define NHH 8
#define HDD 32
#define NN 4096
#define FF 1024
#define MTOT (NB*NN)   // 8192 tokens
#define KVB 128

typedef unsigned short u16;
typedef __attribute__((ext_vector_type(8))) short bf16x8;
typedef __attribute__((ext_vector_type(4))) short s16x4;
typedef __attribute__((ext_vector_type(4))) float f32x4;
typedef __attribute__((ext_vector_type(4))) unsigned short us4;
typedef __attribute__((ext_vector_type(4))) unsigned int u32x4;

__device__ __forceinline__ u16 f2bf(float f) {
    union { float f; unsigned int i; } u; u.f = f;
    unsigned int r = u.i + 0x7FFFu + ((u.i >> 16) & 1u);
    return (u16)(r >> 16);
}

__device__ __forceinline__ unsigned cvt_pk_bf16(float a, float b) {
    unsigned r; asm("v_cvt_pk_bf16_f32 %0, %1, %2" : "=v"(r) : "v"(a), "v"(b)); return r;
}

// async global->LDS, 16B per lane: dst = (uniform base) + lane*16, src per-lane
__device__ __forceinline__ void glds16(const void* g, void* l) {
    __builtin_amdgcn_global_load_lds(
        (__attribute__((address_space(1))) void*)g,
        (__attribute__((address_space(3))) void*)l, 16, 0, 0);
}

// ---------------------------------------------------------------------------
// Weight f32 -> bf16 conversion (all 7 weight matrices, concatenated)
// ---------------------------------------------------------------------------
__global__ __launch_bounds__(256) void wconv(
    const float* __restrict__ s0, const float* __restrict__ s1,
    const float* __restrict__ s2, const float* __restrict__ s3,
    const float* __restrict__ s4, const float* __restrict__ s5,
    const float* __restrict__ s6, u16* __restrict__ d)
{
    int i = blockIdx.x * 256 + threadIdx.x;
    if (i >= 753664) return;
    const float* s; int off;
    if      (i <  16384) { s = s0; off = i; }
    else if (i <  81920) { s = s1; off = i -  16384; }
    else if (i < 147456) { s = s2; off = i -  81920; }
    else if (i < 212992) { s = s3; off = i - 147456; }
    else if (i < 229376) { s = s4; off = i - 212992; }
    else if (i < 491520) { s = s5; off = i - 229376; }
    else                 { s = s6; off = i - 491520; }
    d[i] = f2bf(s[off]);
}

// ---------------------------------------------------------------------------
// (B, C, N) f32  ->  (B, N, C) bf16   (channels-first to token-major)
// ---------------------------------------------------------------------------
__global__ __launch_bounds__(256) void tconv(const float* __restrict__ src,
                                             u16* __restrict__ dst, int C)
{
    __shared__ float tile[64][65];
    const int n0 = blockIdx.x * 64;
    const int c0 = blockIdx.y * 64;
    const int b  = blockIdx.z;
    const int t  = threadIdx.x;
#pragma unroll
    for (int i = 0; i < 4; ++i) {
        int cc = t + i * 256;
        int c = cc >> 4, off = (cc & 15) * 4;
        const float4 v = *(const float4*)&src[((size_t)b*C + c0 + c)*NN + n0 + off];
        tile[c][off+0] = v.x; tile[c][off+1] = v.y;
        tile[c][off+2] = v.z; tile[c][off+3] = v.w;
    }
    __syncthreads();
    const int n = t >> 2, cch = (t & 3) * 16;
    bf16x8 t0, t1;
#pragma unroll
    for (int i = 0; i < 8; ++i) ((u16*)&t0)[i] = f2bf(tile[cch + i][n]);
#pragma unroll
    for (int i = 0; i < 8; ++i) ((u16*)&t1)[i] = f2bf(tile[cch + 8 + i][n]);
    u16* dp = &dst[((size_t)b*NN + n0 + n)*C + c0 + cch];
    *(bf16x8*)&dp[0] = t0;
    *(bf16x8*)&dp[8] = t1;
}

// ---------------------------------------------------------------------------
// Generic C = A * B^T  (A: M x K row-major bf16, B: N x K row-major bf16)
// 128x128 tile, 4 waves (2x2 of 64x64), 16x16x32 bf16 MFMA, BK=32.
// Epilogues:
//  0: QKV-layout bf16 store ((b,h,n,hd)), value*scale
//  1: f32 row-major (resid)
//  2: f32 = acc + add[idx]             (Wo out + resid)
//  3: bf16 relu(acc + bias[col])       (FFN1)
//  4: f32 = acc + bias[col] + add[idx] (FFN2 + skip)
//  5: V fragment-permuted layout for flash PV B-frags (see flash_attn)
// ---------------------------------------------------------------------------
template<int MODE>
__global__ __launch_bounds__(256) void gemm_bt(
    const u16* __restrict__ A, const u16* __restrict__ Bw,
    int M, int N, int K,
    const float* __restrict__ bias, const float* __restrict__ add,
    float* __restrict__ outf, u16* __restrict__ outb, float scale)
{
    __shared__ u16 lA[128*40];
    __shared__ u16 lB[128*40];
    const int bm = blockIdx.x * 128;
    const int bn = blockIdx.y * 128;
    const int t = threadIdx.x;
    const int lane = t & 63;
    const int wid = t >> 6;
    const int wr = (wid >> 1) * 64, wc = (wid & 1) * 64;
    const int lrow = lane & 15, lk = (lane >> 4) * 8;
    f32x4 acc[4][4] = {};
    for (int k0 = 0; k0 < K; k0 += 32) {
#pragma unroll
        for (int i = 0; i < 2; ++i) {
            int c = t + i * 256;
            int row = c >> 2, off = (c & 3) * 8;
            *(bf16x8*)&lA[row*40 + off] = *(const bf16x8*)&A[(size_t)(bm+row)*K + k0 + off];
            *(bf16x8*)&lB[row*40 + off] = *(const bf16x8*)&Bw[(size_t)(bn+row)*K + k0 + off];
        }
        __syncthreads();
        bf16x8 af[4], bfr[4];
#pragma unroll
        for (int mf = 0; mf < 4; ++mf)
            af[mf] = *(const bf16x8*)&lA[(wr + mf*16 + lrow)*40 + lk];
#pragma unroll
        for (int nf = 0; nf < 4; ++nf)
            bfr[nf] = *(const bf16x8*)&lB[(wc + nf*16 + lrow)*40 + lk];
#pragma unroll
        for (int mf = 0; mf < 4; ++mf)
#pragma unroll
            for (int nf = 0; nf < 4; ++nf)
                acc[mf][nf] = __builtin_amdgcn_mfma_f32_16x16x32_bf16(af[mf], bfr[nf], acc[mf][nf], 0, 0, 0);
        __syncthreads();
    }
#pragma unroll
    for (int mf = 0; mf < 4; ++mf) {
#pragma unroll
        for (int nf = 0; nf < 4; ++nf) {
#pragma unroll
            for (int j = 0; j < 4; ++j) {
                int row = bm + wr + mf*16 + (lane >> 4)*4 + j;
                int col = bn + wc + nf*16 + lrow;
                float v = acc[mf][nf][j];
                if (MODE == 0) {
                    int b = row >> 12, n = row & 4095;
                    int h = col >> 5, hd = col & 31;
                    outb[(((size_t)b*NHH + h)*NN + n)*HDD + hd] = f2bf(v * scale);
                } else if (MODE == 1) {
                    outf[(size_t)row*N + col] = v;
                } else if (MODE == 2) {
                    size_t idx = (size_t)row*N + col;
                    outf[idx] = v + add[idx];
                } else if (MODE == 3) {
                    float r = v + bias[col];
                    outb[(size_t)row*N + col] = f2bf(r > 0.f ? r : 0.f);
                } else if (MODE == 4) {
                    size_t idx = (size_t)row*N + col;
                    outf[idx] = v + bias[col] + add[idx];
                } else {
                    // MODE 5: V fragment-permuted scatter.
                    // value = V[token=col][d_full=row]
                    // dest element: [bh][kb=n>>5][hf][g][d][ hp*4 + r ]
                    int b = col >> 12, n = col & 4095;
                    int h = row >> 5, hd = row & 31;
                    int hf = hd >> 4, d = hd & 15;
                    int bh = b*NHH + h;
                    int kb = n >> 5, kwb = n & 31;
                    int hp = kwb >> 4, gg = (kwb >> 2) & 3, r = kwb & 3;
                    size_t idx = ((((size_t)bh*128 + kb)*2 + hf)*64 + gg*16 + d)*8
                               + hp*4 + r;
                    outb[idx] = f2bf(v);
                }
            }
        }
    }
}

// ---------------------------------------------------------------------------
// Flash attention v7: LDS double-buffered K/V tiles via global_load_lds.
// - block = 4 waves x 16 q = 64 q rows; 1024 blocks -> 4 blocks/CU, 4 w/SIMD
// - per 128-key tile: K tile 8KB ([key][hd] row-major) + Vperm tile 8KB
//   (fragment-linear), both contiguous in global -> linear gload_lds x4/wave
// - no-max base-2 softmax (scale+log2e folded into Q); swapped QK^T so the
//   softmax row is lane-local; PV A-frag = lane's own P (cvt_pk);
//   all LDS reads b128, conflict-free. One __syncthreads per tile (its
//   implicit vmcnt drain covers the async stage).
// - XCD swizzle: 128 consecutive blocks per XCD cover 2 (b,h).
// ---------------------------------------------------------------------------
__global__ __launch_bounds__(256) void flash_attn(
    const u16* __restrict__ Qp, const u16* __restrict__ Kp,
    const u16* __restrict__ Vperm, u16* __restrict__ Op)
{
    __shared__ u16 Kl[2][4096];   // [128 keys][32 hd]
    __shared__ u16 Vl[2][4096];   // [kb 4][hf 2][g 4][d 16][8]
    const int id = blockIdx.x;                 // 0..1023
    const int sw = (id & 7) * 128 + (id >> 3); // XCD-grouped
    const int qt = sw & 63;
    const int bh = sw >> 6;                    // b*8 + h
    const size_t base = (size_t)bh * NN * HDD; // Q/K (b,h,n,hd)
    const int t = threadIdx.x, lane = t & 63, w = t >> 6;
    const int q0 = qt * 64;
    const int lrow = lane & 15, g = lane >> 4;

    const bf16x8 qf = *(const bf16x8*)&Qp[base + (size_t)(q0 + w*16 + lrow)*HDD + g*8];

    // staging: wave w owns elements [w*1024, w*1024+1024) of each 4096-elem tile
    const u16* kgw = &Kp[base + w*1024 + lane*8];
    const u16* vgw = &Vperm[(size_t)bh*131072 + w*1024 + lane*8];
    const int lw = w * 1024;

    // prologue: stage tile 0 into buffer 0
    glds16(kgw,       &Kl[0][lw]);
    glds16(kgw + 512, &Kl[0][lw + 512]);
    glds16(vgw,       &Vl[0][lw]);
    glds16(vgw + 512, &Vl[0][lw + 512]);

    f32x4 o[2] = {};
    float lrun = 0.f;
    __syncthreads();

    for (int tt = 0; tt < NN/KVB; ++tt) {
        const int cur = tt & 1;
        if (tt < NN/KVB - 1) {                 // async-stage tile tt+1
            const u16* kg = kgw + (size_t)(tt+1)*4096;
            const u16* vg = vgw + (size_t)(tt+1)*4096;
            glds16(kg,       &Kl[cur^1][lw]);
            glds16(kg + 512, &Kl[cur^1][lw + 512]);
            glds16(vg,       &Vl[cur^1][lw]);
            glds16(vg + 512, &Vl[cur^1][lw + 512]);
        }
        // S^T = K Q^T : lane -> q = lrow, keys nf*16 + g*4 + jj
        f32x4 s[8];
#pragma unroll
        for (int nf = 0; nf < 8; ++nf) {
            bf16x8 kf = *(const bf16x8*)&Kl[cur][(nf*16 + lrow)*32 + g*8];
            f32x4 z = {};
            s[nf] = __builtin_amdgcn_mfma_f32_16x16x32_bf16(kf, qf, z, 0, 0, 0);
        }
        // softmax + PV per 32-key block kk
#pragma unroll
        for (int kk = 0; kk < 4; ++kk) {
            float p0[4], p1[4];
#pragma unroll
            for (int jj = 0; jj < 4; ++jj) {
                p0[jj] = exp2f(s[2*kk][jj]);
                p1[jj] = exp2f(s[2*kk+1][jj]);
            }
#pragma unroll
            for (int jj = 0; jj < 4; ++jj) lrun += p0[jj] + p1[jj];
            u32x4 paw;
            paw[0] = cvt_pk_bf16(p0[0], p0[1]);
            paw[1] = cvt_pk_bf16(p0[2], p0[3]);
            paw[2] = cvt_pk_bf16(p1[0], p1[1]);
            paw[3] = cvt_pk_bf16(p1[2], p1[3]);
            bf16x8 pa = *(bf16x8*)&paw;
#pragma unroll
            for (int hf = 0; hf < 2; ++hf) {
                bf16x8 vf = *(const bf16x8*)&Vl[cur][kk*1024 + hf*512 + g*128 + lrow*8];
                o[hf] = __builtin_amdgcn_mfma_f32_16x16x32_bf16(pa, vf, o[hf], 0, 0, 0);
            }
        }
        __syncthreads();   // waves done reading cur; staged tt+1 landed (vmcnt drain)
    }
    // full row sums: reduce across the 4 g-groups (lanes l, l^16, l^32)
    lrun += __shfl_xor(lrun, 16);
    lrun += __shfl_xor(lrun, 32);
    const float inv = 1.f / lrun;              // for q-row = lane&15
    float invr[4];
#pragma unroll
    for (int r = 0; r < 4; ++r)
        invr[r] = __shfl(inv, g*4 + r);        // group-0 lane holding that q
    // O: lane -> d = hf*16 + lrow, q = q0 + w*16 + g*4 + r ; store (b,n,D)
    const int b = bh >> 3, h = bh & 7;
#pragma unroll
    for (int hf = 0; hf < 2; ++hf)
#pragma unroll
        for (int r = 0; r < 4; ++r) {
            int q = q0 + w*16 + g*4 + r;
            int d = h*HDD + hf*16 + lrow;
            Op[((size_t)b*NN + q)*DD + d] = f2bf(o[hf][r] * invr[r]);
        }
}

// ---------------------------------------------------------------------------
// LayerNorm1: y (8192x256 f32) -> x f32 and x bf16. One wave per row.
// ---------------------------------------------------------------------------
__global__ __launch_bounds__(256) void ln_fuse(const float* __restrict__ y,
    const float* __restrict__ g, const float* __restrict__ be,
    float* __restrict__ x, u16* __restrict__ xb)
{
    const int row = blockIdx.x * 4 + (threadIdx.x >> 6);
    const int lane = threadIdx.x & 63;
    const float4 v = *(const float4*)&y[(size_t)row*DD + lane*4];
    float s1 = v.x + v.y + v.z + v.w;
    float s2 = v.x*v.x + v.y*v.y + v.z*v.z + v.w*v.w;
#pragma unroll
    for (int m = 1; m <= 32; m <<= 1) { s1 += __shfl_xor(s1, m); s2 += __shfl_xor(s2, m); }
    float mean = s1 * (1.f/DD);
    float var  = s2 * (1.f/DD) - mean*mean;
    float rstd = rsqrtf(var + 1e-5f);
    const float vv[4] = {v.x, v.y, v.z, v.w};
    float4 xo; us4 xo16;
#pragma unroll
    for (int i = 0; i < 4; ++i) {
        int d = lane*4 + i;
        float r = (vv[i] - mean) * rstd * g[d] + be[d];
        ((float*)&xo)[i] = r;
        xo16[i] = f2bf(r);
    }
    *(float4*)&x[(size_t)row*DD + lane*4] = xo;
    *(us4*)&xb[(size_t)row*DD + lane*4] = xo16;
}

// ---------------------------------------------------------------------------
// LayerNorm2 + transpose to (B, D, H*W). 32 tokens per block via LDS tile.
// ---------------------------------------------------------------------------
__global__ __launch_bounds__(256) void ln2_transpose(const float* __restrict__ z,
    const float* __restrict__ g, const float* __restrict__ be,
    float* __restrict__ out)
{
    __shared__ float tile[32][257];
    const int n0 = blockIdx.x * 32;
    const int b = blockIdx.y;
    const int t = threadIdx.x, lane = t & 63, w = t >> 6;
    for (int r8 = 0; r8 < 8; ++r8) {
        int r = w*8 + r8;
        const float4 v = *(const float4*)&z[((size_t)b*NN + n0 + r)*DD + lane*4];
        float s1 = v.x + v.y + v.z + v.w;
        float s2 = v.x*v.x + v.y*v.y + v.z*v.z + v.w*v.w;
#pragma unroll
        for (int m = 1; m <= 32; m <<= 1) { s1 += __shfl_xor(s1, m); s2 += __shfl_xor(s2, m); }
        float mean = s1 * (1.f/DD);
        float var  = s2 * (1.f/DD) - mean*mean;
        float rstd = rsqrtf(var + 1e-5f);
        const float vv[4] = {v.x, v.y, v.z, v.w};
#pragma unroll
        for (int i = 0; i < 4; ++i) {
            int d = lane*4 + i;
            tile[r][d] = (vv[i] - mean)*rstd*g[d] + be[d];
        }
    }
    __syncthreads();
    const int n = t & 31, dg = t >> 5;
    for (int dd = 0; dd < 32; ++dd) {
        int d = dd*8 + dg;
        out[((size_t)b*DD + d)*NN + n0 + n] = tile[n][d];
    }
}

// ---------------------------------------------------------------------------
extern "C" void kernel_launch(void* const* d_in, const int* in_sizes, int n_in,
                              void* d_out, int out_size, void* d_ws, size_t ws_size,
                              hipStream_t stream)
{
    const float* F_lidar = (const float*)d_in[0];
    const float* F_cam   = (const float*)d_in[1];
    const float* Wq  = (const float*)d_in[2];
    const float* Wk  = (const float*)d_in[3];
    const float* Wv  = (const float*)d_in[4];
    const float* Wo  = (const float*)d_in[5];
    const float* Wrs = (const float*)d_in[6];
    const float* g1  = (const float*)d_in[7];
    const float* b1  = (const float*)d_in[8];
    const float* g2  = (const float*)d_in[9];
    const float* b2  = (const float*)d_in[10];
    const float* W1  = (const float*)d_in[11];
    const float* bf1 = (const float*)d_in[12];
    const float* W2  = (const float*)d_in[13];
    const float* bf2 = (const float*)d_in[14];
    float* out = (float*)d_out;

    char* ws = (char*)d_ws;
    size_t cur = 0;
    auto carve = [&](size_t bytes) {
        size_t o = cur; cur += (bytes + 255) & ~(size_t)255; return (void*)(ws + o);
    };
    u16* wb    = (u16*)carve(753664u * 2);
    u16* xl    = (u16*)carve((size_t)MTOT * C1 * 2);
    u16* xc    = (u16*)carve((size_t)MTOT * C2 * 2);
    u16* Qb    = (u16*)carve((size_t)MTOT * DD * 2);
    u16* Kb    = (u16*)carve((size_t)MTOT * DD * 2);
    u16* Vperm = (u16*)carve((size_t)MTOT * DD * 2);
    float* resid = (float*)carve((size_t)MTOT * DD * 4);
    u16* attn  = (u16*)carve((size_t)MTOT * DD * 2);
    float* y   = (float*)carve((size_t)MTOT * DD * 4);
    float* x   = (float*)carve((size_t)MTOT * DD * 4);
    u16* xb    = (u16*)carve((size_t)MTOT * DD * 2);
    u16* hdn   = (u16*)carve((size_t)MTOT * FF * 2);
    float* zb  = y;   // reuse: y consumed by ln_fuse before FFN2 writes z

    u16* Wqb  = wb;
    u16* Wkb  = wb + 16384;
    u16* Wvb  = wb + 81920;
    u16* Wob  = wb + 147456;
    u16* Wrsb = wb + 212992;
    u16* W1b  = wb + 229376;
    u16* W2b  = wb + 491520;

    wconv<<<2944, 256, 0, stream>>>(Wq, Wk, Wv, Wo, Wrs, W1, W2, wb);
    tconv<<<dim3(64, 1, NB), 256, 0, stream>>>(F_lidar, xl, C1);
    tconv<<<dim3(64, 4, NB), 256, 0, stream>>>(F_cam, xc, C2);

    // softmax scale and log2(e) folded into Q
    const float qscale = 1.4426950408889634f / sqrtf((float)HDD);
    gemm_bt<0><<<dim3(64, 2), 256, 0, stream>>>(xl, Wqb, MTOT, DD, C1, nullptr, nullptr, nullptr, Qb, qscale);
    gemm_bt<0><<<dim3(64, 2), 256, 0, stream>>>(xc, Wkb, MTOT, DD, C2, nullptr, nullptr, nullptr, Kb, 1.f);
    // V^T = Wv * xc^T  (A = Wv 256x256, B = xc 8192x256) -> fragment-permuted
    gemm_bt<5><<<dim3(2, 64), 256, 0, stream>>>(Wvb, xc, DD, MTOT, C2, nullptr, nullptr, nullptr, Vperm, 1.f);
    gemm_bt<1><<<dim3(64, 2), 256, 0, stream>>>(xl, Wrsb, MTOT, DD, C1, nullptr, nullptr, resid, nullptr, 1.f);

    flash_attn<<<1024, 256, 0, stream>>>(Qb, Kb, Vperm, attn);

    gemm_bt<2><<<dim3(64, 2), 256, 0, stream>>>(attn, Wob, MTOT, DD, DD, nullptr, resid, y, nullptr, 1.f);
    ln_fuse<<<2048, 256, 0, stream>>>(y, g1, b1, x, xb);
    gemm_bt<3><<<dim3(64, 8), 256, 0, stream>>>(xb, W1b, MTOT, FF, DD, bf1, nullptr, nullptr, hdn, 1.f);
    gemm_bt<4><<<dim3(64, 2), 256, 0, stream>>>(hdn, W2b, MTOT, DD, FF, bf2, x, zb, nullptr, 1.f);
    ln2_transpose<<<dim3(128, NB), 256, 0, stream>>>(zb, g2, b2, out);
}

// Round 8
// 157.490 us; speedup vs baseline: 1.3163x; 1.2000x over previous
//
#include <hip/hip_runtime.h>
#include <hip/hip_bf16.h>
#include <math.h>

#define NB 2
#define C1 64
#define C2 256
#define DD 256
#define NHH 8
#define HDD 32
#define NN 4096
#define FF 1024
#define MTOT (NB*NN)   // 8192 tokens
#define KVB 128

typedef unsigned short u16;
typedef __attribute__((ext_vector_type(8))) short bf16x8;
typedef __attribute__((ext_vector_type(4))) short s16x4;
typedef __attribute__((ext_vector_type(4))) float f32x4;
typedef __attribute__((ext_vector_type(4))) unsigned short us4;
typedef __attribute__((ext_vector_type(4))) unsigned int u32x4;

__device__ __forceinline__ u16 f2bf(float f) {
    union { float f; unsigned int i; } u; u.f = f;
    unsigned int r = u.i + 0x7FFFu + ((u.i >> 16) & 1u);
    return (u16)(r >> 16);
}

__device__ __forceinline__ unsigned cvt_pk_bf16(float a, float b) {
    unsigned r; asm("v_cvt_pk_bf16_f32 %0, %1, %2" : "=v"(r) : "v"(a), "v"(b)); return r;
}

// async global->LDS, 16B per lane: dst = (uniform base) + lane*16, src per-lane
__device__ __forceinline__ void glds16(const void* g, void* l) {
    __builtin_amdgcn_global_load_lds(
        (__attribute__((address_space(1))) void*)g,
        (__attribute__((address_space(3))) void*)l, 16, 0, 0);
}

// ---------------------------------------------------------------------------
// Weight f32 -> bf16 conversion (all 7 weight matrices, concatenated)
// ---------------------------------------------------------------------------
__global__ __launch_bounds__(256) void wconv(
    const float* __restrict__ s0, const float* __restrict__ s1,
    const float* __restrict__ s2, const float* __restrict__ s3,
    const float* __restrict__ s4, const float* __restrict__ s5,
    const float* __restrict__ s6, u16* __restrict__ d)
{
    int i = blockIdx.x * 256 + threadIdx.x;
    if (i >= 753664) return;
    const float* s; int off;
    if      (i <  16384) { s = s0; off = i; }
    else if (i <  81920) { s = s1; off = i -  16384; }
    else if (i < 147456) { s = s2; off = i -  81920; }
    else if (i < 212992) { s = s3; off = i - 147456; }
    else if (i < 229376) { s = s4; off = i - 212992; }
    else if (i < 491520) { s = s5; off = i - 229376; }
    else                 { s = s6; off = i - 491520; }
    d[i] = f2bf(s[off]);
}

// ---------------------------------------------------------------------------
// (B, C, N) f32  ->  (B, N, C) bf16   (channels-first to token-major)
// ---------------------------------------------------------------------------
__global__ __launch_bounds__(256) void tconv(const float* __restrict__ src,
                                             u16* __restrict__ dst, int C)
{
    __shared__ float tile[64][65];
    const int n0 = blockIdx.x * 64;
    const int c0 = blockIdx.y * 64;
    const int b  = blockIdx.z;
    const int t  = threadIdx.x;
#pragma unroll
    for (int i = 0; i < 4; ++i) {
        int cc = t + i * 256;
        int c = cc >> 4, off = (cc & 15) * 4;
        const float4 v = *(const float4*)&src[((size_t)b*C + c0 + c)*NN + n0 + off];
        tile[c][off+0] = v.x; tile[c][off+1] = v.y;
        tile[c][off+2] = v.z; tile[c][off+3] = v.w;
    }
    __syncthreads();
    const int n = t >> 2, cch = (t & 3) * 16;
    bf16x8 t0, t1;
#pragma unroll
    for (int i = 0; i < 8; ++i) ((u16*)&t0)[i] = f2bf(tile[cch + i][n]);
#pragma unroll
    for (int i = 0; i < 8; ++i) ((u16*)&t1)[i] = f2bf(tile[cch + 8 + i][n]);
    u16* dp = &dst[((size_t)b*NN + n0 + n)*C + c0 + cch];
    *(bf16x8*)&dp[0] = t0;
    *(bf16x8*)&dp[8] = t1;
}

// ---------------------------------------------------------------------------
// Generic C = A * B^T  (A: M x K row-major bf16, B: N x K row-major bf16)
// 128x128 tile, 4 waves (2x2 of 64x64), 16x16x32 bf16 MFMA, BK=32.
// Epilogues:
//  0: QKV-layout bf16 store ((b,h,n,hd)), value*scale
//  1: f32 row-major (resid)
//  2: f32 = acc + add[idx]             (Wo out + resid)
//  3: bf16 relu(acc + bias[col])       (FFN1)
//  4: f32 = acc + bias[col] + add[idx] (FFN2 + skip)
//  5: V fragment-permuted layout for flash PV B-frags (see flash_attn)
//  6: K fragment-permuted layout for flash QK^T A-frags (see flash_attn)
// ---------------------------------------------------------------------------
template<int MODE>
__global__ __launch_bounds__(256) void gemm_bt(
    const u16* __restrict__ A, const u16* __restrict__ Bw,
    int M, int N, int K,
    const float* __restrict__ bias, const float* __restrict__ add,
    float* __restrict__ outf, u16* __restrict__ outb, float scale)
{
    __shared__ u16 lA[128*40];
    __shared__ u16 lB[128*40];
    const int bm = blockIdx.x * 128;
    const int bn = blockIdx.y * 128;
    const int t = threadIdx.x;
    const int lane = t & 63;
    const int wid = t >> 6;
    const int wr = (wid >> 1) * 64, wc = (wid & 1) * 64;
    const int lrow = lane & 15, lk = (lane >> 4) * 8;
    f32x4 acc[4][4] = {};
    for (int k0 = 0; k0 < K; k0 += 32) {
#pragma unroll
        for (int i = 0; i < 2; ++i) {
            int c = t + i * 256;
            int row = c >> 2, off = (c & 3) * 8;
            *(bf16x8*)&lA[row*40 + off] = *(const bf16x8*)&A[(size_t)(bm+row)*K + k0 + off];
            *(bf16x8*)&lB[row*40 + off] = *(const bf16x8*)&Bw[(size_t)(bn+row)*K + k0 + off];
        }
        __syncthreads();
        bf16x8 af[4], bfr[4];
#pragma unroll
        for (int mf = 0; mf < 4; ++mf)
            af[mf] = *(const bf16x8*)&lA[(wr + mf*16 + lrow)*40 + lk];
#pragma unroll
        for (int nf = 0; nf < 4; ++nf)
            bfr[nf] = *(const bf16x8*)&lB[(wc + nf*16 + lrow)*40 + lk];
#pragma unroll
        for (int mf = 0; mf < 4; ++mf)
#pragma unroll
            for (int nf = 0; nf < 4; ++nf)
                acc[mf][nf] = __builtin_amdgcn_mfma_f32_16x16x32_bf16(af[mf], bfr[nf], acc[mf][nf], 0, 0, 0);
        __syncthreads();
    }
#pragma unroll
    for (int mf = 0; mf < 4; ++mf) {
#pragma unroll
        for (int nf = 0; nf < 4; ++nf) {
#pragma unroll
            for (int j = 0; j < 4; ++j) {
                int row = bm + wr + mf*16 + (lane >> 4)*4 + j;
                int col = bn + wc + nf*16 + lrow;
                float v = acc[mf][nf][j];
                if (MODE == 0) {
                    int b = row >> 12, n = row & 4095;
                    int h = col >> 5, hd = col & 31;
                    outb[(((size_t)b*NHH + h)*NN + n)*HDD + hd] = f2bf(v * scale);
                } else if (MODE == 1) {
                    outf[(size_t)row*N + col] = v;
                } else if (MODE == 2) {
                    size_t idx = (size_t)row*N + col;
                    outf[idx] = v + add[idx];
                } else if (MODE == 3) {
                    float r = v + bias[col];
                    outb[(size_t)row*N + col] = f2bf(r > 0.f ? r : 0.f);
                } else if (MODE == 4) {
                    size_t idx = (size_t)row*N + col;
                    outf[idx] = v + bias[col] + add[idx];
                } else if (MODE == 5) {
                    // V fragment-permuted scatter. value = V[token=col][d_full=row]
                    int b = col >> 12, n = col & 4095;
                    int h = row >> 5, hd = row & 31;
                    int hf = hd >> 4, d = hd & 15;
                    int bh = b*NHH + h;
                    int kb = n >> 5, kwb = n & 31;
                    int hp = kwb >> 4, gg = (kwb >> 2) & 3, r = kwb & 3;
                    size_t idx = ((((size_t)bh*128 + kb)*2 + hf)*64 + gg*16 + d)*8
                               + hp*4 + r;
                    outb[idx] = f2bf(v);
                } else {
                    // MODE 6: K fragment-permuted scatter. value = K[token=row][d=col]
                    // dest: [bh][b16 = n>>4][lane = g*16 + (n&15)][j = hd&7]
                    int b = row >> 12, n = row & 4095;
                    int h = col >> 5, hd = col & 31;
                    int bh = b*NHH + h;
                    int b16 = n >> 4, lr = n & 15, gg = hd >> 3, jj = hd & 7;
                    size_t idx = (((size_t)bh*256 + b16)*64 + gg*16 + lr)*8 + jj;
                    outb[idx] = f2bf(v);
                }
            }
        }
    }
}

// ---------------------------------------------------------------------------
// Flash attention v8: LDS double-buffered K/V via global_load_lds; both K and
// V stored fragment-linear in global so every LDS read is lane*16B (2-way
// bank aliasing = free) and every stage is a linear 8KB span.
// - no-max base-2 softmax, raw v_exp_f32 via __builtin_amdgcn_exp2f
//   (scores bounded: scale+log2e folded into Q)
// - swapped QK^T: lane holds S row-segment for q = lane&15 (lane-local)
// - PV A-frag = lane's own P (cvt_pk straight into MFMA operand)
// - row-sum via MFMA against all-ones B: osum[r] = rowsum(q=g*4+r), same
//   lane-mapping as o -> normalization needs NO shuffles at all.
// - block = 4 waves x 16 q; 1024 blocks; XCD swizzle (2 (b,h) per XCD).
// ---------------------------------------------------------------------------
__global__ __launch_bounds__(256) void flash_attn(
    const u16* __restrict__ Qp, const u16* __restrict__ Kperm,
    const u16* __restrict__ Vperm, u16* __restrict__ Op)
{
    __shared__ u16 Kl[2][4096];   // [b16 8][lane 64][8]
    __shared__ u16 Vl[2][4096];   // [kb 4][hf 2][lane 64][8]
    const int id = blockIdx.x;                 // 0..1023
    const int sw = (id & 7) * 128 + (id >> 3); // XCD-grouped
    const int qt = sw & 63;
    const int bh = sw >> 6;                    // b*8 + h
    const size_t base = (size_t)bh * NN * HDD; // Q (b,h,n,hd)
    const int t = threadIdx.x, lane = t & 63, w = t >> 6;
    const int q0 = qt * 64;
    const int lrow = lane & 15, g = lane >> 4;

    const bf16x8 qf = *(const bf16x8*)&Qp[base + (size_t)(q0 + w*16 + lrow)*HDD + g*8];

    // staging: wave w owns elements [w*1024, w*1024+1024) of each 4096-elem tile
    const u16* kgw = &Kperm[(size_t)bh*131072 + w*1024 + lane*8];
    const u16* vgw = &Vperm[(size_t)bh*131072 + w*1024 + lane*8];
    const int lw = w * 1024;

    // all-ones bf16 B-fragment for the row-sum MFMA
    u32x4 onesw = {0x3F803F80u, 0x3F803F80u, 0x3F803F80u, 0x3F803F80u};
    const bf16x8 ones = *(bf16x8*)&onesw;

    // prologue: stage tile 0 into buffer 0
    glds16(kgw,       &Kl[0][lw]);
    glds16(kgw + 512, &Kl[0][lw + 512]);
    glds16(vgw,       &Vl[0][lw]);
    glds16(vgw + 512, &Vl[0][lw + 512]);

    f32x4 o[2] = {};
    f32x4 osum = {};
    __syncthreads();

    for (int tt = 0; tt < NN/KVB; ++tt) {
        const int cur = tt & 1;
        if (tt < NN/KVB - 1) {                 // async-stage tile tt+1
            const u16* kg = kgw + (size_t)(tt+1)*4096;
            const u16* vg = vgw + (size_t)(tt+1)*4096;
            glds16(kg,       &Kl[cur^1][lw]);
            glds16(kg + 512, &Kl[cur^1][lw + 512]);
            glds16(vg,       &Vl[cur^1][lw]);
            glds16(vg + 512, &Vl[cur^1][lw + 512]);
        }
        // S^T = K Q^T : lane -> q = lrow, keys nf*16 + g*4 + jj
        f32x4 s[8];
#pragma unroll
        for (int nf = 0; nf < 8; ++nf) {
            bf16x8 kf = *(const bf16x8*)&Kl[cur][nf*512 + lane*8];
            f32x4 z = {};
            s[nf] = __builtin_amdgcn_mfma_f32_16x16x32_bf16(kf, qf, z, 0, 0, 0);
        }
        // softmax + PV + MFMA row-sum per 32-key block kk
#pragma unroll
        for (int kk = 0; kk < 4; ++kk) {
            float p0[4], p1[4];
#pragma unroll
            for (int jj = 0; jj < 4; ++jj) {
                p0[jj] = __builtin_amdgcn_exp2f(s[2*kk][jj]);
                p1[jj] = __builtin_amdgcn_exp2f(s[2*kk+1][jj]);
            }
            u32x4 paw;
            paw[0] = cvt_pk_bf16(p0[0], p0[1]);
            paw[1] = cvt_pk_bf16(p0[2], p0[3]);
            paw[2] = cvt_pk_bf16(p1[0], p1[1]);
            paw[3] = cvt_pk_bf16(p1[2], p1[3]);
            bf16x8 pa = *(bf16x8*)&paw;
#pragma unroll
            for (int hf = 0; hf < 2; ++hf) {
                bf16x8 vf = *(const bf16x8*)&Vl[cur][kk*1024 + hf*512 + lane*8];
                o[hf] = __builtin_amdgcn_mfma_f32_16x16x32_bf16(pa, vf, o[hf], 0, 0, 0);
            }
            osum = __builtin_amdgcn_mfma_f32_16x16x32_bf16(pa, ones, osum, 0, 0, 0);
        }
        __syncthreads();   // waves done reading cur; staged tt+1 landed (vmcnt drain)
    }
    // normalization: osum[r] = rowsum for q = g*4 + r -- same mapping as o
    const int b = bh >> 3, h = bh & 7;
#pragma unroll
    for (int hf = 0; hf < 2; ++hf)
#pragma unroll
        for (int r = 0; r < 4; ++r) {
            int q = q0 + w*16 + g*4 + r;
            int d = h*HDD + hf*16 + lrow;
            Op[((size_t)b*NN + q)*DD + d] = f2bf(o[hf][r] / osum[r]);
        }
}

// ---------------------------------------------------------------------------
// LayerNorm1: y (8192x256 f32) -> x f32 and x bf16. One wave per row.
// ---------------------------------------------------------------------------
__global__ __launch_bounds__(256) void ln_fuse(const float* __restrict__ y,
    const float* __restrict__ g, const float* __restrict__ be,
    float* __restrict__ x, u16* __restrict__ xb)
{
    const int row = blockIdx.x * 4 + (threadIdx.x >> 6);
    const int lane = threadIdx.x & 63;
    const float4 v = *(const float4*)&y[(size_t)row*DD + lane*4];
    float s1 = v.x + v.y + v.z + v.w;
    float s2 = v.x*v.x + v.y*v.y + v.z*v.z + v.w*v.w;
#pragma unroll
    for (int m = 1; m <= 32; m <<= 1) { s1 += __shfl_xor(s1, m); s2 += __shfl_xor(s2, m); }
    float mean = s1 * (1.f/DD);
    float var  = s2 * (1.f/DD) - mean*mean;
    float rstd = rsqrtf(var + 1e-5f);
    const float vv[4] = {v.x, v.y, v.z, v.w};
    float4 xo; us4 xo16;
#pragma unroll
    for (int i = 0; i < 4; ++i) {
        int d = lane*4 + i;
        float r = (vv[i] - mean) * rstd * g[d] + be[d];
        ((float*)&xo)[i] = r;
        xo16[i] = f2bf(r);
    }
    *(float4*)&x[(size_t)row*DD + lane*4] = xo;
    *(us4*)&xb[(size_t)row*DD + lane*4] = xo16;
}

// ---------------------------------------------------------------------------
// LayerNorm2 + transpose to (B, D, H*W). 32 tokens per block via LDS tile.
// ---------------------------------------------------------------------------
__global__ __launch_bounds__(256) void ln2_transpose(const float* __restrict__ z,
    const float* __restrict__ g, const float* __restrict__ be,
    float* __restrict__ out)
{
    __shared__ float tile[32][257];
    const int n0 = blockIdx.x * 32;
    const int b = blockIdx.y;
    const int t = threadIdx.x, lane = t & 63, w = t >> 6;
    for (int r8 = 0; r8 < 8; ++r8) {
        int r = w*8 + r8;
        const float4 v = *(const float4*)&z[((size_t)b*NN + n0 + r)*DD + lane*4];
        float s1 = v.x + v.y + v.z + v.w;
        float s2 = v.x*v.x + v.y*v.y + v.z*v.z + v.w*v.w;
#pragma unroll
        for (int m = 1; m <= 32; m <<= 1) { s1 += __shfl_xor(s1, m); s2 += __shfl_xor(s2, m); }
        float mean = s1 * (1.f/DD);
        float var  = s2 * (1.f/DD) - mean*mean;
        float rstd = rsqrtf(var + 1e-5f);
        const float vv[4] = {v.x, v.y, v.z, v.w};
#pragma unroll
        for (int i = 0; i < 4; ++i) {
            int d = lane*4 + i;
            tile[r][d] = (vv[i] - mean)*rstd*g[d] + be[d];
        }
    }
    __syncthreads();
    const int n = t & 31, dg = t >> 5;
    for (int dd = 0; dd < 32; ++dd) {
        int d = dd*8 + dg;
        out[((size_t)b*DD + d)*NN + n0 + n] = tile[n][d];
    }
}

// ---------------------------------------------------------------------------
extern "C" void kernel_launch(void* const* d_in, const int* in_sizes, int n_in,
                              void* d_out, int out_size, void* d_ws, size_t ws_size,
                              hipStream_t stream)
{
    const float* F_lidar = (const float*)d_in[0];
    const float* F_cam   = (const float*)d_in[1];
    const float* Wq  = (const float*)d_in[2];
    const float* Wk  = (const float*)d_in[3];
    const float* Wv  = (const float*)d_in[4];
    const float* Wo  = (const float*)d_in[5];
    const float* Wrs = (const float*)d_in[6];
    const float* g1  = (const float*)d_in[7];
    const float* b1  = (const float*)d_in[8];
    const float* g2  = (const float*)d_in[9];
    const float* b2  = (const float*)d_in[10];
    const float* W1  = (const float*)d_in[11];
    const float* bf1 = (const float*)d_in[12];
    const float* W2  = (const float*)d_in[13];
    const float* bf2 = (const float*)d_in[14];
    float* out = (float*)d_out;

    char* ws = (char*)d_ws;
    size_t cur = 0;
    auto carve = [&](size_t bytes) {
        size_t o = cur; cur += (bytes + 255) & ~(size_t)255; return (void*)(ws + o);
    };
    u16* wb    = (u16*)carve(753664u * 2);
    u16* xl    = (u16*)carve((size_t)MTOT * C1 * 2);
    u16* xc    = (u16*)carve((size_t)MTOT * C2 * 2);
    u16* Qb    = (u16*)carve((size_t)MTOT * DD * 2);
    u16* Kperm = (u16*)carve((size_t)MTOT * DD * 2);
    u16* Vperm = (u16*)carve((size_t)MTOT * DD * 2);
    float* resid = (float*)carve((size_t)MTOT * DD * 4);
    u16* attn  = (u16*)carve((size_t)MTOT * DD * 2);
    float* y   = (float*)carve((size_t)MTOT * DD * 4);
    float* x   = (float*)carve((size_t)MTOT * DD * 4);
    u16* xb    = (u16*)carve((size_t)MTOT * DD * 2);
    u16* hdn   = (u16*)carve((size_t)MTOT * FF * 2);
    float* zb  = y;   // reuse: y consumed by ln_fuse before FFN2 writes z

    u16* Wqb  = wb;
    u16* Wkb  = wb + 16384;
    u16* Wvb  = wb + 81920;
    u16* Wob  = wb + 147456;
    u16* Wrsb = wb + 212992;
    u16* W1b  = wb + 229376;
    u16* W2b  = wb + 491520;

    wconv<<<2944, 256, 0, stream>>>(Wq, Wk, Wv, Wo, Wrs, W1, W2, wb);
    tconv<<<dim3(64, 1, NB), 256, 0, stream>>>(F_lidar, xl, C1);
    tconv<<<dim3(64, 4, NB), 256, 0, stream>>>(F_cam, xc, C2);

    // softmax scale and log2(e) folded into Q
    const float qscale = 1.4426950408889634f / sqrtf((float)HDD);
    gemm_bt<0><<<dim3(64, 2), 256, 0, stream>>>(xl, Wqb, MTOT, DD, C1, nullptr, nullptr, nullptr, Qb, qscale);
    // K -> fragment-permuted layout (MODE 6)
    gemm_bt<6><<<dim3(64, 2), 256, 0, stream>>>(xc, Wkb, MTOT, DD, C2, nullptr, nullptr, nullptr, Kperm, 1.f);
    // V^T = Wv * xc^T  (A = Wv 256x256, B = xc 8192x256) -> fragment-permuted
    gemm_bt<5><<<dim3(2, 64), 256, 0, stream>>>(Wvb, xc, DD, MTOT, C2, nullptr, nullptr, nullptr, Vperm, 1.f);
    gemm_bt<1><<<dim3(64, 2), 256, 0, stream>>>(xl, Wrsb, MTOT, DD, C1, nullptr, nullptr, resid, nullptr, 1.f);

    flash_attn<<<1024, 256, 0, stream>>>(Qb, Kperm, Vperm, attn);

    gemm_bt<2><<<dim3(64, 2), 256, 0, stream>>>(attn, Wob, MTOT, DD, DD, nullptr, resid, y, nullptr, 1.f);
    ln_fuse<<<2048, 256, 0, stream>>>(y, g1, b1, x, xb);
    gemm_bt<3><<<dim3(64, 8), 256, 0, stream>>>(xb, W1b, MTOT, FF, DD, bf1, nullptr, nullptr, hdn, 1.f);
    gemm_bt<4><<<dim3(64, 2), 256, 0, stream>>>(hdn, W2b, MTOT, DD, FF, bf2, x, zb, nullptr, 1.f);
    ln2_transpose<<<dim3(128, NB), 256, 0, stream>>>(zb, g2, b2, out);
}

// Round 9
// 145.736 us; speedup vs baseline: 1.4225x; 1.0807x over previous
//
#include <hip/hip_runtime.h>
#include <hip/hip_bf16.h>
#include <math.h>

#define NB 2
#define C1 64
#define C2 256
#define DD 256
#define NHH 8
#define HDD 32
#define NN 4096
#define FF 1024
#define MTOT (NB*NN)   // 8192 tokens
#define KVB 128

typedef unsigned short u16;
typedef __attribute__((ext_vector_type(8))) short bf16x8;
typedef __attribute__((ext_vector_type(4))) float f32x4;
typedef __attribute__((ext_vector_type(4))) unsigned short us4;
typedef __attribute__((ext_vector_type(4))) unsigned int u32x4;

__device__ __forceinline__ u16 f2bf(float f) {
    union { float f; unsigned int i; } u; u.f = f;
    unsigned int r = u.i + 0x7FFFu + ((u.i >> 16) & 1u);
    return (u16)(r >> 16);
}

__device__ __forceinline__ unsigned cvt_pk_bf16(float a, float b) {
    unsigned r; asm("v_cvt_pk_bf16_f32 %0, %1, %2" : "=v"(r) : "v"(a), "v"(b)); return r;
}

// async global->LDS, 16B per lane: dst = (uniform base) + lane*16, src per-lane
__device__ __forceinline__ void glds16(const void* g, void* l) {
    __builtin_amdgcn_global_load_lds(
        (__attribute__((address_space(1))) void*)g,
        (__attribute__((address_space(3))) void*)l, 16, 0, 0);
}

// ---------------------------------------------------------------------------
// Weight f32 -> bf16, packed layout (elems):
//  [Wq 16384][Wres 16384][Wk 65536][Wv 65536][Wo 65536][W1 262144][W2 262144]
//  -> [Wq;Wres] is the fused Q+resid B (512x64); [Wk;Wv] the fused KV B (512x256)
// ---------------------------------------------------------------------------
__global__ __launch_bounds__(256) void wconv(
    const float* __restrict__ Wq, const float* __restrict__ Wres,
    const float* __restrict__ Wk, const float* __restrict__ Wv,
    const float* __restrict__ Wo, const float* __restrict__ W1,
    const float* __restrict__ W2, u16* __restrict__ d)
{
    int i = blockIdx.x * 256 + threadIdx.x;
    if (i >= 753664) return;
    const float* s; int off;
    if      (i <  16384) { s = Wq;   off = i; }
    else if (i <  32768) { s = Wres; off = i -  16384; }
    else if (i <  98304) { s = Wk;   off = i -  32768; }
    else if (i < 163840) { s = Wv;   off = i -  98304; }
    else if (i < 229376) { s = Wo;   off = i - 163840; }
    else if (i < 491520) { s = W1;   off = i - 229376; }
    else                 { s = W2;   off = i - 491520; }
    d[i] = f2bf(s[off]);
}

// ---------------------------------------------------------------------------
// (B, C, N) f32  ->  (B, N, C) bf16   (channels-first to token-major)
// ---------------------------------------------------------------------------
__global__ __launch_bounds__(256) void tconv(const float* __restrict__ src,
                                             u16* __restrict__ dst, int C)
{
    __shared__ float tile[64][65];
    const int n0 = blockIdx.x * 64;
    const int c0 = blockIdx.y * 64;
    const int b  = blockIdx.z;
    const int t  = threadIdx.x;
#pragma unroll
    for (int i = 0; i < 4; ++i) {
        int cc = t + i * 256;
        int c = cc >> 4, off = (cc & 15) * 4;
        const float4 v = *(const float4*)&src[((size_t)b*C + c0 + c)*NN + n0 + off];
        tile[c][off+0] = v.x; tile[c][off+1] = v.y;
        tile[c][off+2] = v.z; tile[c][off+3] = v.w;
    }
    __syncthreads();
    const int n = t >> 2, cch = (t & 3) * 16;
    bf16x8 t0, t1;
#pragma unroll
    for (int i = 0; i < 8; ++i) ((u16*)&t0)[i] = f2bf(tile[cch + i][n]);
#pragma unroll
    for (int i = 0; i < 8; ++i) ((u16*)&t1)[i] = f2bf(tile[cch + 8 + i][n]);
    u16* dp = &dst[((size_t)b*NN + n0 + n)*C + c0 + cch];
    *(bf16x8*)&dp[0] = t0;
    *(bf16x8*)&dp[8] = t1;
}

// ---------------------------------------------------------------------------
// C = A * B^T  (A: M x K row-major bf16, B: N x K row-major bf16)
// m97 structure: 128x128 tile, linear [128][32] LDS via global_load_lds x16B,
// 4 waves (2x2 of 64x64), 16x16x32 bf16 MFMA, BK=32, 2 barriers/K-step.
// Epilogues:
//  0: f32 = acc + add[idx]              (Wo out + resid)
//  1: bf16 relu(acc + bias[col])        (FFN1)
//  2: f32 = acc + bias[col] + add[idx]  (FFN2 + skip)
//  3: fused KV: col<256 -> Kperm scatter (outb); col>=256 -> Vperm scatter (outf cast)
//  4: fused Q+resid: col<256 -> Q (b,h,n,hd)*scale (outb); col>=256 -> resid f32 (outf)
// ---------------------------------------------------------------------------
template<int MODE>
__global__ __launch_bounds__(256) void gemm_bt(
    const u16* __restrict__ A, const u16* __restrict__ Bw,
    int M, int N, int K,
    const float* __restrict__ bias, const float* __restrict__ add,
    float* __restrict__ outf, u16* __restrict__ outb, float scale)
{
    __shared__ u16 lA[128*32];
    __shared__ u16 lB[128*32];
    const int bm = blockIdx.x * 128;
    const int bn = blockIdx.y * 128;
    const int t = threadIdx.x, lane = t & 63, wid = t >> 6;
    const int wr = (wid >> 1) * 64, wc = (wid & 1) * 64;
    const int lrow = lane & 15, lk = (lane >> 4) * 8;
    // staging: wave stages rows [wid*32, wid*32+32); lane -> row wid*32+lane/4,
    // 16B chunk (lane&3)*8 elems. Two glds16 per matrix per K-step.
    const int srow = wid*32 + (lane >> 2);
    const int soff = (lane & 3) * 8;
    const u16* aS = &A[(size_t)(bm + srow)*K + soff];
    const u16* bS = &Bw[(size_t)(bn + srow)*K + soff];
    u16* aL = &lA[wid*1024];
    u16* bL = &lB[wid*1024];
    f32x4 acc[4][4] = {};
    for (int k0 = 0; k0 < K; k0 += 32) {
        glds16(aS + k0,                  aL);
        glds16(aS + (size_t)16*K + k0,   aL + 512);
        glds16(bS + k0,                  bL);
        glds16(bS + (size_t)16*K + k0,   bL + 512);
        __syncthreads();   // implicit vmcnt drain -> staged data visible
        bf16x8 af[4], bfr[4];
#pragma unroll
        for (int mf = 0; mf < 4; ++mf)
            af[mf] = *(const bf16x8*)&lA[(wr + mf*16 + lrow)*32 + lk];
#pragma unroll
        for (int nf = 0; nf < 4; ++nf)
            bfr[nf] = *(const bf16x8*)&lB[(wc + nf*16 + lrow)*32 + lk];
#pragma unroll
        for (int mf = 0; mf < 4; ++mf)
#pragma unroll
            for (int nf = 0; nf < 4; ++nf)
                acc[mf][nf] = __builtin_amdgcn_mfma_f32_16x16x32_bf16(af[mf], bfr[nf], acc[mf][nf], 0, 0, 0);
        __syncthreads();   // all waves done reading before next stage
    }
#pragma unroll
    for (int mf = 0; mf < 4; ++mf) {
#pragma unroll
        for (int nf = 0; nf < 4; ++nf) {
#pragma unroll
            for (int j = 0; j < 4; ++j) {
                int row = bm + wr + mf*16 + (lane >> 4)*4 + j;
                int col = bn + wc + nf*16 + lrow;
                float v = acc[mf][nf][j];
                if (MODE == 0) {
                    size_t idx = (size_t)row*N + col;
                    outf[idx] = v + add[idx];
                } else if (MODE == 1) {
                    float r = v + bias[col];
                    outb[(size_t)row*N + col] = f2bf(r > 0.f ? r : 0.f);
                } else if (MODE == 2) {
                    size_t idx = (size_t)row*N + col;
                    outf[idx] = v + bias[col] + add[idx];
                } else if (MODE == 3) {
                    int b = row >> 12, n = row & 4095;
                    if (col < 256) {
                        // K fragment-permuted: [bh][n>>4][ (hd>>3)*16 + (n&15) ][hd&7]
                        int h = col >> 5, hd = col & 31;
                        int bh = b*NHH + h;
                        size_t idx = (((size_t)bh*256 + (n >> 4))*64
                                      + (hd >> 3)*16 + (n & 15))*8 + (hd & 7);
                        outb[idx] = f2bf(v);
                    } else {
                        // V fragment-permuted: [bh][kb][hf][gg*16+d][hp*4+r]
                        int c = col - 256;
                        int h = c >> 5, hd = c & 31;
                        int hf = hd >> 4, d = hd & 15;
                        int bh = b*NHH + h;
                        int kb = n >> 5, kwb = n & 31;
                        int hp = kwb >> 4, gg = (kwb >> 2) & 3, r = kwb & 3;
                        size_t idx = ((((size_t)bh*128 + kb)*2 + hf)*64 + gg*16 + d)*8
                                   + hp*4 + r;
                        ((u16*)outf)[idx] = f2bf(v);
                    }
                } else {
                    int b = row >> 12, n = row & 4095;
                    if (col < 256) {
                        int h = col >> 5, hd = col & 31;
                        outb[(((size_t)b*NHH + h)*NN + n)*HDD + hd] = f2bf(v * scale);
                    } else {
                        outf[(size_t)row*DD + (col - 256)] = v;
                    }
                }
            }
        }
    }
}

// ---------------------------------------------------------------------------
// Flash attention v9: LDS double-buffered K/V via global_load_lds, both
// fragment-linear in global (every LDS read = lane*16B, conflict-free).
// KV loop manually unrolled x2 so the buffer index is compile-time.
// - no-max base-2 softmax via v_exp_f32 (scale+log2e folded into Q)
// - swapped QK^T (lane-local softmax rows); PV A-frag = lane's own P (cvt_pk)
// - rowsum via MFMA vs all-ones B (lane mapping matches o; no shuffles)
// - block = 4 waves x 16 q; 1024 blocks; XCD swizzle (2 (b,h) per XCD)
// ---------------------------------------------------------------------------
__global__ __launch_bounds__(256) void flash_attn(
    const u16* __restrict__ Qp, const u16* __restrict__ Kperm,
    const u16* __restrict__ Vperm, u16* __restrict__ Op)
{
    __shared__ u16 Kl[2][4096];   // [b16 8][lane 64][8]
    __shared__ u16 Vl[2][4096];   // [kb 4][hf 2][lane 64][8]
    const int id = blockIdx.x;                 // 0..1023
    const int sw = (id & 7) * 128 + (id >> 3); // XCD-grouped
    const int qt = sw & 63;
    const int bh = sw >> 6;                    // b*8 + h
    const size_t base = (size_t)bh * NN * HDD; // Q (b,h,n,hd)
    const int t = threadIdx.x, lane = t & 63, w = t >> 6;
    const int q0 = qt * 64;
    const int lrow = lane & 15, g = lane >> 4;

    const bf16x8 qf = *(const bf16x8*)&Qp[base + (size_t)(q0 + w*16 + lrow)*HDD + g*8];

    const u16* kgw = &Kperm[(size_t)bh*131072 + w*1024 + lane*8];
    const u16* vgw = &Vperm[(size_t)bh*131072 + w*1024 + lane*8];
    const int lw = w * 1024;

    u32x4 onesw = {0x3F803F80u, 0x3F803F80u, 0x3F803F80u, 0x3F803F80u};
    const bf16x8 ones = *(bf16x8*)&onesw;

    // prologue: stage tile 0 into buffer 0
    glds16(kgw,       &Kl[0][lw]);
    glds16(kgw + 512, &Kl[0][lw + 512]);
    glds16(vgw,       &Vl[0][lw]);
    glds16(vgw + 512, &Vl[0][lw + 512]);

    f32x4 o[2] = {};
    f32x4 osum = {};
    __syncthreads();

#define FLASH_STEP(CUR, TT)                                                    \
    {                                                                          \
        if ((TT) < 31) {                                                       \
            const u16* kg = kgw + (size_t)((TT)+1)*4096;                       \
            const u16* vg = vgw + (size_t)((TT)+1)*4096;                       \
            glds16(kg,       &Kl[(CUR)^1][lw]);                                \
            glds16(kg + 512, &Kl[(CUR)^1][lw + 512]);                          \
            glds16(vg,       &Vl[(CUR)^1][lw]);                                \
            glds16(vg + 512, &Vl[(CUR)^1][lw + 512]);                          \
        }                                                                      \
        f32x4 s[8];                                                            \
        _Pragma("unroll")                                                      \
        for (int nf = 0; nf < 8; ++nf) {                                       \
            bf16x8 kf = *(const bf16x8*)&Kl[(CUR)][nf*512 + lane*8];           \
            f32x4 z = {};                                                      \
            s[nf] = __builtin_amdgcn_mfma_f32_16x16x32_bf16(kf, qf, z, 0, 0, 0); \
        }                                                                      \
        _Pragma("unroll")                                                      \
        for (int kk = 0; kk < 4; ++kk) {                                       \
            float p0[4], p1[4];                                                \
            _Pragma("unroll")                                                  \
            for (int jj = 0; jj < 4; ++jj) {                                   \
                p0[jj] = __builtin_amdgcn_exp2f(s[2*kk][jj]);                  \
                p1[jj] = __builtin_amdgcn_exp2f(s[2*kk+1][jj]);                 \
            }                                                                  \
            u32x4 paw;                                                         \
            paw[0] = cvt_pk_bf16(p0[0], p0[1]);                                \
            paw[1] = cvt_pk_bf16(p0[2], p0[3]);                                \
            paw[2] = cvt_pk_bf16(p1[0], p1[1]);                                \
            paw[3] = cvt_pk_bf16(p1[2], p1[3]);                                \
            bf16x8 pa = *(bf16x8*)&paw;                                        \
            _Pragma("unroll")                                                  \
            for (int hf = 0; hf < 2; ++hf) {                                   \
                bf16x8 vf = *(const bf16x8*)&Vl[(CUR)][kk*1024 + hf*512 + lane*8]; \
                o[hf] = __builtin_amdgcn_mfma_f32_16x16x32_bf16(pa, vf, o[hf], 0, 0, 0); \
            }                                                                  \
            osum = __builtin_amdgcn_mfma_f32_16x16x32_bf16(pa, ones, osum, 0, 0, 0); \
        }                                                                      \
        __syncthreads();                                                       \
    }

    for (int tt = 0; tt < 32; tt += 2) {
        FLASH_STEP(0, tt)
        FLASH_STEP(1, tt + 1)
    }
#undef FLASH_STEP

    // normalization: osum[r] = rowsum for q = g*4 + r -- same mapping as o
    const int b = bh >> 3, h = bh & 7;
#pragma unroll
    for (int hf = 0; hf < 2; ++hf)
#pragma unroll
        for (int r = 0; r < 4; ++r) {
            int q = q0 + w*16 + g*4 + r;
            int d = h*HDD + hf*16 + lrow;
            Op[((size_t)b*NN + q)*DD + d] = f2bf(o[hf][r] / osum[r]);
        }
}

// ---------------------------------------------------------------------------
// LayerNorm1: y (8192x256 f32) -> x f32 and x bf16. One wave per row.
// ---------------------------------------------------------------------------
__global__ __launch_bounds__(256) void ln_fuse(const float* __restrict__ y,
    const float* __restrict__ g, const float* __restrict__ be,
    float* __restrict__ x, u16* __restrict__ xb)
{
    const int row = blockIdx.x * 4 + (threadIdx.x >> 6);
    const int lane = threadIdx.x & 63;
    const float4 v = *(const float4*)&y[(size_t)row*DD + lane*4];
    float s1 = v.x + v.y + v.z + v.w;
    float s2 = v.x*v.x + v.y*v.y + v.z*v.z + v.w*v.w;
#pragma unroll
    for (int m = 1; m <= 32; m <<= 1) { s1 += __shfl_xor(s1, m); s2 += __shfl_xor(s2, m); }
    float mean = s1 * (1.f/DD);
    float var  = s2 * (1.f/DD) - mean*mean;
    float rstd = rsqrtf(var + 1e-5f);
    const float vv[4] = {v.x, v.y, v.z, v.w};
    float4 xo; us4 xo16;
#pragma unroll
    for (int i = 0; i < 4; ++i) {
        int d = lane*4 + i;
        float r = (vv[i] - mean) * rstd * g[d] + be[d];
        ((float*)&xo)[i] = r;
        xo16[i] = f2bf(r);
    }
    *(float4*)&x[(size_t)row*DD + lane*4] = xo;
    *(us4*)&xb[(size_t)row*DD + lane*4] = xo16;
}

// ---------------------------------------------------------------------------
// LayerNorm2 + transpose to (B, D, H*W). 32 tokens per block via LDS tile.
// ---------------------------------------------------------------------------
__global__ __launch_bounds__(256) void ln2_transpose(const float* __restrict__ z,
    const float* __restrict__ g, const float* __restrict__ be,
    float* __restrict__ out)
{
    __shared__ float tile[32][257];
    const int n0 = blockIdx.x * 32;
    const int b = blockIdx.y;
    const int t = threadIdx.x, lane = t & 63, w = t >> 6;
    for (int r8 = 0; r8 < 8; ++r8) {
        int r = w*8 + r8;
        const float4 v = *(const float4*)&z[((size_t)b*NN + n0 + r)*DD + lane*4];
        float s1 = v.x + v.y + v.z + v.w;
        float s2 = v.x*v.x + v.y*v.y + v.z*v.z + v.w*v.w;
#pragma unroll
        for (int m = 1; m <= 32; m <<= 1) { s1 += __shfl_xor(s1, m); s2 += __shfl_xor(s2, m); }
        float mean = s1 * (1.f/DD);
        float var  = s2 * (1.f/DD) - mean*mean;
        float rstd = rsqrtf(var + 1e-5f);
        const float vv[4] = {v.x, v.y, v.z, v.w};
#pragma unroll
        for (int i = 0; i < 4; ++i) {
            int d = lane*4 + i;
            tile[r][d] = (vv[i] - mean)*rstd*g[d] + be[d];
        }
    }
    __syncthreads();
    const int n = t & 31, dg = t >> 5;
    for (int dd = 0; dd < 32; ++dd) {
        int d = dd*8 + dg;
        out[((size_t)b*DD + d)*NN + n0 + n] = tile[n][d];
    }
}

// ---------------------------------------------------------------------------
extern "C" void kernel_launch(void* const* d_in, const int* in_sizes, int n_in,
                              void* d_out, int out_size, void* d_ws, size_t ws_size,
                              hipStream_t stream)
{
    const float* F_lidar = (const float*)d_in[0];
    const float* F_cam   = (const float*)d_in[1];
    const float* Wq  = (const float*)d_in[2];
    const float* Wk  = (const float*)d_in[3];
    const float* Wv  = (const float*)d_in[4];
    const float* Wo  = (const float*)d_in[5];
    const float* Wrs = (const float*)d_in[6];
    const float* g1  = (const float*)d_in[7];
    const float* b1  = (const float*)d_in[8];
    const float* g2  = (const float*)d_in[9];
    const float* b2  = (const float*)d_in[10];
    const float* W1  = (const float*)d_in[11];
    const float* bf1 = (const float*)d_in[12];
    const float* W2  = (const float*)d_in[13];
    const float* bf2 = (const float*)d_in[14];
    float* out = (float*)d_out;

    char* ws = (char*)d_ws;
    size_t cur = 0;
    auto carve = [&](size_t bytes) {
        size_t o = cur; cur += (bytes + 255) & ~(size_t)255; return (void*)(ws + o);
    };
    u16* wb    = (u16*)carve(753664u * 2);
    u16* xl    = (u16*)carve((size_t)MTOT * C1 * 2);
    u16* xc    = (u16*)carve((size_t)MTOT * C2 * 2);
    u16* Qb    = (u16*)carve((size_t)MTOT * DD * 2);
    u16* Kperm = (u16*)carve((size_t)MTOT * DD * 2);
    u16* Vperm = (u16*)carve((size_t)MTOT * DD * 2);
    float* resid = (float*)carve((size_t)MTOT * DD * 4);
    u16* attn  = (u16*)carve((size_t)MTOT * DD * 2);
    float* y   = (float*)carve((size_t)MTOT * DD * 4);
    float* x   = (float*)carve((size_t)MTOT * DD * 4);
    u16* xb    = (u16*)carve((size_t)MTOT * DD * 2);
    u16* hdn   = (u16*)carve((size_t)MTOT * FF * 2);
    float* zb  = y;   // reuse: y consumed by ln_fuse before FFN2 writes z

    // packed weight layout (elems)
    u16* WqRes = wb;             // [Wq;Wres] 512 x 64
    u16* WkWv  = wb + 32768;     // [Wk;Wv]   512 x 256
    u16* Wob   = wb + 163840;    // 256 x 256
    u16* W1b   = wb + 229376;    // 1024 x 256
    u16* W2b   = wb + 491520;    // 256 x 1024

    wconv<<<2944, 256, 0, stream>>>(Wq, Wrs, Wk, Wv, Wo, W1, W2, wb);
    tconv<<<dim3(64, 1, NB), 256, 0, stream>>>(F_lidar, xl, C1);
    tconv<<<dim3(64, 4, NB), 256, 0, stream>>>(F_cam, xc, C2);

    // softmax scale and log2(e) folded into Q
    const float qscale = 1.4426950408889634f / sqrtf((float)HDD);
    // fused Q + resid (N=512, 256 blocks)
    gemm_bt<4><<<dim3(64, 4), 256, 0, stream>>>(xl, WqRes, MTOT, 512, C1,
        nullptr, nullptr, resid, Qb, qscale);
    // fused K + V -> fragment-permuted buffers (N=512, 256 blocks)
    gemm_bt<3><<<dim3(64, 4), 256, 0, stream>>>(xc, WkWv, MTOT, 512, C2,
        nullptr, nullptr, (float*)Vperm, Kperm, 1.f);

    flash_attn<<<1024, 256, 0, stream>>>(Qb, Kperm, Vperm, attn);

    gemm_bt<0><<<dim3(64, 2), 256, 0, stream>>>(attn, Wob, MTOT, DD, DD,
        nullptr, resid, y, nullptr, 1.f);
    ln_fuse<<<2048, 256, 0, stream>>>(y, g1, b1, x, xb);
    gemm_bt<1><<<dim3(64, 8), 256, 0, stream>>>(xb, W1b, MTOT, FF, DD,
        bf1, nullptr, nullptr, hdn, 1.f);
    gemm_bt<2><<<dim3(64, 2), 256, 0, stream>>>(hdn, W2b, MTOT, DD, FF,
        bf2, x, zb, nullptr, 1.f);
    ln2_transpose<<<dim3(128, NB), 256, 0, stream>>>(zb, g2, b2, out);
}

// Round 10
// 141.214 us; speedup vs baseline: 1.4680x; 1.0320x over previous
//
#include <hip/hip_runtime.h>
#include <hip/hip_bf16.h>
#include <math.h>

#define NB 2
#define C1 64
#define C2 256
#define DD 256
#define NHH 8
#define HDD 32
#define NN 4096
#define FF 1024
#define MTOT (NB*NN)   // 8192 tokens
#define KVB 128

typedef unsigned short u16;
typedef __attribute__((ext_vector_type(8))) short bf16x8;
typedef __attribute__((ext_vector_type(4))) float f32x4;
typedef __attribute__((ext_vector_type(4))) unsigned short us4;
typedef __attribute__((ext_vector_type(4))) unsigned int u32x4;

__device__ __forceinline__ u16 f2bf(float f) {
    union { float f; unsigned int i; } u; u.f = f;
    unsigned int r = u.i + 0x7FFFu + ((u.i >> 16) & 1u);
    return (u16)(r >> 16);
}

__device__ __forceinline__ unsigned cvt_pk_bf16(float a, float b) {
    unsigned r; asm("v_cvt_pk_bf16_f32 %0, %1, %2" : "=v"(r) : "v"(a), "v"(b)); return r;
}

// async global->LDS, 16B per lane: dst = (uniform base) + lane*16, src per-lane
__device__ __forceinline__ void glds16(const void* g, void* l) {
    __builtin_amdgcn_global_load_lds(
        (__attribute__((address_space(1))) void*)g,
        (__attribute__((address_space(3))) void*)l, 16, 0, 0);
}

// ---------------------------------------------------------------------------
// Weight f32 -> bf16, packed layout (elems):
//  [Wq 16384][Wres 16384][Wk 65536][Wv 65536][Wo 65536][W1 262144][W2 262144]
// ---------------------------------------------------------------------------
__global__ __launch_bounds__(256) void wconv(
    const float* __restrict__ Wq, const float* __restrict__ Wres,
    const float* __restrict__ Wk, const float* __restrict__ Wv,
    const float* __restrict__ Wo, const float* __restrict__ W1,
    const float* __restrict__ W2, u16* __restrict__ d)
{
    int i = blockIdx.x * 256 + threadIdx.x;
    if (i >= 753664) return;
    const float* s; int off;
    if      (i <  16384) { s = Wq;   off = i; }
    else if (i <  32768) { s = Wres; off = i -  16384; }
    else if (i <  98304) { s = Wk;   off = i -  32768; }
    else if (i < 163840) { s = Wv;   off = i -  98304; }
    else if (i < 229376) { s = Wo;   off = i - 163840; }
    else if (i < 491520) { s = W1;   off = i - 229376; }
    else                 { s = W2;   off = i - 491520; }
    d[i] = f2bf(s[off]);
}

// ---------------------------------------------------------------------------
// (B, C, N) f32  ->  (B, N, C) bf16   (channels-first to token-major)
// ---------------------------------------------------------------------------
__global__ __launch_bounds__(256) void tconv(const float* __restrict__ src,
                                             u16* __restrict__ dst, int C)
{
    __shared__ float tile[64][65];
    const int n0 = blockIdx.x * 64;
    const int c0 = blockIdx.y * 64;
    const int b  = blockIdx.z;
    const int t  = threadIdx.x;
#pragma unroll
    for (int i = 0; i < 4; ++i) {
        int cc = t + i * 256;
        int c = cc >> 4, off = (cc & 15) * 4;
        const float4 v = *(const float4*)&src[((size_t)b*C + c0 + c)*NN + n0 + off];
        tile[c][off+0] = v.x; tile[c][off+1] = v.y;
        tile[c][off+2] = v.z; tile[c][off+3] = v.w;
    }
    __syncthreads();
    const int n = t >> 2, cch = (t & 3) * 16;
    bf16x8 t0, t1;
#pragma unroll
    for (int i = 0; i < 8; ++i) ((u16*)&t0)[i] = f2bf(tile[cch + i][n]);
#pragma unroll
    for (int i = 0; i < 8; ++i) ((u16*)&t1)[i] = f2bf(tile[cch + 8 + i][n]);
    u16* dp = &dst[((size_t)b*NN + n0 + n)*C + c0 + cch];
    *(bf16x8*)&dp[0] = t0;
    *(bf16x8*)&dp[8] = t1;
}

// ---------------------------------------------------------------------------
// C = A * B^T  (A: M x K row-major bf16, B: N x K row-major bf16)
// 128x128 tile, DOUBLE-BUFFERED linear [128][32] LDS via global_load_lds x16B
// (flash-proven structure: stage k+1 -> compute k -> one barrier/step).
// 4 waves (2x2 of 64x64), 16x16x32 bf16 MFMA, BK=32.
// Epilogues:
//  0: f32 = acc + add[idx]              (Wo out + resid)
//  1: bf16 relu(acc + bias[col])        (FFN1)
//  2: f32 = acc + bias[col] + add[idx]  (FFN2 + skip)
//  3: fused KV: col<256 -> Kperm scatter (outb); col>=256 -> Vperm (outf cast)
//  4: fused Q+resid: col<256 -> Q (b,h,n,hd)*scale (outb); col>=256 -> resid f32
// ---------------------------------------------------------------------------
template<int MODE>
__global__ __launch_bounds__(256) void gemm_bt(
    const u16* __restrict__ A, const u16* __restrict__ Bw,
    int M, int N, int K,
    const float* __restrict__ bias, const float* __restrict__ add,
    float* __restrict__ outf, u16* __restrict__ outb, float scale)
{
    __shared__ u16 lA[2][4096];
    __shared__ u16 lB[2][4096];
    const int bm = blockIdx.x * 128;
    const int bn = blockIdx.y * 128;
    const int t = threadIdx.x, lane = t & 63, wid = t >> 6;
    const int wr = (wid >> 1) * 64, wc = (wid & 1) * 64;
    const int lrow = lane & 15, lk = (lane >> 4) * 8;
    // staging: wave wid stages rows [wid*32, wid*32+32); lane -> row wid*32+lane/4,
    // 16B chunk (lane&3)*8 elems; two glds16 per matrix per K-step.
    const int srow = wid*32 + (lane >> 2);
    const int soff = (lane & 3) * 8;
    const u16* aS = &A[(size_t)(bm + srow)*K + soff];
    const u16* bS = &Bw[(size_t)(bn + srow)*K + soff];
    const int lw = wid * 1024;
    f32x4 acc[4][4] = {};

    // prologue: stage K-step 0 into buffer 0
    glds16(aS,                  &lA[0][lw]);
    glds16(aS + (size_t)16*K,   &lA[0][lw + 512]);
    glds16(bS,                  &lB[0][lw]);
    glds16(bS + (size_t)16*K,   &lB[0][lw + 512]);
    __syncthreads();   // vmcnt drain -> buffer 0 visible

    const int nst = K >> 5;
    for (int st = 0; st < nst; ++st) {
        const int cur = st & 1;
        if (st < nst - 1) {                    // async-stage K-step st+1
            const int k0 = (st + 1) * 32;
            glds16(aS + k0,                  &lA[cur^1][lw]);
            glds16(aS + (size_t)16*K + k0,   &lA[cur^1][lw + 512]);
            glds16(bS + k0,                  &lB[cur^1][lw]);
            glds16(bS + (size_t)16*K + k0,   &lB[cur^1][lw + 512]);
        }
        bf16x8 af[4], bfr[4];
#pragma unroll
        for (int mf = 0; mf < 4; ++mf)
            af[mf] = *(const bf16x8*)&lA[cur][(wr + mf*16 + lrow)*32 + lk];
#pragma unroll
        for (int nf = 0; nf < 4; ++nf)
            bfr[nf] = *(const bf16x8*)&lB[cur][(wc + nf*16 + lrow)*32 + lk];
#pragma unroll
        for (int mf = 0; mf < 4; ++mf)
#pragma unroll
            for (int nf = 0; nf < 4; ++nf)
                acc[mf][nf] = __builtin_amdgcn_mfma_f32_16x16x32_bf16(af[mf], bfr[nf], acc[mf][nf], 0, 0, 0);
        __syncthreads();   // readers done with cur; staged st+1 landed (vmcnt drain)
    }
#pragma unroll
    for (int mf = 0; mf < 4; ++mf) {
#pragma unroll
        for (int nf = 0; nf < 4; ++nf) {
#pragma unroll
            for (int j = 0; j < 4; ++j) {
                int row = bm + wr + mf*16 + (lane >> 4)*4 + j;
                int col = bn + wc + nf*16 + lrow;
                float v = acc[mf][nf][j];
                if (MODE == 0) {
                    size_t idx = (size_t)row*N + col;
                    outf[idx] = v + add[idx];
                } else if (MODE == 1) {
                    float r = v + bias[col];
                    outb[(size_t)row*N + col] = f2bf(r > 0.f ? r : 0.f);
                } else if (MODE == 2) {
                    size_t idx = (size_t)row*N + col;
                    outf[idx] = v + bias[col] + add[idx];
                } else if (MODE == 3) {
                    int b = row >> 12, n = row & 4095;
                    if (col < 256) {
                        // K fragment-permuted: [bh][n>>4][(hd>>3)*16 + (n&15)][hd&7]
                        int h = col >> 5, hd = col & 31;
                        int bh = b*NHH + h;
                        size_t idx = (((size_t)bh*256 + (n >> 4))*64
                                      + (hd >> 3)*16 + (n & 15))*8 + (hd & 7);
                        outb[idx] = f2bf(v);
                    } else {
                        // V fragment-permuted: [bh][kb][hf][gg*16+d][hp*4+r]
                        int c = col - 256;
                        int h = c >> 5, hd = c & 31;
                        int hf = hd >> 4, d = hd & 15;
                        int bh = b*NHH + h;
                        int kb = n >> 5, kwb = n & 31;
                        int hp = kwb >> 4, gg = (kwb >> 2) & 3, r = kwb & 3;
                        size_t idx = ((((size_t)bh*128 + kb)*2 + hf)*64 + gg*16 + d)*8
                                   + hp*4 + r;
                        ((u16*)outf)[idx] = f2bf(v);
                    }
                } else {
                    int b = row >> 12, n = row & 4095;
                    if (col < 256) {
                        int h = col >> 5, hd = col & 31;
                        outb[(((size_t)b*NHH + h)*NN + n)*HDD + hd] = f2bf(v * scale);
                    } else {
                        outf[(size_t)row*DD + (col - 256)] = v;
                    }
                }
            }
        }
    }
}

// ---------------------------------------------------------------------------
// Flash attention v10: LDS double-buffered K/V via global_load_lds, both
// fragment-linear in global (every LDS read = lane*16B, conflict-free).
// KV loop manually unrolled x2 (compile-time buffer index); s_setprio around
// MFMA clusters (T5).
// - no-max base-2 softmax via v_exp_f32 (scale+log2e folded into Q)
// - swapped QK^T (lane-local softmax rows); PV A-frag = lane's own P (cvt_pk)
// - rowsum via MFMA vs all-ones B (lane mapping matches o; no shuffles)
// - block = 4 waves x 16 q; 1024 blocks; XCD swizzle (2 (b,h) per XCD)
// ---------------------------------------------------------------------------
__global__ __launch_bounds__(256) void flash_attn(
    const u16* __restrict__ Qp, const u16* __restrict__ Kperm,
    const u16* __restrict__ Vperm, u16* __restrict__ Op)
{
    __shared__ u16 Kl[2][4096];   // [b16 8][lane 64][8]
    __shared__ u16 Vl[2][4096];   // [kb 4][hf 2][lane 64][8]
    const int id = blockIdx.x;                 // 0..1023
    const int sw = (id & 7) * 128 + (id >> 3); // XCD-grouped
    const int qt = sw & 63;
    const int bh = sw >> 6;                    // b*8 + h
    const size_t base = (size_t)bh * NN * HDD; // Q (b,h,n,hd)
    const int t = threadIdx.x, lane = t & 63, w = t >> 6;
    const int q0 = qt * 64;
    const int lrow = lane & 15, g = lane >> 4;

    const bf16x8 qf = *(const bf16x8*)&Qp[base + (size_t)(q0 + w*16 + lrow)*HDD + g*8];

    const u16* kgw = &Kperm[(size_t)bh*131072 + w*1024 + lane*8];
    const u16* vgw = &Vperm[(size_t)bh*131072 + w*1024 + lane*8];
    const int lw = w * 1024;

    u32x4 onesw = {0x3F803F80u, 0x3F803F80u, 0x3F803F80u, 0x3F803F80u};
    const bf16x8 ones = *(bf16x8*)&onesw;

    // prologue: stage tile 0 into buffer 0
    glds16(kgw,       &Kl[0][lw]);
    glds16(kgw + 512, &Kl[0][lw + 512]);
    glds16(vgw,       &Vl[0][lw]);
    glds16(vgw + 512, &Vl[0][lw + 512]);

    f32x4 o[2] = {};
    f32x4 osum = {};
    __syncthreads();

#define FLASH_STEP(CUR, TT)                                                    \
    {                                                                          \
        if ((TT) < 31) {                                                       \
            const u16* kg = kgw + (size_t)((TT)+1)*4096;                       \
            const u16* vg = vgw + (size_t)((TT)+1)*4096;                       \
            glds16(kg,       &Kl[(CUR)^1][lw]);                                \
            glds16(kg + 512, &Kl[(CUR)^1][lw + 512]);                          \
            glds16(vg,       &Vl[(CUR)^1][lw]);                                \
            glds16(vg + 512, &Vl[(CUR)^1][lw + 512]);                          \
        }                                                                      \
        f32x4 s[8];                                                            \
        __builtin_amdgcn_s_setprio(1);                                         \
        _Pragma("unroll")                                                      \
        for (int nf = 0; nf < 8; ++nf) {                                       \
            bf16x8 kf = *(const bf16x8*)&Kl[(CUR)][nf*512 + lane*8];           \
            f32x4 z = {};                                                      \
            s[nf] = __builtin_amdgcn_mfma_f32_16x16x32_bf16(kf, qf, z, 0, 0, 0); \
        }                                                                      \
        __builtin_amdgcn_s_setprio(0);                                         \
        _Pragma("unroll")                                                      \
        for (int kk = 0; kk < 4; ++kk) {                                       \
            float p0[4], p1[4];                                                \
            _Pragma("unroll")                                                  \
            for (int jj = 0; jj < 4; ++jj) {                                   \
                p0[jj] = __builtin_amdgcn_exp2f(s[2*kk][jj]);                  \
                p1[jj] = __builtin_amdgcn_exp2f(s[2*kk+1][jj]);                 \
            }                                                                  \
            u32x4 paw;                                                         \
            paw[0] = cvt_pk_bf16(p0[0], p0[1]);                                \
            paw[1] = cvt_pk_bf16(p0[2], p0[3]);                                \
            paw[2] = cvt_pk_bf16(p1[0], p1[1]);                                \
            paw[3] = cvt_pk_bf16(p1[2], p1[3]);                                \
            bf16x8 pa = *(bf16x8*)&paw;                                        \
            __builtin_amdgcn_s_setprio(1);                                     \
            _Pragma("unroll")                                                  \
            for (int hf = 0; hf < 2; ++hf) {                                   \
                bf16x8 vf = *(const bf16x8*)&Vl[(CUR)][kk*1024 + hf*512 + lane*8]; \
                o[hf] = __builtin_amdgcn_mfma_f32_16x16x32_bf16(pa, vf, o[hf], 0, 0, 0); \
            }                                                                  \
            osum = __builtin_amdgcn_mfma_f32_16x16x32_bf16(pa, ones, osum, 0, 0, 0); \
            __builtin_amdgcn_s_setprio(0);                                     \
        }                                                                      \
        __syncthreads();                                                       \
    }

    for (int tt = 0; tt < 32; tt += 2) {
        FLASH_STEP(0, tt)
        FLASH_STEP(1, tt + 1)
    }
#undef FLASH_STEP

    // normalization: osum[r] = rowsum for q = g*4 + r -- same mapping as o
    const int b = bh >> 3, h = bh & 7;
#pragma unroll
    for (int hf = 0; hf < 2; ++hf)
#pragma unroll
        for (int r = 0; r < 4; ++r) {
            int q = q0 + w*16 + g*4 + r;
            int d = h*HDD + hf*16 + lrow;
            Op[((size_t)b*NN + q)*DD + d] = f2bf(o[hf][r] / osum[r]);
        }
}

// ---------------------------------------------------------------------------
// LayerNorm1: y (8192x256 f32) -> x f32 and x bf16. One wave per row.
// ---------------------------------------------------------------------------
__global__ __launch_bounds__(256) void ln_fuse(const float* __restrict__ y,
    const float* __restrict__ g, const float* __restrict__ be,
    float* __restrict__ x, u16* __restrict__ xb)
{
    const int row = blockIdx.x * 4 + (threadIdx.x >> 6);
    const int lane = threadIdx.x & 63;
    const float4 v = *(const float4*)&y[(size_t)row*DD + lane*4];
    float s1 = v.x + v.y + v.z + v.w;
    float s2 = v.x*v.x + v.y*v.y + v.z*v.z + v.w*v.w;
#pragma unroll
    for (int m = 1; m <= 32; m <<= 1) { s1 += __shfl_xor(s1, m); s2 += __shfl_xor(s2, m); }
    float mean = s1 * (1.f/DD);
    float var  = s2 * (1.f/DD) - mean*mean;
    float rstd = rsqrtf(var + 1e-5f);
    const float vv[4] = {v.x, v.y, v.z, v.w};
    float4 xo; us4 xo16;
#pragma unroll
    for (int i = 0; i < 4; ++i) {
        int d = lane*4 + i;
        float r = (vv[i] - mean) * rstd * g[d] + be[d];
        ((float*)&xo)[i] = r;
        xo16[i] = f2bf(r);
    }
    *(float4*)&x[(size_t)row*DD + lane*4] = xo;
    *(us4*)&xb[(size_t)row*DD + lane*4] = xo16;
}

// ---------------------------------------------------------------------------
// LayerNorm2 + transpose to (B, D, H*W). 32 tokens per block via LDS tile.
// ---------------------------------------------------------------------------
__global__ __launch_bounds__(256) void ln2_transpose(const float* __restrict__ z,
    const float* __restrict__ g, const float* __restrict__ be,
    float* __restrict__ out)
{
    __shared__ float tile[32][257];
    const int n0 = blockIdx.x * 32;
    const int b = blockIdx.y;
    const int t = threadIdx.x, lane = t & 63, w = t >> 6;
    for (int r8 = 0; r8 < 8; ++r8) {
        int r = w*8 + r8;
        const float4 v = *(const float4*)&z[((size_t)b*NN + n0 + r)*DD + lane*4];
        float s1 = v.x + v.y + v.z + v.w;
        float s2 = v.x*v.x + v.y*v.y + v.z*v.z + v.w*v.w;
#pragma unroll
        for (int m = 1; m <= 32; m <<= 1) { s1 += __shfl_xor(s1, m); s2 += __shfl_xor(s2, m); }
        float mean = s1 * (1.f/DD);
        float var  = s2 * (1.f/DD) - mean*mean;
        float rstd = rsqrtf(var + 1e-5f);
        const float vv[4] = {v.x, v.y, v.z, v.w};
#pragma unroll
        for (int i = 0; i < 4; ++i) {
            int d = lane*4 + i;
            tile[r][d] = (vv[i] - mean)*rstd*g[d] + be[d];
        }
    }
    __syncthreads();
    const int n = t & 31, dg = t >> 5;
    for (int dd = 0; dd < 32; ++dd) {
        int d = dd*8 + dg;
        out[((size_t)b*DD + d)*NN + n0 + n] = tile[n][d];
    }
}

// ---------------------------------------------------------------------------
extern "C" void kernel_launch(void* const* d_in, const int* in_sizes, int n_in,
                              void* d_out, int out_size, void* d_ws, size_t ws_size,
                              hipStream_t stream)
{
    const float* F_lidar = (const float*)d_in[0];
    const float* F_cam   = (const float*)d_in[1];
    const float* Wq  = (const float*)d_in[2];
    const float* Wk  = (const float*)d_in[3];
    const float* Wv  = (const float*)d_in[4];
    const float* Wo  = (const float*)d_in[5];
    const float* Wrs = (const float*)d_in[6];
    const float* g1  = (const float*)d_in[7];
    const float* b1  = (const float*)d_in[8];
    const float* g2  = (const float*)d_in[9];
    const float* b2  = (const float*)d_in[10];
    const float* W1  = (const float*)d_in[11];
    const float* bf1 = (const float*)d_in[12];
    const float* W2  = (const float*)d_in[13];
    const float* bf2 = (const float*)d_in[14];
    float* out = (float*)d_out;

    char* ws = (char*)d_ws;
    size_t cur = 0;
    auto carve = [&](size_t bytes) {
        size_t o = cur; cur += (bytes + 255) & ~(size_t)255; return (void*)(ws + o);
    };
    u16* wb    = (u16*)carve(753664u * 2);
    u16* xl    = (u16*)carve((size_t)MTOT * C1 * 2);
    u16* xc    = (u16*)carve((size_t)MTOT * C2 * 2);
    u16* Qb    = (u16*)carve((size_t)MTOT * DD * 2);
    u16* Kperm = (u16*)carve((size_t)MTOT * DD * 2);
    u16* Vperm = (u16*)carve((size_t)MTOT * DD * 2);
    float* resid = (float*)carve((size_t)MTOT * DD * 4);
    u16* attn  = (u16*)carve((size_t)MTOT * DD * 2);
    float* y   = (float*)carve((size_t)MTOT * DD * 4);
    float* x   = (float*)carve((size_t)MTOT * DD * 4);
    u16* xb    = (u16*)carve((size_t)MTOT * DD * 2);
    u16* hdn   = (u16*)carve((size_t)MTOT * FF * 2);
    float* zb  = y;   // reuse: y consumed by ln_fuse before FFN2 writes z

    // packed weight layout (elems)
    u16* WqRes = wb;             // [Wq;Wres] 512 x 64
    u16* WkWv  = wb + 32768;     // [Wk;Wv]   512 x 256
    u16* Wob   = wb + 163840;    // 256 x 256
    u16* W1b   = wb + 229376;    // 1024 x 256
    u16* W2b   = wb + 491520;    // 256 x 1024

    wconv<<<2944, 256, 0, stream>>>(Wq, Wrs, Wk, Wv, Wo, W1, W2, wb);
    tconv<<<dim3(64, 1, NB), 256, 0, stream>>>(F_lidar, xl, C1);
    tconv<<<dim3(64, 4, NB), 256, 0, stream>>>(F_cam, xc, C2);

    // softmax scale and log2(e) folded into Q
    const float qscale = 1.4426950408889634f / sqrtf((float)HDD);
    // fused Q + resid (N=512, 256 blocks)
    gemm_bt<4><<<dim3(64, 4), 256, 0, stream>>>(xl, WqRes, MTOT, 512, C1,
        nullptr, nullptr, resid, Qb, qscale);
    // fused K + V -> fragment-permuted buffers (N=512, 256 blocks)
    gemm_bt<3><<<dim3(64, 4), 256, 0, stream>>>(xc, WkWv, MTOT, 512, C2,
        nullptr, nullptr, (float*)Vperm, Kperm, 1.f);

    flash_attn<<<1024, 256, 0, stream>>>(Qb, Kperm, Vperm, attn);

    gemm_bt<0><<<dim3(64, 2), 256, 0, stream>>>(attn, Wob, MTOT, DD, DD,
        nullptr, resid, y, nullptr, 1.f);
    ln_fuse<<<2048, 256, 0, stream>>>(y, g1, b1, x, xb);
    gemm_bt<1><<<dim3(64, 8), 256, 0, stream>>>(xb, W1b, MTOT, FF, DD,
        bf1, nullptr, nullptr, hdn, 1.f);
    gemm_bt<2><<<dim3(64, 2), 256, 0, stream>>>(hdn, W2b, MTOT, DD, FF,
        bf2, x, zb, nullptr, 1.f);
    ln2_transpose<<<dim3(128, NB), 256, 0, stream>>>(zb, g2, b2, out);
}

// Round 11
// 123.777 us; speedup vs baseline: 1.6748x; 1.1409x over previous
//
#include <hip/hip_runtime.h>
#include <hip/hip_bf16.h>
#include <math.h>

#define NB 2
#define C1 64
#define C2 256
#define DD 256
#define NHH 8
#define HDD 32
#define NN 4096
#define FF 1024
#define MTOT (NB*NN)   // 8192 tokens
#define KVB 128

typedef unsigned short u16;
typedef __attribute__((ext_vector_type(8))) short bf16x8;
typedef __attribute__((ext_vector_type(4))) float f32x4;
typedef __attribute__((ext_vector_type(4))) unsigned short us4;
typedef __attribute__((ext_vector_type(4))) unsigned int u32x4;

__device__ __forceinline__ u16 f2bf(float f) {
    union { float f; unsigned int i; } u; u.f = f;
    unsigned int r = u.i + 0x7FFFu + ((u.i >> 16) & 1u);
    return (u16)(r >> 16);
}

__device__ __forceinline__ unsigned cvt_pk_bf16(float a, float b) {
    unsigned r; asm("v_cvt_pk_bf16_f32 %0, %1, %2" : "=v"(r) : "v"(a), "v"(b)); return r;
}

// async global->LDS, 16B per lane: dst = (uniform base) + lane*16, src per-lane
__device__ __forceinline__ void glds16(const void* g, void* l) {
    __builtin_amdgcn_global_load_lds(
        (__attribute__((address_space(1))) void*)g,
        (__attribute__((address_space(3))) void*)l, 16, 0, 0);
}

// ---------------------------------------------------------------------------
// tconv body: (B, C, N) f32 -> (B, N, C) bf16, one 64x64 tile
// ---------------------------------------------------------------------------
__device__ __forceinline__ void tconv_body(const float* __restrict__ src,
    u16* __restrict__ dst, int C, int n0, int c0, int b, int t,
    float (*tile)[65])
{
#pragma unroll
    for (int i = 0; i < 4; ++i) {
        int cc = t + i * 256;
        int c = cc >> 4, off = (cc & 15) * 4;
        const float4 v = *(const float4*)&src[((size_t)b*C + c0 + c)*NN + n0 + off];
        tile[c][off+0] = v.x; tile[c][off+1] = v.y;
        tile[c][off+2] = v.z; tile[c][off+3] = v.w;
    }
    __syncthreads();
    const int n = t >> 2, cch = (t & 3) * 16;
    bf16x8 t0, t1;
#pragma unroll
    for (int i = 0; i < 8; ++i) ((u16*)&t0)[i] = f2bf(tile[cch + i][n]);
#pragma unroll
    for (int i = 0; i < 8; ++i) ((u16*)&t1)[i] = f2bf(tile[cch + 8 + i][n]);
    u16* dp = &dst[((size_t)b*NN + n0 + n)*C + c0 + cch];
    *(bf16x8*)&dp[0] = t0;
    *(bf16x8*)&dp[8] = t1;
}

// ---------------------------------------------------------------------------
// prep: fused weight-convert (x4 vectorized) + both input transposes.
// blocks [0,736): wconv ; [736,864): tconv lidar ; [864,1376): tconv cam
// weight pack (elems): [Wq 16k][Wres 16k][Wk 64k][Wv 64k][Wo 64k][W1 256k][W2 256k]
// ---------------------------------------------------------------------------
__global__ __launch_bounds__(256) void prep(
    const float* __restrict__ Wq, const float* __restrict__ Wres,
    const float* __restrict__ Wk, const float* __restrict__ Wv,
    const float* __restrict__ Wo, const float* __restrict__ W1,
    const float* __restrict__ W2, u16* __restrict__ d,
    const float* __restrict__ F_lidar, const float* __restrict__ F_cam,
    u16* __restrict__ xl, u16* __restrict__ xc)
{
    __shared__ float tile[64][65];
    const int id = blockIdx.x, t = threadIdx.x;
    if (id < 736) {
        int i4 = (id * 256 + t) * 4;
        const float* s; int off;
        if      (i4 <  16384) { s = Wq;   off = i4; }
        else if (i4 <  32768) { s = Wres; off = i4 -  16384; }
        else if (i4 <  98304) { s = Wk;   off = i4 -  32768; }
        else if (i4 < 163840) { s = Wv;   off = i4 -  98304; }
        else if (i4 < 229376) { s = Wo;   off = i4 - 163840; }
        else if (i4 < 491520) { s = W1;   off = i4 - 229376; }
        else                  { s = W2;   off = i4 - 491520; }
        const float4 v = *(const float4*)&s[off];
        us4 o; o[0] = f2bf(v.x); o[1] = f2bf(v.y); o[2] = f2bf(v.z); o[3] = f2bf(v.w);
        *(us4*)&d[i4] = o;
    } else if (id < 864) {
        int l = id - 736;
        tconv_body(F_lidar, xl, C1, (l & 63)*64, 0, l >> 6, t, tile);
    } else {
        int l = id - 864;
        tconv_body(F_cam, xc, C2, (l & 63)*64, ((l >> 6) & 3)*64, l >> 8, t, tile);
    }
}

// ---------------------------------------------------------------------------
// GEMM body: C = A * B^T (A: M x K row-major bf16, B: N x K row-major bf16)
// BM x 128 tile, double-buffered linear LDS via global_load_lds x16B,
// 4 waves (2x2, wave tile (BM/2)x64), 16x16x32 bf16 MFMA, BK=32.
// Epilogues:
//  0: f32 = acc + add[idx]              (Wo out + resid)
//  1: bf16 relu(acc + bias[col])        (FFN1)
//  2: f32 = acc + bias[col] + add[idx]  (FFN2 + skip)
//  3: fused KV: col<256 -> Kperm scatter (outb); col>=256 -> Vperm (outf cast)
//  4: fused Q+resid: col<256 -> Q (b,h,n,hd)*scale (outb); col>=256 -> resid f32
// ---------------------------------------------------------------------------
template<int MODE, int BM>
__device__ __forceinline__ void gemm_body(
    const u16* __restrict__ A, const u16* __restrict__ Bw,
    int N, int K,
    const float* __restrict__ bias, const float* __restrict__ add,
    float* __restrict__ outf, u16* __restrict__ outb, float scale,
    int bm, int bn, u16* lA, u16* lB)
{
    constexpr int MFR = BM / 32;          // m-frags per wave
    constexpr int ASZ = BM * 32;          // elems per A buffer
    const int t = threadIdx.x, lane = t & 63, wid = t >> 6;
    const int wr = (wid >> 1) * (BM/2), wc = (wid & 1) * 64;
    const int lrow = lane & 15, lk = (lane >> 4) * 8;
    const int arow = wid*(BM/4) + (lane >> 2);
    const int brow = wid*32 + (lane >> 2);
    const int soff = (lane & 3) * 8;
    const u16* aS = &A[(size_t)(bm + arow)*K + soff];
    const u16* bS = &Bw[(size_t)(bn + brow)*K + soff];
    const int lwA = wid*(BM/4)*32;
    const int lwB = wid*1024;
    f32x4 acc[MFR][4] = {};

    // prologue: stage K-step 0 into buffer 0
    glds16(aS, &lA[lwA]);
    if (BM == 128) glds16(aS + (size_t)16*K, &lA[lwA + 512]);
    glds16(bS, &lB[lwB]);
    glds16(bS + (size_t)16*K, &lB[lwB + 512]);
    __syncthreads();

    const int nst = K >> 5;
    for (int st = 0; st < nst; ++st) {
        const int cur = st & 1;
        if (st < nst - 1) {
            const int k0 = (st + 1) * 32;
            const int nb = (cur ^ 1);
            glds16(aS + k0, &lA[nb*ASZ + lwA]);
            if (BM == 128) glds16(aS + (size_t)16*K + k0, &lA[nb*ASZ + lwA + 512]);
            glds16(bS + k0, &lB[nb*4096 + lwB]);
            glds16(bS + (size_t)16*K + k0, &lB[nb*4096 + lwB + 512]);
        }
        bf16x8 af[MFR], bfr[4];
#pragma unroll
        for (int mf = 0; mf < MFR; ++mf)
            af[mf] = *(const bf16x8*)&lA[cur*ASZ + (wr + mf*16 + lrow)*32 + lk];
#pragma unroll
        for (int nf = 0; nf < 4; ++nf)
            bfr[nf] = *(const bf16x8*)&lB[cur*4096 + (wc + nf*16 + lrow)*32 + lk];
#pragma unroll
        for (int mf = 0; mf < MFR; ++mf)
#pragma unroll
            for (int nf = 0; nf < 4; ++nf)
                acc[mf][nf] = __builtin_amdgcn_mfma_f32_16x16x32_bf16(af[mf], bfr[nf], acc[mf][nf], 0, 0, 0);
        __syncthreads();
    }
#pragma unroll
    for (int mf = 0; mf < MFR; ++mf) {
#pragma unroll
        for (int nf = 0; nf < 4; ++nf) {
#pragma unroll
            for (int j = 0; j < 4; ++j) {
                int row = bm + wr + mf*16 + (lane >> 4)*4 + j;
                int col = bn + wc + nf*16 + lrow;
                float v = acc[mf][nf][j];
                if (MODE == 0) {
                    size_t idx = (size_t)row*N + col;
                    outf[idx] = v + add[idx];
                } else if (MODE == 1) {
                    float r = v + bias[col];
                    outb[(size_t)row*N + col] = f2bf(r > 0.f ? r : 0.f);
                } else if (MODE == 2) {
                    size_t idx = (size_t)row*N + col;
                    outf[idx] = v + bias[col] + add[idx];
                } else if (MODE == 3) {
                    int b = row >> 12, n = row & 4095;
                    if (col < 256) {
                        // K fragment-permuted: [bh][n>>4][(hd>>3)*16 + (n&15)][hd&7]
                        int h = col >> 5, hd = col & 31;
                        int bh = b*NHH + h;
                        size_t idx = (((size_t)bh*256 + (n >> 4))*64
                                      + (hd >> 3)*16 + (n & 15))*8 + (hd & 7);
                        outb[idx] = f2bf(v);
                    } else {
                        // V fragment-permuted: [bh][kb][hf][gg*16+d][hp*4+r]
                        int c = col - 256;
                        int h = c >> 5, hd = c & 31;
                        int hf = hd >> 4, d2 = hd & 15;
                        int bh = b*NHH + h;
                        int kb = n >> 5, kwb = n & 31;
                        int hp = kwb >> 4, gg = (kwb >> 2) & 3, r = kwb & 3;
                        size_t idx = ((((size_t)bh*128 + kb)*2 + hf)*64 + gg*16 + d2)*8
                                   + hp*4 + r;
                        ((u16*)outf)[idx] = f2bf(v);
                    }
                } else {
                    int b = row >> 12, n = row & 4095;
                    if (col < 256) {
                        int h = col >> 5, hd = col & 31;
                        outb[(((size_t)b*NHH + h)*NN + n)*HDD + hd] = f2bf(v * scale);
                    } else {
                        outf[(size_t)row*DD + (col - 256)] = v;
                    }
                }
            }
        }
    }
}

template<int MODE, int BM>
__global__ __launch_bounds__(256) void gemm_bt(
    const u16* __restrict__ A, const u16* __restrict__ Bw,
    int N, int K, const float* __restrict__ bias, const float* __restrict__ add,
    float* __restrict__ outf, u16* __restrict__ outb, float scale)
{
    __shared__ u16 lA[2*BM*32];
    __shared__ u16 lB[2*4096];
    gemm_body<MODE, BM>(A, Bw, N, K, bias, add, outf, outb, scale,
                        blockIdx.x*BM, blockIdx.y*128, lA, lB);
}

// ---------------------------------------------------------------------------
// Fused QKV projections: blocks [0,256) -> Q+resid (K=64); [256,512) -> K+V
// (K=256, fragment-permuted outputs). 512 blocks = 2/CU, two GEMMs overlap.
// ---------------------------------------------------------------------------
__global__ __launch_bounds__(256) void qkv_gemm(
    const u16* __restrict__ xl, const u16* __restrict__ xc,
    const u16* __restrict__ WqRes, const u16* __restrict__ WkWv,
    float* __restrict__ resid, u16* __restrict__ Qb,
    u16* __restrict__ Kperm, u16* __restrict__ Vperm, float qscale)
{
    __shared__ u16 lA[2*128*32];
    __shared__ u16 lB[2*4096];
    int l = blockIdx.x;
    if (l < 256) {
        gemm_body<4, 128>(xl, WqRes, 512, 64, nullptr, nullptr, resid, Qb,
                          qscale, (l & 63)*128, (l >> 6)*128, lA, lB);
    } else {
        l -= 256;
        gemm_body<3, 128>(xc, WkWv, 512, 256, nullptr, nullptr,
                          (float*)Vperm, Kperm, 1.f, (l & 63)*128, (l >> 6)*128, lA, lB);
    }
}

// ---------------------------------------------------------------------------
// Flash attention (v10 structure, unchanged): LDS double-buffered K/V via
// global_load_lds, fragment-linear layouts, no-max base-2 softmax, swapped
// QK^T, MFMA rowsum vs all-ones, XCD swizzle.
// ---------------------------------------------------------------------------
__global__ __launch_bounds__(256) void flash_attn(
    const u16* __restrict__ Qp, const u16* __restrict__ Kperm,
    const u16* __restrict__ Vperm, u16* __restrict__ Op)
{
    __shared__ u16 Kl[2][4096];   // [b16 8][lane 64][8]
    __shared__ u16 Vl[2][4096];   // [kb 4][hf 2][lane 64][8]
    const int id = blockIdx.x;                 // 0..1023
    const int sw = (id & 7) * 128 + (id >> 3); // XCD-grouped
    const int qt = sw & 63;
    const int bh = sw >> 6;                    // b*8 + h
    const size_t base = (size_t)bh * NN * HDD; // Q (b,h,n,hd)
    const int t = threadIdx.x, lane = t & 63, w = t >> 6;
    const int q0 = qt * 64;
    const int lrow = lane & 15, g = lane >> 4;

    const bf16x8 qf = *(const bf16x8*)&Qp[base + (size_t)(q0 + w*16 + lrow)*HDD + g*8];

    const u16* kgw = &Kperm[(size_t)bh*131072 + w*1024 + lane*8];
    const u16* vgw = &Vperm[(size_t)bh*131072 + w*1024 + lane*8];
    const int lw = w * 1024;

    u32x4 onesw = {0x3F803F80u, 0x3F803F80u, 0x3F803F80u, 0x3F803F80u};
    const bf16x8 ones = *(bf16x8*)&onesw;

    glds16(kgw,       &Kl[0][lw]);
    glds16(kgw + 512, &Kl[0][lw + 512]);
    glds16(vgw,       &Vl[0][lw]);
    glds16(vgw + 512, &Vl[0][lw + 512]);

    f32x4 o[2] = {};
    f32x4 osum = {};
    __syncthreads();

#define FLASH_STEP(CUR, TT)                                                    \
    {                                                                          \
        if ((TT) < 31) {                                                       \
            const u16* kg = kgw + (size_t)((TT)+1)*4096;                       \
            const u16* vg = vgw + (size_t)((TT)+1)*4096;                       \
            glds16(kg,       &Kl[(CUR)^1][lw]);                                \
            glds16(kg + 512, &Kl[(CUR)^1][lw + 512]);                          \
            glds16(vg,       &Vl[(CUR)^1][lw]);                                \
            glds16(vg + 512, &Vl[(CUR)^1][lw + 512]);                          \
        }                                                                      \
        f32x4 s[8];                                                            \
        __builtin_amdgcn_s_setprio(1);                                         \
        _Pragma("unroll")                                                      \
        for (int nf = 0; nf < 8; ++nf) {                                       \
            bf16x8 kf = *(const bf16x8*)&Kl[(CUR)][nf*512 + lane*8];           \
            f32x4 z = {};                                                      \
            s[nf] = __builtin_amdgcn_mfma_f32_16x16x32_bf16(kf, qf, z, 0, 0, 0); \
        }                                                                      \
        __builtin_amdgcn_s_setprio(0);                                         \
        _Pragma("unroll")                                                      \
        for (int kk = 0; kk < 4; ++kk) {                                       \
            float p0[4], p1[4];                                                \
            _Pragma("unroll")                                                  \
            for (int jj = 0; jj < 4; ++jj) {                                   \
                p0[jj] = __builtin_amdgcn_exp2f(s[2*kk][jj]);                  \
                p1[jj] = __builtin_amdgcn_exp2f(s[2*kk+1][jj]);                 \
            }                                                                  \
            u32x4 paw;                                                         \
            paw[0] = cvt_pk_bf16(p0[0], p0[1]);                                \
            paw[1] = cvt_pk_bf16(p0[2], p0[3]);                                \
            paw[2] = cvt_pk_bf16(p1[0], p1[1]);                                \
            paw[3] = cvt_pk_bf16(p1[2], p1[3]);                                \
            bf16x8 pa = *(bf16x8*)&paw;                                        \
            __builtin_amdgcn_s_setprio(1);                                     \
            _Pragma("unroll")                                                  \
            for (int hf = 0; hf < 2; ++hf) {                                   \
                bf16x8 vf = *(const bf16x8*)&Vl[(CUR)][kk*1024 + hf*512 + lane*8]; \
                o[hf] = __builtin_amdgcn_mfma_f32_16x16x32_bf16(pa, vf, o[hf], 0, 0, 0); \
            }                                                                  \
            osum = __builtin_amdgcn_mfma_f32_16x16x32_bf16(pa, ones, osum, 0, 0, 0); \
            __builtin_amdgcn_s_setprio(0);                                     \
        }                                                                      \
        __syncthreads();                                                       \
    }

    for (int tt = 0; tt < 32; tt += 2) {
        FLASH_STEP(0, tt)
        FLASH_STEP(1, tt + 1)
    }
#undef FLASH_STEP

    const int b = bh >> 3, h = bh & 7;
#pragma unroll
    for (int hf = 0; hf < 2; ++hf)
#pragma unroll
        for (int r = 0; r < 4; ++r) {
            int q = q0 + w*16 + g*4 + r;
            int d = h*HDD + hf*16 + lrow;
            Op[((size_t)b*NN + q)*DD + d] = f2bf(o[hf][r] / osum[r]);
        }
}

// ---------------------------------------------------------------------------
// LayerNorm1: y (8192x256 f32) -> x f32 and x bf16. One wave per row.
// ---------------------------------------------------------------------------
__global__ __launch_bounds__(256) void ln_fuse(const float* __restrict__ y,
    const float* __restrict__ g, const float* __restrict__ be,
    float* __restrict__ x, u16* __restrict__ xb)
{
    const int row = blockIdx.x * 4 + (threadIdx.x >> 6);
    const int lane = threadIdx.x & 63;
    const float4 v = *(const float4*)&y[(size_t)row*DD + lane*4];
    float s1 = v.x + v.y + v.z + v.w;
    float s2 = v.x*v.x + v.y*v.y + v.z*v.z + v.w*v.w;
#pragma unroll
    for (int m = 1; m <= 32; m <<= 1) { s1 += __shfl_xor(s1, m); s2 += __shfl_xor(s2, m); }
    float mean = s1 * (1.f/DD);
    float var  = s2 * (1.f/DD) - mean*mean;
    float rstd = rsqrtf(var + 1e-5f);
    const float vv[4] = {v.x, v.y, v.z, v.w};
    float4 xo; us4 xo16;
#pragma unroll
    for (int i = 0; i < 4; ++i) {
        int d = lane*4 + i;
        float r = (vv[i] - mean) * rstd * g[d] + be[d];
        ((float*)&xo)[i] = r;
        xo16[i] = f2bf(r);
    }
    *(float4*)&x[(size_t)row*DD + lane*4] = xo;
    *(us4*)&xb[(size_t)row*DD + lane*4] = xo16;
}

// ---------------------------------------------------------------------------
// LayerNorm2 + transpose to (B, D, H*W). 32 tokens per block via LDS tile.
// ---------------------------------------------------------------------------
__global__ __launch_bounds__(256) void ln2_transpose(const float* __restrict__ z,
    const float* __restrict__ g, const float* __restrict__ be,
    float* __restrict__ out)
{
    __shared__ float tile[32][257];
    const int n0 = blockIdx.x * 32;
    const int b = blockIdx.y;
    const int t = threadIdx.x, lane = t & 63, w = t >> 6;
    for (int r8 = 0; r8 < 8; ++r8) {
        int r = w*8 + r8;
        const float4 v = *(const float4*)&z[((size_t)b*NN + n0 + r)*DD + lane*4];
        float s1 = v.x + v.y + v.z + v.w;
        float s2 = v.x*v.x + v.y*v.y + v.z*v.z + v.w*v.w;
#pragma unroll
        for (int m = 1; m <= 32; m <<= 1) { s1 += __shfl_xor(s1, m); s2 += __shfl_xor(s2, m); }
        float mean = s1 * (1.f/DD);
        float var  = s2 * (1.f/DD) - mean*mean;
        float rstd = rsqrtf(var + 1e-5f);
        const float vv[4] = {v.x, v.y, v.z, v.w};
#pragma unroll
        for (int i = 0; i < 4; ++i) {
            int d = lane*4 + i;
            tile[r][d] = (vv[i] - mean)*rstd*g[d] + be[d];
        }
    }
    __syncthreads();
    const int n = t & 31, dg = t >> 5;
    for (int dd = 0; dd < 32; ++dd) {
        int d = dd*8 + dg;
        out[((size_t)b*DD + d)*NN + n0 + n] = tile[n][d];
    }
}

// ---------------------------------------------------------------------------
extern "C" void kernel_launch(void* const* d_in, const int* in_sizes, int n_in,
                              void* d_out, int out_size, void* d_ws, size_t ws_size,
                              hipStream_t stream)
{
    const float* F_lidar = (const float*)d_in[0];
    const float* F_cam   = (const float*)d_in[1];
    const float* Wq  = (const float*)d_in[2];
    const float* Wk  = (const float*)d_in[3];
    const float* Wv  = (const float*)d_in[4];
    const float* Wo  = (const float*)d_in[5];
    const float* Wrs = (const float*)d_in[6];
    const float* g1  = (const float*)d_in[7];
    const float* b1  = (const float*)d_in[8];
    const float* g2  = (const float*)d_in[9];
    const float* b2  = (const float*)d_in[10];
    const float* W1  = (const float*)d_in[11];
    const float* bf1 = (const float*)d_in[12];
    const float* W2  = (const float*)d_in[13];
    const float* bf2 = (const float*)d_in[14];
    float* out = (float*)d_out;

    char* ws = (char*)d_ws;
    size_t cur = 0;
    auto carve = [&](size_t bytes) {
        size_t o = cur; cur += (bytes + 255) & ~(size_t)255; return (void*)(ws + o);
    };
    u16* wb    = (u16*)carve(753664u * 2);
    u16* xl    = (u16*)carve((size_t)MTOT * C1 * 2);
    u16* xc    = (u16*)carve((size_t)MTOT * C2 * 2);
    u16* Qb    = (u16*)carve((size_t)MTOT * DD * 2);
    u16* Kperm = (u16*)carve((size_t)MTOT * DD * 2);
    u16* Vperm = (u16*)carve((size_t)MTOT * DD * 2);
    float* resid = (float*)carve((size_t)MTOT * DD * 4);
    u16* attn  = (u16*)carve((size_t)MTOT * DD * 2);
    float* y   = (float*)carve((size_t)MTOT * DD * 4);
    float* x   = (float*)carve((size_t)MTOT * DD * 4);
    u16* xb    = (u16*)carve((size_t)MTOT * DD * 2);
    u16* hdn   = (u16*)carve((size_t)MTOT * FF * 2);
    float* zb  = y;   // reuse: y consumed by ln_fuse before FFN2 writes z

    // packed weight layout (elems)
    u16* WqRes = wb;             // [Wq;Wres] 512 x 64
    u16* WkWv  = wb + 32768;     // [Wk;Wv]   512 x 256
    u16* Wob   = wb + 163840;    // 256 x 256
    u16* W1b   = wb + 229376;    // 1024 x 256
    u16* W2b   = wb + 491520;    // 256 x 1024

    prep<<<1376, 256, 0, stream>>>(Wq, Wrs, Wk, Wv, Wo, W1, W2, wb,
                                   F_lidar, F_cam, xl, xc);

    // softmax scale and log2(e) folded into Q
    const float qscale = 1.4426950408889634f / sqrtf((float)HDD);
    qkv_gemm<<<512, 256, 0, stream>>>(xl, xc, WqRes, WkWv,
                                      resid, Qb, Kperm, Vperm, qscale);

    flash_attn<<<1024, 256, 0, stream>>>(Qb, Kperm, Vperm, attn);

    gemm_bt<0, 64><<<dim3(128, 2), 256, 0, stream>>>(attn, Wob, DD, DD,
        nullptr, resid, y, nullptr, 1.f);
    ln_fuse<<<2048, 256, 0, stream>>>(y, g1, b1, x, xb);
    gemm_bt<1, 128><<<dim3(64, 8), 256, 0, stream>>>(xb, W1b, FF, DD,
        bf1, nullptr, nullptr, hdn, 1.f);
    gemm_bt<2, 64><<<dim3(128, 2), 256, 0, stream>>>(hdn, W2b, DD, FF,
        bf2, x, zb, nullptr, 1.f);
    ln2_transpose<<<dim3(128, NB), 256, 0, stream>>>(zb, g2, b2, out);
}

// Round 12
// 122.216 us; speedup vs baseline: 1.6962x; 1.0128x over previous
//
#include <hip/hip_runtime.h>
#include <hip/hip_bf16.h>
#include <math.h>

#define NB 2
#define C1 64
#define C2 256
#define DD 256
#define NHH 8
#define HDD 32
#define NN 4096
#define FF 1024
#define MTOT (NB*NN)   // 8192 tokens
#define KVB 128

typedef unsigned short u16;
typedef __attribute__((ext_vector_type(8))) short bf16x8;
typedef __attribute__((ext_vector_type(4))) float f32x4;
typedef __attribute__((ext_vector_type(4))) unsigned short us4;
typedef __attribute__((ext_vector_type(4))) unsigned int u32x4;

__device__ __forceinline__ u16 f2bf(float f) {
    union { float f; unsigned int i; } u; u.f = f;
    unsigned int r = u.i + 0x7FFFu + ((u.i >> 16) & 1u);
    return (u16)(r >> 16);
}

__device__ __forceinline__ unsigned cvt_pk_bf16(float a, float b) {
    unsigned r; asm("v_cvt_pk_bf16_f32 %0, %1, %2" : "=v"(r) : "v"(a), "v"(b)); return r;
}

// async global->LDS, 16B per lane: dst = (uniform base) + lane*16, src per-lane
__device__ __forceinline__ void glds16(const void* g, void* l) {
    __builtin_amdgcn_global_load_lds(
        (__attribute__((address_space(1))) void*)g,
        (__attribute__((address_space(3))) void*)l, 16, 0, 0);
}

// ---------------------------------------------------------------------------
// tconv body: (B, C, N) f32 -> (B, N, C) bf16, one 64x64 tile
// ---------------------------------------------------------------------------
__device__ __forceinline__ void tconv_body(const float* __restrict__ src,
    u16* __restrict__ dst, int C, int n0, int c0, int b, int t,
    float (*tile)[65])
{
#pragma unroll
    for (int i = 0; i < 4; ++i) {
        int cc = t + i * 256;
        int c = cc >> 4, off = (cc & 15) * 4;
        const float4 v = *(const float4*)&src[((size_t)b*C + c0 + c)*NN + n0 + off];
        tile[c][off+0] = v.x; tile[c][off+1] = v.y;
        tile[c][off+2] = v.z; tile[c][off+3] = v.w;
    }
    __syncthreads();
    const int n = t >> 2, cch = (t & 3) * 16;
    bf16x8 t0, t1;
#pragma unroll
    for (int i = 0; i < 8; ++i) ((u16*)&t0)[i] = f2bf(tile[cch + i][n]);
#pragma unroll
    for (int i = 0; i < 8; ++i) ((u16*)&t1)[i] = f2bf(tile[cch + 8 + i][n]);
    u16* dp = &dst[((size_t)b*NN + n0 + n)*C + c0 + cch];
    *(bf16x8*)&dp[0] = t0;
    *(bf16x8*)&dp[8] = t1;
}

// ---------------------------------------------------------------------------
// prep: fused weight-convert (x4 vectorized) + both input transposes.
// blocks [0,736): wconv ; [736,864): tconv lidar ; [864,1376): tconv cam
// ---------------------------------------------------------------------------
__global__ __launch_bounds__(256) void prep(
    const float* __restrict__ Wq, const float* __restrict__ Wres,
    const float* __restrict__ Wk, const float* __restrict__ Wv,
    const float* __restrict__ Wo, const float* __restrict__ W1,
    const float* __restrict__ W2, u16* __restrict__ d,
    const float* __restrict__ F_lidar, const float* __restrict__ F_cam,
    u16* __restrict__ xl, u16* __restrict__ xc)
{
    __shared__ float tile[64][65];
    const int id = blockIdx.x, t = threadIdx.x;
    if (id < 736) {
        int i4 = (id * 256 + t) * 4;
        const float* s; int off;
        if      (i4 <  16384) { s = Wq;   off = i4; }
        else if (i4 <  32768) { s = Wres; off = i4 -  16384; }
        else if (i4 <  98304) { s = Wk;   off = i4 -  32768; }
        else if (i4 < 163840) { s = Wv;   off = i4 -  98304; }
        else if (i4 < 229376) { s = Wo;   off = i4 - 163840; }
        else if (i4 < 491520) { s = W1;   off = i4 - 229376; }
        else                  { s = W2;   off = i4 - 491520; }
        const float4 v = *(const float4*)&s[off];
        us4 o; o[0] = f2bf(v.x); o[1] = f2bf(v.y); o[2] = f2bf(v.z); o[3] = f2bf(v.w);
        *(us4*)&d[i4] = o;
    } else if (id < 864) {
        int l = id - 736;
        tconv_body(F_lidar, xl, C1, (l & 63)*64, 0, l >> 6, t, tile);
    } else {
        int l = id - 864;
        tconv_body(F_cam, xc, C2, (l & 63)*64, ((l >> 6) & 3)*64, l >> 8, t, tile);
    }
}

// ---------------------------------------------------------------------------
// GEMM body (BM x 128 tile, dbuf glds16 staging) -- as round 11.
// Epilogues: 1: bf16 relu(acc+bias) (FFN1)
//            3: fused KV -> Kperm/Vperm scatters
//            4: fused Q+resid
// ---------------------------------------------------------------------------
template<int MODE, int BM>
__device__ __forceinline__ void gemm_body(
    const u16* __restrict__ A, const u16* __restrict__ Bw,
    int N, int K,
    const float* __restrict__ bias, const float* __restrict__ add,
    float* __restrict__ outf, u16* __restrict__ outb, float scale,
    int bm, int bn, u16* lA, u16* lB)
{
    constexpr int MFR = BM / 32;
    constexpr int ASZ = BM * 32;
    const int t = threadIdx.x, lane = t & 63, wid = t >> 6;
    const int wr = (wid >> 1) * (BM/2), wc = (wid & 1) * 64;
    const int lrow = lane & 15, lk = (lane >> 4) * 8;
    const int arow = wid*(BM/4) + (lane >> 2);
    const int brow = wid*32 + (lane >> 2);
    const int soff = (lane & 3) * 8;
    const u16* aS = &A[(size_t)(bm + arow)*K + soff];
    const u16* bS = &Bw[(size_t)(bn + brow)*K + soff];
    const int lwA = wid*(BM/4)*32;
    const int lwB = wid*1024;
    f32x4 acc[MFR][4] = {};

    glds16(aS, &lA[lwA]);
    if (BM == 128) glds16(aS + (size_t)16*K, &lA[lwA + 512]);
    glds16(bS, &lB[lwB]);
    glds16(bS + (size_t)16*K, &lB[lwB + 512]);
    __syncthreads();

    const int nst = K >> 5;
    for (int st = 0; st < nst; ++st) {
        const int cur = st & 1;
        if (st < nst - 1) {
            const int k0 = (st + 1) * 32;
            const int nb = (cur ^ 1);
            glds16(aS + k0, &lA[nb*ASZ + lwA]);
            if (BM == 128) glds16(aS + (size_t)16*K + k0, &lA[nb*ASZ + lwA + 512]);
            glds16(bS + k0, &lB[nb*4096 + lwB]);
            glds16(bS + (size_t)16*K + k0, &lB[nb*4096 + lwB + 512]);
        }
        bf16x8 af[MFR], bfr[4];
#pragma unroll
        for (int mf = 0; mf < MFR; ++mf)
            af[mf] = *(const bf16x8*)&lA[cur*ASZ + (wr + mf*16 + lrow)*32 + lk];
#pragma unroll
        for (int nf = 0; nf < 4; ++nf)
            bfr[nf] = *(const bf16x8*)&lB[cur*4096 + (wc + nf*16 + lrow)*32 + lk];
#pragma unroll
        for (int mf = 0; mf < MFR; ++mf)
#pragma unroll
            for (int nf = 0; nf < 4; ++nf)
                acc[mf][nf] = __builtin_amdgcn_mfma_f32_16x16x32_bf16(af[mf], bfr[nf], acc[mf][nf], 0, 0, 0);
        __syncthreads();
    }
#pragma unroll
    for (int mf = 0; mf < MFR; ++mf) {
#pragma unroll
        for (int nf = 0; nf < 4; ++nf) {
#pragma unroll
            for (int j = 0; j < 4; ++j) {
                int row = bm + wr + mf*16 + (lane >> 4)*4 + j;
                int col = bn + wc + nf*16 + lrow;
                float v = acc[mf][nf][j];
                if (MODE == 1) {
                    float r = v + bias[col];
                    outb[(size_t)row*N + col] = f2bf(r > 0.f ? r : 0.f);
                } else if (MODE == 3) {
                    int b = row >> 12, n = row & 4095;
                    if (col < 256) {
                        int h = col >> 5, hd = col & 31;
                        int bh = b*NHH + h;
                        size_t idx = (((size_t)bh*256 + (n >> 4))*64
                                      + (hd >> 3)*16 + (n & 15))*8 + (hd & 7);
                        outb[idx] = f2bf(v);
                    } else {
                        int c = col - 256;
                        int h = c >> 5, hd = c & 31;
                        int hf = hd >> 4, d2 = hd & 15;
                        int bh = b*NHH + h;
                        int kb = n >> 5, kwb = n & 31;
                        int hp = kwb >> 4, gg = (kwb >> 2) & 3, r = kwb & 3;
                        size_t idx = ((((size_t)bh*128 + kb)*2 + hf)*64 + gg*16 + d2)*8
                                   + hp*4 + r;
                        ((u16*)outf)[idx] = f2bf(v);
                    }
                } else if (MODE == 4) {
                    int b = row >> 12, n = row & 4095;
                    if (col < 256) {
                        int h = col >> 5, hd = col & 31;
                        outb[(((size_t)b*NHH + h)*NN + n)*HDD + hd] = f2bf(v * scale);
                    } else {
                        outf[(size_t)row*DD + (col - 256)] = v;
                    }
                }
            }
        }
    }
}

template<int MODE, int BM>
__global__ __launch_bounds__(256) void gemm_bt(
    const u16* __restrict__ A, const u16* __restrict__ Bw,
    int N, int K, const float* __restrict__ bias, const float* __restrict__ add,
    float* __restrict__ outf, u16* __restrict__ outb, float scale)
{
    __shared__ u16 lA[2*BM*32];
    __shared__ u16 lB[2*4096];
    gemm_body<MODE, BM>(A, Bw, N, K, bias, add, outf, outb, scale,
                        blockIdx.x*BM, blockIdx.y*128, lA, lB);
}

// ---------------------------------------------------------------------------
// Fused QKV projections: blocks [0,256) -> Q+resid (K=64); [256,512) -> K+V
// ---------------------------------------------------------------------------
__global__ __launch_bounds__(256) void qkv_gemm(
    const u16* __restrict__ xl, const u16* __restrict__ xc,
    const u16* __restrict__ WqRes, const u16* __restrict__ WkWv,
    float* __restrict__ resid, u16* __restrict__ Qb,
    u16* __restrict__ Kperm, u16* __restrict__ Vperm, float qscale)
{
    __shared__ u16 lA[2*128*32];
    __shared__ u16 lB[2*4096];
    int l = blockIdx.x;
    if (l < 256) {
        gemm_body<4, 128>(xl, WqRes, 512, 64, nullptr, nullptr, resid, Qb,
                          qscale, (l & 63)*128, (l >> 6)*128, lA, lB);
    } else {
        l -= 256;
        gemm_body<3, 128>(xc, WkWv, 512, 256, nullptr, nullptr,
                          (float*)Vperm, Kperm, 1.f, (l & 63)*128, (l >> 6)*128, lA, lB);
    }
}

// ---------------------------------------------------------------------------
// gemm_ln<MODE>: C = A * B^T with FULL-ROW tile (32 x 256) + fused LayerNorm.
// grid 256 blocks (1/CU), 4 waves each owning a 64-col strip.
// Staging: A 2KB/step (waves 0-1), B 16KB/step (4 x 1KB calls per wave),
// double-buffered.  Epilogue LDS f32 tile [32][257] ALIASES the staging
// buffers (safe: trailing barrier after last K-step).
// MODE 0 (Wo+LN1):  v = acc + resid;  LN(g1,b1) -> x f32 + xb bf16
// MODE 1 (FFN2+LN2+transpose): v = acc + bias + x; LN(g2,b2) -> out (B,D,N)
// ---------------------------------------------------------------------------
template<int MODE>
__global__ __launch_bounds__(256) void gemm_ln(
    const u16* __restrict__ A, const u16* __restrict__ Bw, int K,
    const float* __restrict__ bias, const float* __restrict__ add,
    const float* __restrict__ g, const float* __restrict__ be,
    float* __restrict__ xf, u16* __restrict__ xb, float* __restrict__ out)
{
    __shared__ char smem[37888];            // lA 4KB | lB 32KB | pad; epi aliases
    u16* lA = (u16*)smem;                   // [2][1024]
    u16* lB = (u16*)(smem + 4096);          // [2][8192]
    float (*epi)[257] = (float(*)[257])smem; // 32*257*4 = 32896 B

    const int bm = blockIdx.x * 32;
    const int t = threadIdx.x, lane = t & 63, wid = t >> 6;
    const int wc = wid * 64;
    const int lrow = lane & 15, g4 = lane >> 4, lk = g4 * 8;
    const int sr = lane >> 2, sc = (lane & 3) * 8;
    const u16* aS = &A[(size_t)(bm + wid*16 + sr)*K + sc];        // wid<2 only
    const u16* bS = &Bw[(size_t)(wid*64 + sr)*K + sc];            // + c*16*K
    f32x4 acc[2][4] = {};

    // prologue: stage K-step 0 into buffer 0
    if (wid < 2) glds16(aS, &lA[wid*512]);
#pragma unroll
    for (int c = 0; c < 4; ++c)
        glds16(bS + (size_t)c*16*K, &lB[wid*2048 + c*512]);
    __syncthreads();

    const int nst = K >> 5;
    for (int st = 0; st < nst; ++st) {
        const int cur = st & 1;
        if (st < nst - 1) {
            const int k0 = (st + 1) * 32;
            const int nb = cur ^ 1;
            if (wid < 2) glds16(aS + k0, &lA[nb*1024 + wid*512]);
#pragma unroll
            for (int c = 0; c < 4; ++c)
                glds16(bS + (size_t)c*16*K + k0, &lB[nb*8192 + wid*2048 + c*512]);
        }
        bf16x8 af[2], bfr[4];
#pragma unroll
        for (int mf = 0; mf < 2; ++mf)
            af[mf] = *(const bf16x8*)&lA[cur*1024 + (mf*16 + lrow)*32 + lk];
#pragma unroll
        for (int nf = 0; nf < 4; ++nf)
            bfr[nf] = *(const bf16x8*)&lB[cur*8192 + (wc + nf*16 + lrow)*32 + lk];
#pragma unroll
        for (int mf = 0; mf < 2; ++mf)
#pragma unroll
            for (int nf = 0; nf < 4; ++nf)
                acc[mf][nf] = __builtin_amdgcn_mfma_f32_16x16x32_bf16(af[mf], bfr[nf], acc[mf][nf], 0, 0, 0);
        __syncthreads();   // also protects the epi alias after the last step
    }

    // epilogue 1: acc (+resid / +bias + x) -> epi LDS tile
#pragma unroll
    for (int mf = 0; mf < 2; ++mf)
#pragma unroll
        for (int nf = 0; nf < 4; ++nf)
#pragma unroll
            for (int j = 0; j < 4; ++j) {
                int rl = mf*16 + g4*4 + j;
                int col = wc + nf*16 + lrow;
                float v = acc[mf][nf][j];
                if (MODE == 0) v += add[(size_t)(bm + rl)*DD + col];
                else           v += bias[col] + add[(size_t)(bm + rl)*DD + col];
                epi[rl][col] = v;
            }
    __syncthreads();

    // epilogue 2: LN per row (wave handles 8 rows; 64 lanes x 4 elems)
#pragma unroll
    for (int r8 = 0; r8 < 8; ++r8) {
        int r = wid*8 + r8;
        const float4 v = *(const float4*)&epi[r][lane*4];
        float s1 = v.x + v.y + v.z + v.w;
        float s2 = v.x*v.x + v.y*v.y + v.z*v.z + v.w*v.w;
#pragma unroll
        for (int m = 1; m <= 32; m <<= 1) { s1 += __shfl_xor(s1, m); s2 += __shfl_xor(s2, m); }
        float mean = s1 * (1.f/DD);
        float var  = s2 * (1.f/DD) - mean*mean;
        float rstd = rsqrtf(var + 1e-5f);
        const float vv[4] = {v.x, v.y, v.z, v.w};
        if (MODE == 0) {
            float4 xo; us4 xo16;
#pragma unroll
            for (int i = 0; i < 4; ++i) {
                int d = lane*4 + i;
                float rr = (vv[i] - mean) * rstd * g[d] + be[d];
                ((float*)&xo)[i] = rr;
                xo16[i] = f2bf(rr);
            }
            *(float4*)&xf[(size_t)(bm + r)*DD + lane*4] = xo;
            *(us4*)&xb[(size_t)(bm + r)*DD + lane*4] = xo16;
        } else {
            float4 xo;
#pragma unroll
            for (int i = 0; i < 4; ++i) {
                int d = lane*4 + i;
                ((float*)&xo)[i] = (vv[i] - mean) * rstd * g[d] + be[d];
            }
            *(float4*)&epi[r][lane*4] = xo;
        }
    }
    if (MODE == 1) {
        __syncthreads();
        const int n = t & 31, dg = t >> 5;
        const int b = bm >> 12, n0 = bm & 4095;
#pragma unroll
        for (int dd = 0; dd < 32; ++dd) {
            int d = dd*8 + dg;
            out[((size_t)b*DD + d)*NN + n0 + n] = epi[n][d];
        }
    }
}

// ---------------------------------------------------------------------------
// Flash attention (v10 structure, unchanged).
// ---------------------------------------------------------------------------
__global__ __launch_bounds__(256) void flash_attn(
    const u16* __restrict__ Qp, const u16* __restrict__ Kperm,
    const u16* __restrict__ Vperm, u16* __restrict__ Op)
{
    __shared__ u16 Kl[2][4096];
    __shared__ u16 Vl[2][4096];
    const int id = blockIdx.x;
    const int sw = (id & 7) * 128 + (id >> 3);
    const int qt = sw & 63;
    const int bh = sw >> 6;
    const size_t base = (size_t)bh * NN * HDD;
    const int t = threadIdx.x, lane = t & 63, w = t >> 6;
    const int q0 = qt * 64;
    const int lrow = lane & 15, g = lane >> 4;

    const bf16x8 qf = *(const bf16x8*)&Qp[base + (size_t)(q0 + w*16 + lrow)*HDD + g*8];

    const u16* kgw = &Kperm[(size_t)bh*131072 + w*1024 + lane*8];
    const u16* vgw = &Vperm[(size_t)bh*131072 + w*1024 + lane*8];
    const int lw = w * 1024;

    u32x4 onesw = {0x3F803F80u, 0x3F803F80u, 0x3F803F80u, 0x3F803F80u};
    const bf16x8 ones = *(bf16x8*)&onesw;

    glds16(kgw,       &Kl[0][lw]);
    glds16(kgw + 512, &Kl[0][lw + 512]);
    glds16(vgw,       &Vl[0][lw]);
    glds16(vgw + 512, &Vl[0][lw + 512]);

    f32x4 o[2] = {};
    f32x4 osum = {};
    __syncthreads();

#define FLASH_STEP(CUR, TT)                                                    \
    {                                                                          \
        if ((TT) < 31) {                                                       \
            const u16* kg = kgw + (size_t)((TT)+1)*4096;                       \
            const u16* vg = vgw + (size_t)((TT)+1)*4096;                       \
            glds16(kg,       &Kl[(CUR)^1][lw]);                                \
            glds16(kg + 512, &Kl[(CUR)^1][lw + 512]);                          \
            glds16(vg,       &Vl[(CUR)^1][lw]);                                \
            glds16(vg + 512, &Vl[(CUR)^1][lw + 512]);                          \
        }                                                                      \
        f32x4 s[8];                                                            \
        __builtin_amdgcn_s_setprio(1);                                         \
        _Pragma("unroll")                                                      \
        for (int nf = 0; nf < 8; ++nf) {                                       \
            bf16x8 kf = *(const bf16x8*)&Kl[(CUR)][nf*512 + lane*8];           \
            f32x4 z = {};                                                      \
            s[nf] = __builtin_amdgcn_mfma_f32_16x16x32_bf16(kf, qf, z, 0, 0, 0); \
        }                                                                      \
        __builtin_amdgcn_s_setprio(0);                                         \
        _Pragma("unroll")                                                      \
        for (int kk = 0; kk < 4; ++kk) {                                       \
            float p0[4], p1[4];                                                \
            _Pragma("unroll")                                                  \
            for (int jj = 0; jj < 4; ++jj) {                                   \
                p0[jj] = __builtin_amdgcn_exp2f(s[2*kk][jj]);                  \
                p1[jj] = __builtin_amdgcn_exp2f(s[2*kk+1][jj]);                 \
            }                                                                  \
            u32x4 paw;                                                         \
            paw[0] = cvt_pk_bf16(p0[0], p0[1]);                                \
            paw[1] = cvt_pk_bf16(p0[2], p0[3]);                                \
            paw[2] = cvt_pk_bf16(p1[0], p1[1]);                                \
            paw[3] = cvt_pk_bf16(p1[2], p1[3]);                                \
            bf16x8 pa = *(bf16x8*)&paw;                                        \
            __builtin_amdgcn_s_setprio(1);                                     \
            _Pragma("unroll")                                                  \
            for (int hf = 0; hf < 2; ++hf) {                                   \
                bf16x8 vf = *(const bf16x8*)&Vl[(CUR)][kk*1024 + hf*512 + lane*8]; \
                o[hf] = __builtin_amdgcn_mfma_f32_16x16x32_bf16(pa, vf, o[hf], 0, 0, 0); \
            }                                                                  \
            osum = __builtin_amdgcn_mfma_f32_16x16x32_bf16(pa, ones, osum, 0, 0, 0); \
            __builtin_amdgcn_s_setprio(0);                                     \
        }                                                                      \
        __syncthreads();                                                       \
    }

    for (int tt = 0; tt < 32; tt += 2) {
        FLASH_STEP(0, tt)
        FLASH_STEP(1, tt + 1)
    }
#undef FLASH_STEP

    const int b = bh >> 3, h = bh & 7;
#pragma unroll
    for (int hf = 0; hf < 2; ++hf)
#pragma unroll
        for (int r = 0; r < 4; ++r) {
            int q = q0 + w*16 + g*4 + r;
            int d = h*HDD + hf*16 + lrow;
            Op[((size_t)b*NN + q)*DD + d] = f2bf(o[hf][r] / osum[r]);
        }
}

// ---------------------------------------------------------------------------
extern "C" void kernel_launch(void* const* d_in, const int* in_sizes, int n_in,
                              void* d_out, int out_size, void* d_ws, size_t ws_size,
                              hipStream_t stream)
{
    const float* F_lidar = (const float*)d_in[0];
    const float* F_cam   = (const float*)d_in[1];
    const float* Wq  = (const float*)d_in[2];
    const float* Wk  = (const float*)d_in[3];
    const float* Wv  = (const float*)d_in[4];
    const float* Wo  = (const float*)d_in[5];
    const float* Wrs = (const float*)d_in[6];
    const float* g1  = (const float*)d_in[7];
    const float* b1  = (const float*)d_in[8];
    const float* g2  = (const float*)d_in[9];
    const float* b2  = (const float*)d_in[10];
    const float* W1  = (const float*)d_in[11];
    const float* bf1 = (const float*)d_in[12];
    const float* W2  = (const float*)d_in[13];
    const float* bf2 = (const float*)d_in[14];
    float* out = (float*)d_out;

    char* ws = (char*)d_ws;
    size_t cur = 0;
    auto carve = [&](size_t bytes) {
        size_t o = cur; cur += (bytes + 255) & ~(size_t)255; return (void*)(ws + o);
    };
    u16* wb    = (u16*)carve(753664u * 2);
    u16* xl    = (u16*)carve((size_t)MTOT * C1 * 2);
    u16* xc    = (u16*)carve((size_t)MTOT * C2 * 2);
    u16* Qb    = (u16*)carve((size_t)MTOT * DD * 2);
    u16* Kperm = (u16*)carve((size_t)MTOT * DD * 2);
    u16* Vperm = (u16*)carve((size_t)MTOT * DD * 2);
    float* resid = (float*)carve((size_t)MTOT * DD * 4);
    u16* attn  = (u16*)carve((size_t)MTOT * DD * 2);
    float* x   = (float*)carve((size_t)MTOT * DD * 4);
    u16* xb    = (u16*)carve((size_t)MTOT * DD * 2);
    u16* hdn   = (u16*)carve((size_t)MTOT * FF * 2);

    // packed weight layout (elems)
    u16* WqRes = wb;             // [Wq;Wres] 512 x 64
    u16* WkWv  = wb + 32768;     // [Wk;Wv]   512 x 256
    u16* Wob   = wb + 163840;    // 256 x 256
    u16* W1b   = wb + 229376;    // 1024 x 256
    u16* W2b   = wb + 491520;    // 256 x 1024

    prep<<<1376, 256, 0, stream>>>(Wq, Wrs, Wk, Wv, Wo, W1, W2, wb,
                                   F_lidar, F_cam, xl, xc);

    const float qscale = 1.4426950408889634f / sqrtf((float)HDD);
    qkv_gemm<<<512, 256, 0, stream>>>(xl, xc, WqRes, WkWv,
                                      resid, Qb, Kperm, Vperm, qscale);

    flash_attn<<<1024, 256, 0, stream>>>(Qb, Kperm, Vperm, attn);

    // Wo GEMM + resid + LN1 -> x (f32), xb (bf16)
    gemm_ln<0><<<256, 256, 0, stream>>>(attn, Wob, DD,
        nullptr, resid, g1, b1, x, xb, nullptr);
    // FFN1
    gemm_bt<1, 128><<<dim3(64, 8), 256, 0, stream>>>(xb, W1b, FF, DD,
        bf1, nullptr, nullptr, hdn, 1.f);
    // FFN2 + bias + skip(x) + LN2 + transpose -> out
    gemm_ln<1><<<256, 256, 0, stream>>>(hdn, W2b, FF,
        bf2, x, g2, b2, nullptr, nullptr, out);
}

// Round 14
// 121.225 us; speedup vs baseline: 1.7101x; 1.0082x over previous
//
#include <hip/hip_runtime.h>
#include <hip/hip_bf16.h>
#include <math.h>

#define NB 2
#define C1 64
#define C2 256
#define DD 256
#define NHH 8
#define HDD 32
#define NN 4096
#define FF 1024
#define MTOT (NB*NN)   // 8192 tokens

typedef unsigned short u16;
typedef __attribute__((ext_vector_type(8))) short bf16x8;
typedef __attribute__((ext_vector_type(4))) float f32x4;
typedef __attribute__((ext_vector_type(4))) unsigned short us4;
typedef __attribute__((ext_vector_type(4))) unsigned int u32x4;

__device__ __forceinline__ u16 f2bf(float f) {
    union { float f; unsigned int i; } u; u.f = f;
    unsigned int r = u.i + 0x7FFFu + ((u.i >> 16) & 1u);
    return (u16)(r >> 16);
}

__device__ __forceinline__ float bf2f(u16 x) {
    union { unsigned i; float f; } u; u.i = ((unsigned)x) << 16; return u.f;
}

__device__ __forceinline__ unsigned cvt_pk_bf16(float a, float b) {
    unsigned r; asm("v_cvt_pk_bf16_f32 %0, %1, %2" : "=v"(r) : "v"(a), "v"(b)); return r;
}

// async global->LDS, 16B per lane: dst = (uniform base) + lane*16, src per-lane
__device__ __forceinline__ void glds16(const void* g, void* l) {
    __builtin_amdgcn_global_load_lds(
        (__attribute__((address_space(1))) void*)g,
        (__attribute__((address_space(3))) void*)l, 16, 0, 0);
}

// ---------------------------------------------------------------------------
// tconv body: (B, C, N) f32 -> (B, N, C) bf16, one 64x64 tile
// ---------------------------------------------------------------------------
__device__ __forceinline__ void tconv_body(const float* __restrict__ src,
    u16* __restrict__ dst, int C, int n0, int c0, int b, int t,
    float (*tile)[65])
{
#pragma unroll
    for (int i = 0; i < 4; ++i) {
        int cc = t + i * 256;
        int c = cc >> 4, off = (cc & 15) * 4;
        const float4 v = *(const float4*)&src[((size_t)b*C + c0 + c)*NN + n0 + off];
        tile[c][off+0] = v.x; tile[c][off+1] = v.y;
        tile[c][off+2] = v.z; tile[c][off+3] = v.w;
    }
    __syncthreads();
    const int n = t >> 2, cch = (t & 3) * 16;
    bf16x8 t0, t1;
#pragma unroll
    for (int i = 0; i < 8; ++i) ((u16*)&t0)[i] = f2bf(tile[cch + i][n]);
#pragma unroll
    for (int i = 0; i < 8; ++i) ((u16*)&t1)[i] = f2bf(tile[cch + 8 + i][n]);
    u16* dp = &dst[((size_t)b*NN + n0 + n)*C + c0 + cch];
    *(bf16x8*)&dp[0] = t0;
    *(bf16x8*)&dp[8] = t1;
}

// ---------------------------------------------------------------------------
// prep: convert ONLY the qkv weights ([Wq;Wres][Wk;Wv], 163840 elems) + both
// input transposes.  blocks [0,160): wconv ; [160,288): tconv lidar ;
// [288,800): tconv cam.
// ---------------------------------------------------------------------------
__global__ __launch_bounds__(256) void prep(
    const float* __restrict__ Wq, const float* __restrict__ Wres,
    const float* __restrict__ Wk, const float* __restrict__ Wv,
    u16* __restrict__ d,
    const float* __restrict__ F_lidar, const float* __restrict__ F_cam,
    u16* __restrict__ xl, u16* __restrict__ xc)
{
    __shared__ float tile[64][65];
    const int id = blockIdx.x, t = threadIdx.x;
    if (id < 160) {
        int i4 = (id * 256 + t) * 4;
        const float* s; int off;
        if      (i4 <  16384) { s = Wq;   off = i4; }
        else if (i4 <  32768) { s = Wres; off = i4 -  16384; }
        else if (i4 <  98304) { s = Wk;   off = i4 -  32768; }
        else                  { s = Wv;   off = i4 -  98304; }
        const float4 v = *(const float4*)&s[off];
        us4 o; o[0] = f2bf(v.x); o[1] = f2bf(v.y); o[2] = f2bf(v.z); o[3] = f2bf(v.w);
        *(us4*)&d[i4] = o;
    } else if (id < 288) {
        int l = id - 160;
        tconv_body(F_lidar, xl, C1, (l & 63)*64, 0, l >> 6, t, tile);
    } else {
        int l = id - 288;
        tconv_body(F_cam, xc, C2, (l & 63)*64, ((l >> 6) & 3)*64, l >> 8, t, tile);
    }
}

// ---------------------------------------------------------------------------
// GEMM body (BM x 128 tile, dbuf glds16 staging).
// MODE 1: bf16 relu(acc+bias) (FFN1)
// MODE 3: fused KV -> Kperm (outb) / Vperm (outf cast) scatters
// MODE 4: fused Q+resid
// ---------------------------------------------------------------------------
template<int MODE, int BM>
__device__ __forceinline__ void gemm_body(
    const u16* __restrict__ A, const u16* __restrict__ Bw,
    int N, int K,
    const float* __restrict__ bias,
    float* __restrict__ outf, u16* __restrict__ outb, float scale,
    int bm, int bn, u16* lA, u16* lB)
{
    constexpr int MFR = BM / 32;
    constexpr int ASZ = BM * 32;
    const int t = threadIdx.x, lane = t & 63, wid = t >> 6;
    const int wr = (wid >> 1) * (BM/2), wc = (wid & 1) * 64;
    const int lrow = lane & 15, lk = (lane >> 4) * 8;
    const int arow = wid*(BM/4) + (lane >> 2);
    const int brow = wid*32 + (lane >> 2);
    const int soff = (lane & 3) * 8;
    const u16* aS = &A[(size_t)(bm + arow)*K + soff];
    const u16* bS = &Bw[(size_t)(bn + brow)*K + soff];
    const int lwA = wid*(BM/4)*32;
    const int lwB = wid*1024;
    f32x4 acc[MFR][4] = {};

    glds16(aS, &lA[lwA]);
    if (BM == 128) glds16(aS + (size_t)16*K, &lA[lwA + 512]);
    glds16(bS, &lB[lwB]);
    glds16(bS + (size_t)16*K, &lB[lwB + 512]);
    __syncthreads();

    const int nst = K >> 5;
    for (int st = 0; st < nst; ++st) {
        const int cur = st & 1;
        if (st < nst - 1) {
            const int k0 = (st + 1) * 32;
            const int nb = (cur ^ 1);
            glds16(aS + k0, &lA[nb*ASZ + lwA]);
            if (BM == 128) glds16(aS + (size_t)16*K + k0, &lA[nb*ASZ + lwA + 512]);
            glds16(bS + k0, &lB[nb*4096 + lwB]);
            glds16(bS + (size_t)16*K + k0, &lB[nb*4096 + lwB + 512]);
        }
        bf16x8 af[MFR], bfr[4];
#pragma unroll
        for (int mf = 0; mf < MFR; ++mf)
            af[mf] = *(const bf16x8*)&lA[cur*ASZ + (wr + mf*16 + lrow)*32 + lk];
#pragma unroll
        for (int nf = 0; nf < 4; ++nf)
            bfr[nf] = *(const bf16x8*)&lB[cur*4096 + (wc + nf*16 + lrow)*32 + lk];
#pragma unroll
        for (int mf = 0; mf < MFR; ++mf)
#pragma unroll
            for (int nf = 0; nf < 4; ++nf)
                acc[mf][nf] = __builtin_amdgcn_mfma_f32_16x16x32_bf16(af[mf], bfr[nf], acc[mf][nf], 0, 0, 0);
        __syncthreads();
    }
#pragma unroll
    for (int mf = 0; mf < MFR; ++mf) {
#pragma unroll
        for (int nf = 0; nf < 4; ++nf) {
#pragma unroll
            for (int j = 0; j < 4; ++j) {
                int row = bm + wr + mf*16 + (lane >> 4)*4 + j;
                int col = bn + wc + nf*16 + lrow;
                float v = acc[mf][nf][j];
                if (MODE == 1) {
                    float r = v + bias[col];
                    outb[(size_t)row*N + col] = f2bf(r > 0.f ? r : 0.f);
                } else if (MODE == 3) {
                    int b = row >> 12, n = row & 4095;
                    if (col < 256) {
                        int h = col >> 5, hd = col & 31;
                        int bh = b*NHH + h;
                        size_t idx = (((size_t)bh*256 + (n >> 4))*64
                                      + (hd >> 3)*16 + (n & 15))*8 + (hd & 7);
                        outb[idx] = f2bf(v);
                    } else {
                        int c = col - 256;
                        int h = c >> 5, hd = c & 31;
                        int hf = hd >> 4, d2 = hd & 15;
                        int bh = b*NHH + h;
                        int kb = n >> 5, kwb = n & 31;
                        int hp = kwb >> 4, gg = (kwb >> 2) & 3, r = kwb & 3;
                        size_t idx = ((((size_t)bh*128 + kb)*2 + hf)*64 + gg*16 + d2)*8
                                   + hp*4 + r;
                        ((u16*)outf)[idx] = f2bf(v);
                    }
                } else if (MODE == 4) {
                    int b = row >> 12, n = row & 4095;
                    if (col < 256) {
                        int h = col >> 5, hd = col & 31;
                        outb[(((size_t)b*NHH + h)*NN + n)*HDD + hd] = f2bf(v * scale);
                    } else {
                        outf[(size_t)row*DD + (col - 256)] = v;
                    }
                }
            }
        }
    }
}

template<int MODE, int BM>
__global__ __launch_bounds__(256) void gemm_bt(
    const u16* __restrict__ A, const u16* __restrict__ Bw,
    int N, int K, const float* __restrict__ bias,
    float* __restrict__ outf, u16* __restrict__ outb, float scale)
{
    __shared__ u16 lA[2*BM*32];
    __shared__ u16 lB[2*4096];
    gemm_body<MODE, BM>(A, Bw, N, K, bias, outf, outb, scale,
                        blockIdx.x*BM, blockIdx.y*128, lA, lB);
}

// ---------------------------------------------------------------------------
// Fused QKV projections + tail-weight conversion.
// blocks [0,256): Q+resid (K=64); [256,512): K+V (K=256, fragment-permuted);
// blocks [512,1088): convert Wo/W1/W2 f32->bf16 (overlaps qkv compute; only
// needed two launches later).
// ---------------------------------------------------------------------------
__global__ __launch_bounds__(256) void qkv_gemm(
    const u16* __restrict__ xl, const u16* __restrict__ xc,
    const u16* __restrict__ WqRes, const u16* __restrict__ WkWv,
    float* __restrict__ resid, u16* __restrict__ Qb,
    u16* __restrict__ Kperm, u16* __restrict__ Vperm, float qscale,
    const float* __restrict__ Wo, const float* __restrict__ W1,
    const float* __restrict__ W2, u16* __restrict__ wb)
{
    __shared__ u16 lA[2*128*32];
    __shared__ u16 lB[2*4096];
    int l = blockIdx.x;
    if (l < 256) {
        gemm_body<4, 128>(xl, WqRes, 512, 64, nullptr, resid, Qb,
                          qscale, (l & 63)*128, (l >> 6)*128, lA, lB);
    } else if (l < 512) {
        l -= 256;
        gemm_body<3, 128>(xc, WkWv, 512, 256, nullptr, (float*)Vperm,
                          Kperm, 1.f, (l & 63)*128, (l >> 6)*128, lA, lB);
    } else {
        int i4 = ((l - 512) * 256 + threadIdx.x) * 4;   // [0, 589824)
        const float* s; int off;
        if      (i4 <  65536) { s = Wo; off = i4; }
        else if (i4 < 327680) { s = W1; off = i4 -  65536; }
        else                  { s = W2; off = i4 - 327680; }
        const float4 v = *(const float4*)&s[off];
        us4 o; o[0] = f2bf(v.x); o[1] = f2bf(v.y); o[2] = f2bf(v.z); o[3] = f2bf(v.w);
        *(us4*)&wb[163840 + i4] = o;
    }
}

// ---------------------------------------------------------------------------
// gemm_ln<MODE>: C = A * B^T with FULL-ROW tile (32 x 256) + fused LayerNorm.
// MODE 0 (Wo+LN1):  v = acc + addf;  LN(g,be) -> xb bf16 only
// MODE 1 (FFN2+LN2+transpose): v = acc + bias + bf2f(addb); LN -> out (B,D,N)
// ---------------------------------------------------------------------------
template<int MODE>
__global__ __launch_bounds__(256) void gemm_ln(
    const u16* __restrict__ A, const u16* __restrict__ Bw, int K,
    const float* __restrict__ bias, const float* __restrict__ addf,
    const u16* __restrict__ addb,
    const float* __restrict__ g, const float* __restrict__ be,
    u16* __restrict__ xb, float* __restrict__ out)
{
    __shared__ __align__(16) char smem[37888];  // lA 4KB | lB 32KB; epi aliases
    u16* lA = (u16*)smem;                    // [2][1024]
    u16* lB = (u16*)(smem + 4096);           // [2][8192]
    float (*epi)[257] = (float(*)[257])smem; // 32*257*4 B

    const int bm = blockIdx.x * 32;
    const int t = threadIdx.x, lane = t & 63, wid = t >> 6;
    const int wc = wid * 64;
    const int lrow = lane & 15, g4 = lane >> 4, lk = g4 * 8;
    const int sr = lane >> 2, sc = (lane & 3) * 8;
    const u16* aS = &A[(size_t)(bm + wid*16 + sr)*K + sc];
    const u16* bS = &Bw[(size_t)(wid*64 + sr)*K + sc];
    f32x4 acc[2][4] = {};

    if (wid < 2) glds16(aS, &lA[wid*512]);
#pragma unroll
    for (int c = 0; c < 4; ++c)
        glds16(bS + (size_t)c*16*K, &lB[wid*2048 + c*512]);
    __syncthreads();

    const int nst = K >> 5;
    for (int st = 0; st < nst; ++st) {
        const int cur = st & 1;
        if (st < nst - 1) {
            const int k0 = (st + 1) * 32;
            const int nb = cur ^ 1;
            if (wid < 2) glds16(aS + k0, &lA[nb*1024 + wid*512]);
#pragma unroll
            for (int c = 0; c < 4; ++c)
                glds16(bS + (size_t)c*16*K + k0, &lB[nb*8192 + wid*2048 + c*512]);
        }
        bf16x8 af[2], bfr[4];
#pragma unroll
        for (int mf = 0; mf < 2; ++mf)
            af[mf] = *(const bf16x8*)&lA[cur*1024 + (mf*16 + lrow)*32 + lk];
#pragma unroll
        for (int nf = 0; nf < 4; ++nf)
            bfr[nf] = *(const bf16x8*)&lB[cur*8192 + (wc + nf*16 + lrow)*32 + lk];
#pragma unroll
        for (int mf = 0; mf < 2; ++mf)
#pragma unroll
            for (int nf = 0; nf < 4; ++nf)
                acc[mf][nf] = __builtin_amdgcn_mfma_f32_16x16x32_bf16(af[mf], bfr[nf], acc[mf][nf], 0, 0, 0);
        __syncthreads();   // also protects the epi alias after the last step
    }

    // epilogue 1: acc (+resid / +bias + skip) -> epi LDS tile
#pragma unroll
    for (int mf = 0; mf < 2; ++mf)
#pragma unroll
        for (int nf = 0; nf < 4; ++nf)
#pragma unroll
            for (int j = 0; j < 4; ++j) {
                int rl = mf*16 + g4*4 + j;
                int col = wc + nf*16 + lrow;
                float v = acc[mf][nf][j];
                if (MODE == 0) v += addf[(size_t)(bm + rl)*DD + col];
                else           v += bias[col] + bf2f(addb[(size_t)(bm + rl)*DD + col]);
                epi[rl][col] = v;
            }
    __syncthreads();

    // epilogue 2: LN per row (wave handles 8 rows; 64 lanes x 4 elems)
#pragma unroll
    for (int r8 = 0; r8 < 8; ++r8) {
        int r = wid*8 + r8;
        const float4 v = *(const float4*)&epi[r][lane*4];
        float s1 = v.x + v.y + v.z + v.w;
        float s2 = v.x*v.x + v.y*v.y + v.z*v.z + v.w*v.w;
#pragma unroll
        for (int m = 1; m <= 32; m <<= 1) { s1 += __shfl_xor(s1, m); s2 += __shfl_xor(s2, m); }
        float mean = s1 * (1.f/DD);
        float var  = s2 * (1.f/DD) - mean*mean;
        float rstd = rsqrtf(var + 1e-5f);
        const float vv[4] = {v.x, v.y, v.z, v.w};
        if (MODE == 0) {
            us4 xo16;
#pragma unroll
            for (int i = 0; i < 4; ++i) {
                int d = lane*4 + i;
                xo16[i] = f2bf((vv[i] - mean) * rstd * g[d] + be[d]);
            }
            *(us4*)&xb[(size_t)(bm + r)*DD + lane*4] = xo16;
        } else {
            float4 xo;
#pragma unroll
            for (int i = 0; i < 4; ++i) {
                int d = lane*4 + i;
                ((float*)&xo)[i] = (vv[i] - mean) * rstd * g[d] + be[d];
            }
            *(float4*)&epi[r][lane*4] = xo;
        }
    }
    if (MODE == 1) {
        __syncthreads();
        const int n = t & 31, dg = t >> 5;
        const int b = bm >> 12, n0 = bm & 4095;
#pragma unroll
        for (int dd = 0; dd < 32; ++dd) {
            int d = dd*8 + dg;
            out[((size_t)b*DD + d)*NN + n0 + n] = epi[n][d];
        }
    }
}

// ---------------------------------------------------------------------------
// Flash attention (v10 verified structure, unchanged).
// ---------------------------------------------------------------------------
__global__ __launch_bounds__(256) void flash_attn(
    const u16* __restrict__ Qp, const u16* __restrict__ Kperm,
    const u16* __restrict__ Vperm, u16* __restrict__ Op)
{
    __shared__ u16 Kl[2][4096];
    __shared__ u16 Vl[2][4096];
    const int id = blockIdx.x;
    const int sw = (id & 7) * 128 + (id >> 3);
    const int qt = sw & 63;
    const int bh = sw >> 6;
    const size_t base = (size_t)bh * NN * HDD;
    const int t = threadIdx.x, lane = t & 63, w = t >> 6;
    const int q0 = qt * 64;
    const int lrow = lane & 15, g = lane >> 4;

    const bf16x8 qf = *(const bf16x8*)&Qp[base + (size_t)(q0 + w*16 + lrow)*HDD + g*8];

    const u16* kgw = &Kperm[(size_t)bh*131072 + w*1024 + lane*8];
    const u16* vgw = &Vperm[(size_t)bh*131072 + w*1024 + lane*8];
    const int lw = w * 1024;

    u32x4 onesw = {0x3F803F80u, 0x3F803F80u, 0x3F803F80u, 0x3F803F80u};
    const bf16x8 ones = *(bf16x8*)&onesw;

    glds16(kgw,       &Kl[0][lw]);
    glds16(kgw + 512, &Kl[0][lw + 512]);
    glds16(vgw,       &Vl[0][lw]);
    glds16(vgw + 512, &Vl[0][lw + 512]);

    f32x4 o[2] = {};
    f32x4 osum = {};
    __syncthreads();

#define FLASH_STEP(CUR, TT)                                                    \
    {                                                                          \
        if ((TT) < 31) {                                                       \
            const u16* kg = kgw + (size_t)((TT)+1)*4096;                       \
            const u16* vg = vgw + (size_t)((TT)+1)*4096;                       \
            glds16(kg,       &Kl[(CUR)^1][lw]);                                \
            glds16(kg + 512, &Kl[(CUR)^1][lw + 512]);                          \
            glds16(vg,       &Vl[(CUR)^1][lw]);                                \
            glds16(vg + 512, &Vl[(CUR)^1][lw + 512]);                          \
        }                                                                      \
        f32x4 s[8];                                                            \
        _Pragma("unroll")                                                      \
        for (int nf = 0; nf < 8; ++nf) {                                       \
            bf16x8 kf = *(const bf16x8*)&Kl[(CUR)][nf*512 + lane*8];           \
            f32x4 z = {};                                                      \
            s[nf] = __builtin_amdgcn_mfma_f32_16x16x32_bf16(kf, qf, z, 0, 0, 0); \
        }                                                                      \
        _Pragma("unroll")                                                      \
        for (int kk = 0; kk < 4; ++kk) {                                       \
            float p0[4], p1[4];                                                \
            _Pragma("unroll")                                                  \
            for (int jj = 0; jj < 4; ++jj) {                                   \
                p0[jj] = __builtin_amdgcn_exp2f(s[2*kk][jj]);                  \
                p1[jj] = __builtin_amdgcn_exp2f(s[2*kk+1][jj]);                 \
            }                                                                  \
            u32x4 paw;                                                         \
            paw[0] = cvt_pk_bf16(p0[0], p0[1]);                                \
            paw[1] = cvt_pk_bf16(p0[2], p0[3]);                                \
            paw[2] = cvt_pk_bf16(p1[0], p1[1]);                                \
            paw[3] = cvt_pk_bf16(p1[2], p1[3]);                                \
            bf16x8 pa = *(bf16x8*)&paw;                                        \
            _Pragma("unroll")                                                  \
            for (int hf = 0; hf < 2; ++hf) {                                   \
                bf16x8 vf = *(const bf16x8*)&Vl[(CUR)][kk*1024 + hf*512 + lane*8]; \
                o[hf] = __builtin_amdgcn_mfma_f32_16x16x32_bf16(pa, vf, o[hf], 0, 0, 0); \
            }                                                                  \
            osum = __builtin_amdgcn_mfma_f32_16x16x32_bf16(pa, ones, osum, 0, 0, 0); \
        }                                                                      \
        __syncthreads();                                                       \
    }

    for (int tt = 0; tt < 32; tt += 2) {
        FLASH_STEP(0, tt)
        FLASH_STEP(1, tt + 1)
    }
#undef FLASH_STEP

    const int b = bh >> 3, h = bh & 7;
#pragma unroll
    for (int hf = 0; hf < 2; ++hf)
#pragma unroll
        for (int r = 0; r < 4; ++r) {
            int q = q0 + w*16 + g*4 + r;
            int d = h*HDD + hf*16 + lrow;
            Op[((size_t)b*NN + q)*DD + d] = f2bf(o[hf][r] / osum[r]);
        }
}

// ---------------------------------------------------------------------------
extern "C" void kernel_launch(void* const* d_in, const int* in_sizes, int n_in,
                              void* d_out, int out_size, void* d_ws, size_t ws_size,
                              hipStream_t stream)
{
    const float* F_lidar = (const float*)d_in[0];
    const float* F_cam   = (const float*)d_in[1];
    const float* Wq  = (const float*)d_in[2];
    const float* Wk  = (const float*)d_in[3];
    const float* Wv  = (const float*)d_in[4];
    const float* Wo  = (const float*)d_in[5];
    const float* Wrs = (const float*)d_in[6];
    const float* g1  = (const float*)d_in[7];
    const float* b1  = (const float*)d_in[8];
    const float* g2  = (const float*)d_in[9];
    const float* b2  = (const float*)d_in[10];
    const float* W1  = (const float*)d_in[11];
    const float* bf1 = (const float*)d_in[12];
    const float* W2  = (const float*)d_in[13];
    const float* bf2 = (const float*)d_in[14];
    float* out = (float*)d_out;

    char* ws = (char*)d_ws;
    size_t cur = 0;
    auto carve = [&](size_t bytes) {
        size_t o = cur; cur += (bytes + 255) & ~(size_t)255; return (void*)(ws + o);
    };
    u16* wb    = (u16*)carve(753664u * 2);
    u16* xl    = (u16*)carve((size_t)MTOT * C1 * 2);
    u16* xc    = (u16*)carve((size_t)MTOT * C2 * 2);
    u16* Qb    = (u16*)carve((size_t)MTOT * DD * 2);
    u16* Kperm = (u16*)carve((size_t)MTOT * DD * 2);
    u16* Vperm = (u16*)carve((size_t)MTOT * DD * 2);
    float* resid = (float*)carve((size_t)MTOT * DD * 4);
    u16* attn  = (u16*)carve((size_t)MTOT * DD * 2);
    u16* xb    = (u16*)carve((size_t)MTOT * DD * 2);
    u16* hdn   = (u16*)carve((size_t)MTOT * FF * 2);

    // packed weight layout (elems)
    u16* WqRes = wb;             // [Wq;Wres] 512 x 64
    u16* WkWv  = wb + 32768;     // [Wk;Wv]   512 x 256
    u16* Wob   = wb + 163840;    // 256 x 256
    u16* W1b   = wb + 229376;    // 1024 x 256
    u16* W2b   = wb + 491520;    // 256 x 1024

    prep<<<800, 256, 0, stream>>>(Wq, Wrs, Wk, Wv, wb, F_lidar, F_cam, xl, xc);

    const float qscale = 1.4426950408889634f / sqrtf((float)HDD);
    qkv_gemm<<<1088, 256, 0, stream>>>(xl, xc, WqRes, WkWv,
                                       resid, Qb, Kperm, Vperm, qscale,
                                       Wo, W1, W2, wb);

    flash_attn<<<1024, 256, 0, stream>>>(Qb, Kperm, Vperm, attn);

    // Wo GEMM + resid + LN1 -> xb (bf16)
    gemm_ln<0><<<256, 256, 0, stream>>>(attn, Wob, DD,
        nullptr, resid, nullptr, g1, b1, xb, nullptr);
    // FFN1
    gemm_bt<1, 128><<<dim3(64, 8), 256, 0, stream>>>(xb, W1b, FF, DD,
        bf1, nullptr, hdn, 1.f);
    // FFN2 + bias + skip(xb) + LN2 + transpose -> out
    gemm_ln<1><<<256, 256, 0, stream>>>(hdn, W2b, FF,
        bf2, nullptr, xb, g2, b2, nullptr, out);
}

// Round 15
// 117.707 us; speedup vs baseline: 1.7612x; 1.0299x over previous
//
#include <hip/hip_runtime.h>
#include <hip/hip_bf16.h>
#include <math.h>

#define NB 2
#define C1 64
#define C2 256
#define DD 256
#define NHH 8
#define HDD 32
#define NN 4096
#define FF 1024
#define MTOT (NB*NN)   // 8192 tokens

typedef unsigned short u16;
typedef __attribute__((ext_vector_type(8))) short bf16x8;
typedef __attribute__((ext_vector_type(4))) float f32x4;
typedef __attribute__((ext_vector_type(4))) unsigned short us4;
typedef __attribute__((ext_vector_type(4))) unsigned int u32x4;

__device__ __forceinline__ u16 f2bf(float f) {
    union { float f; unsigned int i; } u; u.f = f;
    unsigned int r = u.i + 0x7FFFu + ((u.i >> 16) & 1u);
    return (u16)(r >> 16);
}

__device__ __forceinline__ float bf2f(u16 x) {
    union { unsigned i; float f; } u; u.i = ((unsigned)x) << 16; return u.f;
}

__device__ __forceinline__ unsigned cvt_pk_bf16(float a, float b) {
    unsigned r; asm("v_cvt_pk_bf16_f32 %0, %1, %2" : "=v"(r) : "v"(a), "v"(b)); return r;
}

// async global->LDS, 16B per lane: dst = (uniform base) + lane*16, src per-lane
__device__ __forceinline__ void glds16(const void* g, void* l) {
    __builtin_amdgcn_global_load_lds(
        (__attribute__((address_space(1))) void*)g,
        (__attribute__((address_space(3))) void*)l, 16, 0, 0);
}

// ---------------------------------------------------------------------------
// tconv body: (B, C, N) f32 -> (B, N, C) bf16, one 64x64 tile
// ---------------------------------------------------------------------------
__device__ __forceinline__ void tconv_body(const float* __restrict__ src,
    u16* __restrict__ dst, int C, int n0, int c0, int b, int t,
    float (*tile)[65])
{
#pragma unroll
    for (int i = 0; i < 4; ++i) {
        int cc = t + i * 256;
        int c = cc >> 4, off = (cc & 15) * 4;
        const float4 v = *(const float4*)&src[((size_t)b*C + c0 + c)*NN + n0 + off];
        tile[c][off+0] = v.x; tile[c][off+1] = v.y;
        tile[c][off+2] = v.z; tile[c][off+3] = v.w;
    }
    __syncthreads();
    const int n = t >> 2, cch = (t & 3) * 16;
    bf16x8 t0, t1;
#pragma unroll
    for (int i = 0; i < 8; ++i) ((u16*)&t0)[i] = f2bf(tile[cch + i][n]);
#pragma unroll
    for (int i = 0; i < 8; ++i) ((u16*)&t1)[i] = f2bf(tile[cch + 8 + i][n]);
    u16* dp = &dst[((size_t)b*NN + n0 + n)*C + c0 + cch];
    *(bf16x8*)&dp[0] = t0;
    *(bf16x8*)&dp[8] = t1;
}

// ---------------------------------------------------------------------------
// prep: convert ONLY the qkv weights + both input transposes.
// blocks [0,160): wconv ; [160,288): tconv lidar ; [288,800): tconv cam.
// ---------------------------------------------------------------------------
__global__ __launch_bounds__(256) void prep(
    const float* __restrict__ Wq, const float* __restrict__ Wres,
    const float* __restrict__ Wk, const float* __restrict__ Wv,
    u16* __restrict__ d,
    const float* __restrict__ F_lidar, const float* __restrict__ F_cam,
    u16* __restrict__ xl, u16* __restrict__ xc)
{
    __shared__ float tile[64][65];
    const int id = blockIdx.x, t = threadIdx.x;
    if (id < 160) {
        int i4 = (id * 256 + t) * 4;
        const float* s; int off;
        if      (i4 <  16384) { s = Wq;   off = i4; }
        else if (i4 <  32768) { s = Wres; off = i4 -  16384; }
        else if (i4 <  98304) { s = Wk;   off = i4 -  32768; }
        else                  { s = Wv;   off = i4 -  98304; }
        const float4 v = *(const float4*)&s[off];
        us4 o; o[0] = f2bf(v.x); o[1] = f2bf(v.y); o[2] = f2bf(v.z); o[3] = f2bf(v.w);
        *(us4*)&d[i4] = o;
    } else if (id < 288) {
        int l = id - 160;
        tconv_body(F_lidar, xl, C1, (l & 63)*64, 0, l >> 6, t, tile);
    } else {
        int l = id - 288;
        tconv_body(F_cam, xc, C2, (l & 63)*64, ((l >> 6) & 3)*64, l >> 8, t, tile);
    }
}

// ---------------------------------------------------------------------------
// GEMM body (BM x 128 tile, dbuf glds16 staging).
// MODE 1: bf16 relu(acc+bias) (FFN1)
// MODE 3: fused KV -> Kperm (outb) / Vperm (outf cast) scatters
// MODE 4: fused Q+resid
// ---------------------------------------------------------------------------
template<int MODE, int BM>
__device__ __forceinline__ void gemm_body(
    const u16* __restrict__ A, const u16* __restrict__ Bw,
    int N, int K,
    const float* __restrict__ bias,
    float* __restrict__ outf, u16* __restrict__ outb, float scale,
    int bm, int bn, u16* lA, u16* lB)
{
    constexpr int MFR = BM / 32;
    constexpr int ASZ = BM * 32;
    const int t = threadIdx.x, lane = t & 63, wid = t >> 6;
    const int wr = (wid >> 1) * (BM/2), wc = (wid & 1) * 64;
    const int lrow = lane & 15, lk = (lane >> 4) * 8;
    const int arow = wid*(BM/4) + (lane >> 2);
    const int brow = wid*32 + (lane >> 2);
    const int soff = (lane & 3) * 8;
    const u16* aS = &A[(size_t)(bm + arow)*K + soff];
    const u16* bS = &Bw[(size_t)(bn + brow)*K + soff];
    const int lwA = wid*(BM/4)*32;
    const int lwB = wid*1024;
    f32x4 acc[MFR][4] = {};

    glds16(aS, &lA[lwA]);
    if (BM == 128) glds16(aS + (size_t)16*K, &lA[lwA + 512]);
    glds16(bS, &lB[lwB]);
    glds16(bS + (size_t)16*K, &lB[lwB + 512]);
    __syncthreads();

    const int nst = K >> 5;
    for (int st = 0; st < nst; ++st) {
        const int cur = st & 1;
        if (st < nst - 1) {
            const int k0 = (st + 1) * 32;
            const int nb = (cur ^ 1);
            glds16(aS + k0, &lA[nb*ASZ + lwA]);
            if (BM == 128) glds16(aS + (size_t)16*K + k0, &lA[nb*ASZ + lwA + 512]);
            glds16(bS + k0, &lB[nb*4096 + lwB]);
            glds16(bS + (size_t)16*K + k0, &lB[nb*4096 + lwB + 512]);
        }
        bf16x8 af[MFR], bfr[4];
#pragma unroll
        for (int mf = 0; mf < MFR; ++mf)
            af[mf] = *(const bf16x8*)&lA[cur*ASZ + (wr + mf*16 + lrow)*32 + lk];
#pragma unroll
        for (int nf = 0; nf < 4; ++nf)
            bfr[nf] = *(const bf16x8*)&lB[cur*4096 + (wc + nf*16 + lrow)*32 + lk];
#pragma unroll
        for (int mf = 0; mf < MFR; ++mf)
#pragma unroll
            for (int nf = 0; nf < 4; ++nf)
                acc[mf][nf] = __builtin_amdgcn_mfma_f32_16x16x32_bf16(af[mf], bfr[nf], acc[mf][nf], 0, 0, 0);
        __syncthreads();
    }
#pragma unroll
    for (int mf = 0; mf < MFR; ++mf) {
#pragma unroll
        for (int nf = 0; nf < 4; ++nf) {
#pragma unroll
            for (int j = 0; j < 4; ++j) {
                int row = bm + wr + mf*16 + (lane >> 4)*4 + j;
                int col = bn + wc + nf*16 + lrow;
                float v = acc[mf][nf][j];
                if (MODE == 1) {
                    float r = v + bias[col];
                    outb[(size_t)row*N + col] = f2bf(r > 0.f ? r : 0.f);
                } else if (MODE == 3) {
                    int b = row >> 12, n = row & 4095;
                    if (col < 256) {
                        int h = col >> 5, hd = col & 31;
                        int bh = b*NHH + h;
                        size_t idx = (((size_t)bh*256 + (n >> 4))*64
                                      + (hd >> 3)*16 + (n & 15))*8 + (hd & 7);
                        outb[idx] = f2bf(v);
                    } else {
                        int c = col - 256;
                        int h = c >> 5, hd = c & 31;
                        int hf = hd >> 4, d2 = hd & 15;
                        int bh = b*NHH + h;
                        int kb = n >> 5, kwb = n & 31;
                        int hp = kwb >> 4, gg = (kwb >> 2) & 3, r = kwb & 3;
                        size_t idx = ((((size_t)bh*128 + kb)*2 + hf)*64 + gg*16 + d2)*8
                                   + hp*4 + r;
                        ((u16*)outf)[idx] = f2bf(v);
                    }
                } else if (MODE == 4) {
                    int b = row >> 12, n = row & 4095;
                    if (col < 256) {
                        int h = col >> 5, hd = col & 31;
                        outb[(((size_t)b*NHH + h)*NN + n)*HDD + hd] = f2bf(v * scale);
                    } else {
                        outf[(size_t)row*DD + (col - 256)] = v;
                    }
                }
            }
        }
    }
}

template<int MODE, int BM>
__global__ __launch_bounds__(256) void gemm_bt(
    const u16* __restrict__ A, const u16* __restrict__ Bw,
    int N, int K, const float* __restrict__ bias,
    float* __restrict__ outf, u16* __restrict__ outb, float scale)
{
    __shared__ u16 lA[2*BM*32];
    __shared__ u16 lB[2*4096];
    gemm_body<MODE, BM>(A, Bw, N, K, bias, outf, outb, scale,
                        blockIdx.x*BM, blockIdx.y*128, lA, lB);
}

// ---------------------------------------------------------------------------
// Fused QKV projections + tail-weight conversion.
// blocks [0,256): Q+resid (K=64); [256,512): K+V (K=256, fragment-permuted);
// blocks [512,1088): convert Wo/W1/W2 f32->bf16 (overlaps qkv compute).
// ---------------------------------------------------------------------------
__global__ __launch_bounds__(256) void qkv_gemm(
    const u16* __restrict__ xl, const u16* __restrict__ xc,
    const u16* __restrict__ WqRes, const u16* __restrict__ WkWv,
    float* __restrict__ resid, u16* __restrict__ Qb,
    u16* __restrict__ Kperm, u16* __restrict__ Vperm, float qscale,
    const float* __restrict__ Wo, const float* __restrict__ W1,
    const float* __restrict__ W2, u16* __restrict__ wb)
{
    __shared__ u16 lA[2*128*32];
    __shared__ u16 lB[2*4096];
    int l = blockIdx.x;
    if (l < 256) {
        gemm_body<4, 128>(xl, WqRes, 512, 64, nullptr, resid, Qb,
                          qscale, (l & 63)*128, (l >> 6)*128, lA, lB);
    } else if (l < 512) {
        l -= 256;
        gemm_body<3, 128>(xc, WkWv, 512, 256, nullptr, (float*)Vperm,
                          Kperm, 1.f, (l & 63)*128, (l >> 6)*128, lA, lB);
    } else {
        int i4 = ((l - 512) * 256 + threadIdx.x) * 4;   // [0, 589824)
        const float* s; int off;
        if      (i4 <  65536) { s = Wo; off = i4; }
        else if (i4 < 327680) { s = W1; off = i4 -  65536; }
        else                  { s = W2; off = i4 - 327680; }
        const float4 v = *(const float4*)&s[off];
        us4 o; o[0] = f2bf(v.x); o[1] = f2bf(v.y); o[2] = f2bf(v.z); o[3] = f2bf(v.w);
        *(us4*)&wb[163840 + i4] = o;
    }
}

// ---------------------------------------------------------------------------
// gemm_ln<MODE>: full-row tile (32 x 256) + fused LayerNorm (round-14 verified)
// MODE 0 (Wo+LN1):  v = acc + addf;  LN(g,be) -> xb bf16 only
// MODE 1 (FFN2+LN2+transpose): v = acc + bias + bf2f(addb); LN -> out (B,D,N)
// ---------------------------------------------------------------------------
template<int MODE>
__global__ __launch_bounds__(256) void gemm_ln(
    const u16* __restrict__ A, const u16* __restrict__ Bw, int K,
    const float* __restrict__ bias, const float* __restrict__ addf,
    const u16* __restrict__ addb,
    const float* __restrict__ g, const float* __restrict__ be,
    u16* __restrict__ xb, float* __restrict__ out)
{
    __shared__ __align__(16) char smem[37888];  // lA 4KB | lB 32KB; epi aliases
    u16* lA = (u16*)smem;                    // [2][1024]
    u16* lB = (u16*)(smem + 4096);           // [2][8192]
    float (*epi)[257] = (float(*)[257])smem; // 32*257*4 B

    const int bm = blockIdx.x * 32;
    const int t = threadIdx.x, lane = t & 63, wid = t >> 6;
    const int wc = wid * 64;
    const int lrow = lane & 15, g4 = lane >> 4, lk = g4 * 8;
    const int sr = lane >> 2, sc = (lane & 3) * 8;
    const u16* aS = &A[(size_t)(bm + wid*16 + sr)*K + sc];
    const u16* bS = &Bw[(size_t)(wid*64 + sr)*K + sc];
    f32x4 acc[2][4] = {};

    if (wid < 2) glds16(aS, &lA[wid*512]);
#pragma unroll
    for (int c = 0; c < 4; ++c)
        glds16(bS + (size_t)c*16*K, &lB[wid*2048 + c*512]);
    __syncthreads();

    const int nst = K >> 5;
    for (int st = 0; st < nst; ++st) {
        const int cur = st & 1;
        if (st < nst - 1) {
            const int k0 = (st + 1) * 32;
            const int nb = cur ^ 1;
            if (wid < 2) glds16(aS + k0, &lA[nb*1024 + wid*512]);
#pragma unroll
            for (int c = 0; c < 4; ++c)
                glds16(bS + (size_t)c*16*K + k0, &lB[nb*8192 + wid*2048 + c*512]);
        }
        bf16x8 af[2], bfr[4];
#pragma unroll
        for (int mf = 0; mf < 2; ++mf)
            af[mf] = *(const bf16x8*)&lA[cur*1024 + (mf*16 + lrow)*32 + lk];
#pragma unroll
        for (int nf = 0; nf < 4; ++nf)
            bfr[nf] = *(const bf16x8*)&lB[cur*8192 + (wc + nf*16 + lrow)*32 + lk];
#pragma unroll
        for (int mf = 0; mf < 2; ++mf)
#pragma unroll
            for (int nf = 0; nf < 4; ++nf)
                acc[mf][nf] = __builtin_amdgcn_mfma_f32_16x16x32_bf16(af[mf], bfr[nf], acc[mf][nf], 0, 0, 0);
        __syncthreads();   // also protects the epi alias after the last step
    }

    // epilogue 1: acc (+resid / +bias + skip) -> epi LDS tile
#pragma unroll
    for (int mf = 0; mf < 2; ++mf)
#pragma unroll
        for (int nf = 0; nf < 4; ++nf)
#pragma unroll
            for (int j = 0; j < 4; ++j) {
                int rl = mf*16 + g4*4 + j;
                int col = wc + nf*16 + lrow;
                float v = acc[mf][nf][j];
                if (MODE == 0) v += addf[(size_t)(bm + rl)*DD + col];
                else           v += bias[col] + bf2f(addb[(size_t)(bm + rl)*DD + col]);
                epi[rl][col] = v;
            }
    __syncthreads();

    // epilogue 2: LN per row (wave handles 8 rows; 64 lanes x 4 elems)
#pragma unroll
    for (int r8 = 0; r8 < 8; ++r8) {
        int r = wid*8 + r8;
        const float4 v = *(const float4*)&epi[r][lane*4];
        float s1 = v.x + v.y + v.z + v.w;
        float s2 = v.x*v.x + v.y*v.y + v.z*v.z + v.w*v.w;
#pragma unroll
        for (int m = 1; m <= 32; m <<= 1) { s1 += __shfl_xor(s1, m); s2 += __shfl_xor(s2, m); }
        float mean = s1 * (1.f/DD);
        float var  = s2 * (1.f/DD) - mean*mean;
        float rstd = rsqrtf(var + 1e-5f);
        const float vv[4] = {v.x, v.y, v.z, v.w};
        if (MODE == 0) {
            us4 xo16;
#pragma unroll
            for (int i = 0; i < 4; ++i) {
                int d = lane*4 + i;
                xo16[i] = f2bf((vv[i] - mean) * rstd * g[d] + be[d]);
            }
            *(us4*)&xb[(size_t)(bm + r)*DD + lane*4] = xo16;
        } else {
            float4 xo;
#pragma unroll
            for (int i = 0; i < 4; ++i) {
                int d = lane*4 + i;
                ((float*)&xo)[i] = (vv[i] - mean) * rstd * g[d] + be[d];
            }
            *(float4*)&epi[r][lane*4] = xo;
        }
    }
    if (MODE == 1) {
        __syncthreads();
        const int n = t & 31, dg = t >> 5;
        const int b = bm >> 12, n0 = bm & 4095;
#pragma unroll
        for (int dd = 0; dd < 32; ++dd) {
            int d = dd*8 + dg;
            out[((size_t)b*DD + d)*NN + n0 + n] = epi[n][d];
        }
    }
}

// ---------------------------------------------------------------------------
// Flash attention v11: 128 q-rows per block (2 Q-frags per wave), 512 blocks.
// K-fragments and V-fragments shared by both Q-halves -> staging traffic,
// barriers, and K-loads per unit work halve vs v10; exp2/cvt unchanged.
// LDS double-buffered K/V via glds16, fragment-linear layouts, no-max base-2
// softmax, swapped QK^T, MFMA rowsum vs all-ones, XCD swizzle (2 bh / XCD).
// ---------------------------------------------------------------------------
__global__ __launch_bounds__(256) void flash_attn(
    const u16* __restrict__ Qp, const u16* __restrict__ Kperm,
    const u16* __restrict__ Vperm, u16* __restrict__ Op)
{
    __shared__ u16 Kl[2][4096];   // [b16 8][lane 64][8]
    __shared__ u16 Vl[2][4096];   // [kb 4][hf 2][lane 64][8]
    const int id = blockIdx.x;                 // 0..511
    const int sw = (id & 7) * 64 + (id >> 3);  // XCD-grouped
    const int qt = sw & 31;
    const int bh = sw >> 5;                    // b*8 + h
    const size_t base = (size_t)bh * NN * HDD; // Q (b,h,n,hd)
    const int t = threadIdx.x, lane = t & 63, w = t >> 6;
    const int q0 = qt * 128 + w * 32;          // wave's 32 q rows
    const int lrow = lane & 15, g = lane >> 4;

    const bf16x8 qfa = *(const bf16x8*)&Qp[base + (size_t)(q0 + lrow)*HDD + g*8];
    const bf16x8 qfb = *(const bf16x8*)&Qp[base + (size_t)(q0 + 16 + lrow)*HDD + g*8];

    const u16* kgw = &Kperm[(size_t)bh*131072 + w*1024 + lane*8];
    const u16* vgw = &Vperm[(size_t)bh*131072 + w*1024 + lane*8];
    const int lw = w * 1024;

    u32x4 onesw = {0x3F803F80u, 0x3F803F80u, 0x3F803F80u, 0x3F803F80u};
    const bf16x8 ones = *(bf16x8*)&onesw;

    glds16(kgw,       &Kl[0][lw]);
    glds16(kgw + 512, &Kl[0][lw + 512]);
    glds16(vgw,       &Vl[0][lw]);
    glds16(vgw + 512, &Vl[0][lw + 512]);

    f32x4 oa[2] = {}, ob[2] = {};
    f32x4 osa = {}, osb = {};
    __syncthreads();

#define FLASH_STEP(CUR, TT)                                                    \
    {                                                                          \
        if ((TT) < 31) {                                                       \
            const u16* kg = kgw + (size_t)((TT)+1)*4096;                       \
            const u16* vg = vgw + (size_t)((TT)+1)*4096;                       \
            glds16(kg,       &Kl[(CUR)^1][lw]);                                \
            glds16(kg + 512, &Kl[(CUR)^1][lw + 512]);                          \
            glds16(vg,       &Vl[(CUR)^1][lw]);                                \
            glds16(vg + 512, &Vl[(CUR)^1][lw + 512]);                          \
        }                                                                      \
        f32x4 sa[8], sb[8];                                                    \
        _Pragma("unroll")                                                      \
        for (int nf = 0; nf < 8; ++nf) {                                       \
            bf16x8 kf = *(const bf16x8*)&Kl[(CUR)][nf*512 + lane*8];           \
            f32x4 z = {};                                                      \
            sa[nf] = __builtin_amdgcn_mfma_f32_16x16x32_bf16(kf, qfa, z, 0, 0, 0); \
            sb[nf] = __builtin_amdgcn_mfma_f32_16x16x32_bf16(kf, qfb, z, 0, 0, 0); \
        }                                                                      \
        _Pragma("unroll")                                                      \
        for (int kk = 0; kk < 4; ++kk) {                                       \
            float pa0[4], pa1[4], pb0[4], pb1[4];                              \
            _Pragma("unroll")                                                  \
            for (int jj = 0; jj < 4; ++jj) {                                   \
                pa0[jj] = __builtin_amdgcn_exp2f(sa[2*kk][jj]);                \
                pa1[jj] = __builtin_amdgcn_exp2f(sa[2*kk+1][jj]);              \
                pb0[jj] = __builtin_amdgcn_exp2f(sb[2*kk][jj]);                \
                pb1[jj] = __builtin_amdgcn_exp2f(sb[2*kk+1][jj]);              \
            }                                                                  \
            u32x4 wa, wbk;                                                     \
            wa[0] = cvt_pk_bf16(pa0[0], pa0[1]);                               \
            wa[1] = cvt_pk_bf16(pa0[2], pa0[3]);                               \
            wa[2] = cvt_pk_bf16(pa1[0], pa1[1]);                               \
            wa[3] = cvt_pk_bf16(pa1[2], pa1[3]);                               \
            wbk[0] = cvt_pk_bf16(pb0[0], pb0[1]);                              \
            wbk[1] = cvt_pk_bf16(pb0[2], pb0[3]);                              \
            wbk[2] = cvt_pk_bf16(pb1[0], pb1[1]);                              \
            wbk[3] = cvt_pk_bf16(pb1[2], pb1[3]);                              \
            bf16x8 paf = *(bf16x8*)&wa;                                        \
            bf16x8 pbf = *(bf16x8*)&wbk;                                       \
            _Pragma("unroll")                                                  \
            for (int hf = 0; hf < 2; ++hf) {                                   \
                bf16x8 vf = *(const bf16x8*)&Vl[(CUR)][kk*1024 + hf*512 + lane*8]; \
                oa[hf] = __builtin_amdgcn_mfma_f32_16x16x32_bf16(paf, vf, oa[hf], 0, 0, 0); \
                ob[hf] = __builtin_amdgcn_mfma_f32_16x16x32_bf16(pbf, vf, ob[hf], 0, 0, 0); \
            }                                                                  \
            osa = __builtin_amdgcn_mfma_f32_16x16x32_bf16(paf, ones, osa, 0, 0, 0); \
            osb = __builtin_amdgcn_mfma_f32_16x16x32_bf16(pbf, ones, osb, 0, 0, 0); \
        }                                                                      \
        __syncthreads();                                                       \
    }

    for (int tt = 0; tt < 32; tt += 2) {
        FLASH_STEP(0, tt)
        FLASH_STEP(1, tt + 1)
    }
#undef FLASH_STEP

    // normalization: os*[r] = rowsum for q = (+16) + g*4 + r -- same map as o
    const int b = bh >> 3, h = bh & 7;
#pragma unroll
    for (int hf = 0; hf < 2; ++hf)
#pragma unroll
        for (int r = 0; r < 4; ++r) {
            int qa = q0 + g*4 + r;
            int qb = qa + 16;
            int d = h*HDD + hf*16 + lrow;
            Op[((size_t)b*NN + qa)*DD + d] = f2bf(oa[hf][r] / osa[r]);
            Op[((size_t)b*NN + qb)*DD + d] = f2bf(ob[hf][r] / osb[r]);
        }
}

// ---------------------------------------------------------------------------
extern "C" void kernel_launch(void* const* d_in, const int* in_sizes, int n_in,
                              void* d_out, int out_size, void* d_ws, size_t ws_size,
                              hipStream_t stream)
{
    const float* F_lidar = (const float*)d_in[0];
    const float* F_cam   = (const float*)d_in[1];
    const float* Wq  = (const float*)d_in[2];
    const float* Wk  = (const float*)d_in[3];
    const float* Wv  = (const float*)d_in[4];
    const float* Wo  = (const float*)d_in[5];
    const float* Wrs = (const float*)d_in[6];
    const float* g1  = (const float*)d_in[7];
    const float* b1  = (const float*)d_in[8];
    const float* g2  = (const float*)d_in[9];
    const float* b2  = (const float*)d_in[10];
    const float* W1  = (const float*)d_in[11];
    const float* bf1 = (const float*)d_in[12];
    const float* W2  = (const float*)d_in[13];
    const float* bf2 = (const float*)d_in[14];
    float* out = (float*)d_out;

    char* ws = (char*)d_ws;
    size_t cur = 0;
    auto carve = [&](size_t bytes) {
        size_t o = cur; cur += (bytes + 255) & ~(size_t)255; return (void*)(ws + o);
    };
    u16* wb    = (u16*)carve(753664u * 2);
    u16* xl    = (u16*)carve((size_t)MTOT * C1 * 2);
    u16* xc    = (u16*)carve((size_t)MTOT * C2 * 2);
    u16* Qb    = (u16*)carve((size_t)MTOT * DD * 2);
    u16* Kperm = (u16*)carve((size_t)MTOT * DD * 2);
    u16* Vperm = (u16*)carve((size_t)MTOT * DD * 2);
    float* resid = (float*)carve((size_t)MTOT * DD * 4);
    u16* attn  = (u16*)carve((size_t)MTOT * DD * 2);
    u16* xb    = (u16*)carve((size_t)MTOT * DD * 2);
    u16* hdn   = (u16*)carve((size_t)MTOT * FF * 2);

    // packed weight layout (elems)
    u16* WqRes = wb;             // [Wq;Wres] 512 x 64
    u16* WkWv  = wb + 32768;     // [Wk;Wv]   512 x 256
    u16* Wob   = wb + 163840;    // 256 x 256
    u16* W1b   = wb + 229376;    // 1024 x 256
    u16* W2b   = wb + 491520;    // 256 x 1024

    prep<<<800, 256, 0, stream>>>(Wq, Wrs, Wk, Wv, wb, F_lidar, F_cam, xl, xc);

    const float qscale = 1.4426950408889634f / sqrtf((float)HDD);
    qkv_gemm<<<1088, 256, 0, stream>>>(xl, xc, WqRes, WkWv,
                                       resid, Qb, Kperm, Vperm, qscale,
                                       Wo, W1, W2, wb);

    flash_attn<<<512, 256, 0, stream>>>(Qb, Kperm, Vperm, attn);

    // Wo GEMM + resid + LN1 -> xb (bf16)
    gemm_ln<0><<<256, 256, 0, stream>>>(attn, Wob, DD,
        nullptr, resid, nullptr, g1, b1, xb, nullptr);
    // FFN1
    gemm_bt<1, 128><<<dim3(64, 8), 256, 0, stream>>>(xb, W1b, FF, DD,
        bf1, nullptr, hdn, 1.f);
    // FFN2 + bias + skip(xb) + LN2 + transpose -> out
    gemm_ln<1><<<256, 256, 0, stream>>>(hdn, W2b, FF,
        bf2, nullptr, xb, g2, b2, nullptr, out);
}